// Round 8
// baseline (622.693 us; speedup 1.0000x reference)
//
#include <hip/hip_runtime.h>
#include <hip/hip_bf16.h>
#include <math.h>

#define N_TOK   2048
#define HIDDEN  1024
#define INTER   2816
#define NEXP    8
#define NADAPT  2
#define MAXRANK 16
#define TOPK    2
#define NSEQ    8
#define NPAIRS  (N_TOK*TOPK)     // 4096
#define NGU     (2*INTER)        // 5632

typedef unsigned short u16;
typedef __attribute__((ext_vector_type(8))) short bf16x8;
typedef __attribute__((ext_vector_type(4))) float f32x4;

// ---- FAST workspace layout (bytes), FAST_NEED = 164 MiB (unchanged) ----
#define F_CNT   0u
#define F_PERM  4096u        // 131072
#define F_ZG    139264u      // 262144
#define F_ZU    401408u      // 262144
#define F_ZD    663552u      // 262144 (ends 925696)
#define F_XBF   1048576u     // 4194304
#define F_ACT   5242880u     // 23068672
#define F_GB    28311552u    // 1441792
#define F_UB    29753344u    // 1441792
#define F_DB    31195136u    // 524288  (ends 31719424)
#define F_GA_BF 31719424u    // 524288  bf16 gate_a
#define F_UA_BF 32243712u    // 524288  bf16 up_a   (ends 32768000)
#define F_ZDF   32768000u    // 524288  f32 zd accumulator (ends 33292288)
#define F_DA_BF 33554432u    // 1441792 bf16 down_a
#define FAST_NEED 171966464u

// ---- fallback layout, ~24.1 MB ----
#define B_CNT   0u
#define B_PERM  4096u
#define B_ZG    262144u
#define B_ZU    524288u
#define B_ZD    786432u
#define B_ACT   1048576u

__device__ __forceinline__ float bf2f(u16 u){
  union { unsigned int i; float f; } v; v.i = ((unsigned int)u)<<16; return v.f;
}
__device__ __forceinline__ u16 f2bf(float f){
  union { float f; unsigned int i; } v; v.f = f;
  unsigned int i = v.i;
  return (u16)((i + 0x7fffu + ((i>>16)&1u)) >> 16);
}
__device__ __forceinline__ uint4 cvt8(const float* src){
  float4 lo = *(const float4*)src;
  float4 hi = *(const float4*)(src+4);
  uint4 r;
  r.x = (unsigned)f2bf(lo.x) | ((unsigned)f2bf(lo.y)<<16);
  r.y = (unsigned)f2bf(lo.z) | ((unsigned)f2bf(lo.w)<<16);
  r.z = (unsigned)f2bf(hi.x) | ((unsigned)f2bf(hi.y)<<16);
  r.w = (unsigned)f2bf(hi.z) | ((unsigned)f2bf(hi.w)<<16);
  return r;
}
__device__ __forceinline__ uint2 cvt4(float4 v){
  uint2 r;
  r.x = (unsigned)f2bf(v.x) | ((unsigned)f2bf(v.y)<<16);
  r.y = (unsigned)f2bf(v.z) | ((unsigned)f2bf(v.w)<<16);
  return r;
}

// HW packed f32->bf16 (gfx950 v_cvt_pk_bf16_f32) — weight-staging fast path only
__device__ __forceinline__ unsigned cvtpk(float a, float b){
  unsigned r;
  asm("v_cvt_pk_bf16_f32 %0, %1, %2" : "=v"(r) : "v"(a), "v"(b));
  return r;
}
__device__ __forceinline__ bf16x8 pack8v(f32x4 a, f32x4 b){
  union { uint4 u; bf16x8 h; } v;
  v.u.x = cvtpk(a[0], a[1]);
  v.u.y = cvtpk(a[2], a[3]);
  v.u.z = cvtpk(b[0], b[1]);
  v.u.w = cvtpk(b[2], b[3]);
  return v.h;
}

// convert one 8192-float chunk c: loads first (8 in flight), then stores
__device__ __forceinline__ void cvt_chunk8k(const float* __restrict__ src, u16* __restrict__ dst, int c, int t){
  size_t b4 = (size_t)c*2048 + t;
  float4 v0 = ((const float4*)src)[b4];
  float4 v1 = ((const float4*)src)[b4 + 256];
  float4 v2 = ((const float4*)src)[b4 + 512];
  float4 v3 = ((const float4*)src)[b4 + 768];
  float4 v4 = ((const float4*)src)[b4 + 1024];
  float4 v5 = ((const float4*)src)[b4 + 1280];
  float4 v6 = ((const float4*)src)[b4 + 1536];
  float4 v7 = ((const float4*)src)[b4 + 1792];
  ((uint2*)dst)[b4]        = cvt4(v0);
  ((uint2*)dst)[b4 + 256]  = cvt4(v1);
  ((uint2*)dst)[b4 + 512]  = cvt4(v2);
  ((uint2*)dst)[b4 + 768]  = cvt4(v3);
  ((uint2*)dst)[b4 + 1024] = cvt4(v4);
  ((uint2*)dst)[b4 + 1280] = cvt4(v5);
  ((uint2*)dst)[b4 + 1536] = cvt4(v6);
  ((uint2*)dst)[b4 + 1792] = cvt4(v7);
}
__device__ __forceinline__ void zero_chunk8k(float* dst, int c, int t){
  size_t b4 = (size_t)c*2048 + t;
  #pragma unroll
  for (int i = 0; i < 8; ++i)
    ((float4*)dst)[b4 + i*256] = make_float4(0.f,0.f,0.f,0.f);
}

// async 16B global -> LDS (wave-uniform LDS base + lane*16)
__device__ __forceinline__ void gl16(const void* g, void* l){
  __builtin_amdgcn_global_load_lds(
      (const __attribute__((address_space(1))) unsigned int*)g,
      (__attribute__((address_space(3))) unsigned int*)l, 16, 0, 0);
}

__device__ __forceinline__ int token_adapter(int n, const int* seq_lens, const int* widx){
  int cum = 0;
  #pragma unroll
  for (int s = 0; s < NSEQ; ++s){ cum += seq_lens[s]; if (n < cum) return widx[s]; }
  return widx[NSEQ-1];
}

// fallback-path zero kernel
__global__ void k_zero(float* outf, int* cnt, float* zdf){
  int t = threadIdx.x;
  if (blockIdx.x < 2048){
    int id = blockIdx.x*256 + t;
    *(float4*)&outf[(size_t)id*4] = make_float4(0.f,0.f,0.f,0.f);
  } else {
    int id = (blockIdx.x - 2048)*256 + t;
    *(float4*)&zdf[(size_t)id*4] = make_float4(0.f,0.f,0.f,0.f);
  }
  if (blockIdx.x == 0 && t < NEXP) cnt[t] = 0;
}

__global__ void k_route(const int* __restrict__ topk_ids, int* cnt, int* perm){
  int p = blockIdx.x*256 + threadIdx.x;
  if (p >= NPAIRS) return;
  int e = topk_ids[p];
  int pos = atomicAdd(&cnt[e], 1);
  perm[e*NPAIRS + pos] = p;
}

// f32 -> bf16, 4 elems/thread, coalesced (small late conversions)
__global__ void k_cvt(const float* __restrict__ src, u16* __restrict__ dst, int n4){
  int id = blockIdx.x*256 + threadIdx.x;
  if (id >= n4) return;
  ((uint2*)dst)[id] = cvt4(((const float4*)src)[id]);
}

// prep: all small conversions + zeroing, 1 launch, 8192 floats/block.
// blocks: x[0,256) gb[256,344) ub[344,432) ga[432,464) ua[464,496) db[496,528)
//         da[528,616) outfZ[616,872) zdfZ[872,888) -> grid 888
__global__ void k_prep(
    const float* __restrict__ x,  const float* __restrict__ gb, const float* __restrict__ ub,
    const float* __restrict__ ga, const float* __restrict__ ua, const float* __restrict__ db_,
    const float* __restrict__ da,
    u16* xb, u16* gbb, u16* ubb, u16* gab, u16* uab, u16* dbb, u16* dab,
    float* outf, float* zdf, int* cnt)
{
  int b = blockIdx.x, t = threadIdx.x;
  if (b == 0 && t < NEXP) cnt[t] = 0;
  if      (b < 256) cvt_chunk8k(x,   xb,  b,       t);
  else if (b < 344) cvt_chunk8k(gb,  gbb, b - 256, t);
  else if (b < 432) cvt_chunk8k(ub,  ubb, b - 344, t);
  else if (b < 464) cvt_chunk8k(ga,  gab, b - 432, t);
  else if (b < 496) cvt_chunk8k(ua,  uab, b - 464, t);
  else if (b < 528) cvt_chunk8k(db_, dbb, b - 496, t);
  else if (b < 616) cvt_chunk8k(da,  dab, b - 528, t);
  else if (b < 872) zero_chunk8k(outf, b - 616, t);
  else              zero_chunk8k(zdf,  b - 872, t);
}

// ===================== MFMA z-kernels (fast path) =====================
// zg/zu: per (expert, 64-pair tile): [64 pairs] x [64 cols: zg(0..31)|zu(32..63)], K=HIDDEN.
__global__ __launch_bounds__(256) void k_zgu_mfma(
    const u16* __restrict__ xb, const u16* __restrict__ gab, const u16* __restrict__ uab,
    const int* __restrict__ cnt, const int* __restrict__ perm,
    const int* __restrict__ widx, const int* __restrict__ seq_lens,
    const int* __restrict__ ranks, const float* __restrict__ scal,
    u16* __restrict__ zg, u16* __restrict__ zu)
{
  int e = blockIdx.y;
  int me = cnt[e];
  int tm = blockIdx.x;
  if (tm*64 >= me) return;
  int t = threadIdx.x;

  __shared__ __align__(16) u16 As[64*32];
  __shared__ __align__(16) u16 Bs[64*32];

  int r0 = t >> 2;
  int kc = ((t&3) - r0) & 3;     // swizzle: slot (t&3) holds logical chunk kc
  int ko = kc*8;
  int mg = tm*64 + r0;
  int pa = perm[e*NPAIRS + min(mg, me-1)];
  const u16* arow = xb + (size_t)(pa>>1)*HIDDEN + ko;
  int jr = r0 & 31;              // B row: r0<32 -> gate_a, else up_a
  const u16* brow = (r0 < 32 ? gab : uab)
                    + (size_t)(((jr>>4)*NEXP + e)*MAXRANK + (jr&15))*HIDDEN + ko;

  int wv = t>>6, lane = t&63;
  u16* Asw = &As[wv*512];
  u16* Bsw = &Bs[wv*512];
  int wm = wv>>1, wn = wv&1;
  int l15 = lane&15, q = lane>>4;

  f32x4 acc[2][2] = {};
  int aoff[2], boff[2];
  #pragma unroll
  for (int i=0;i<2;++i){ int row = wm*32 + i*16 + l15; aoff[i] = row*32 + ((q+row)&3)*8; }
  #pragma unroll
  for (int j=0;j<2;++j){ int row = wn*32 + j*16 + l15; boff[j] = row*32 + ((q+row)&3)*8; }

  for (int kt = 0; kt < HIDDEN/32; ++kt){
    __syncthreads();
    gl16(arow + kt*32, Asw);
    gl16(brow + kt*32, Bsw);
    __syncthreads();
    bf16x8 af[2], bfr[2];
    #pragma unroll
    for (int i=0;i<2;++i) af[i] = *(const bf16x8*)&As[aoff[i]];
    #pragma unroll
    for (int j=0;j<2;++j) bfr[j] = *(const bf16x8*)&Bs[boff[j]];
    #pragma unroll
    for (int i=0;i<2;++i)
      #pragma unroll
      for (int j=0;j<2;++j)
        acc[i][j] = __builtin_amdgcn_mfma_f32_16x16x32_bf16(af[i], bfr[j], acc[i][j],0,0,0);
  }

  u16* dstz = wn ? zu : zg;
  #pragma unroll
  for (int i=0;i<2;++i){
    #pragma unroll
    for (int r=0;r<4;++r){
      int mgo = tm*64 + wm*32 + i*16 + q*4 + r;
      if (mgo < me){
        int p = perm[e*NPAIRS + mgo];
        int a = token_adapter(p>>1, seq_lens, widx);
        int rank = ranks[a]; float sc = scal[a];
        #pragma unroll
        for (int j=0;j<2;++j){
          int jc = j*16 + l15;
          float v = ((jc>>4)==a && (jc&15)<rank) ? sc*acc[i][j][r] : 0.f;
          dstz[(size_t)p*32 + jc] = f2bf(v);
        }
      }
    }
  }
}

// zd: per (ksplit, 64-pair tile, expert), f32 atomic accumulation into zdf
__global__ __launch_bounds__(256) void k_zd_mfma(
    const u16* __restrict__ act, const u16* __restrict__ dab,
    const int* __restrict__ cnt, const int* __restrict__ perm,
    const int* __restrict__ widx, const int* __restrict__ seq_lens,
    const int* __restrict__ ranks, const float* __restrict__ scal,
    float* __restrict__ zdf)
{
  int e = blockIdx.z;
  int me = cnt[e];
  int tm = blockIdx.y;
  if (tm*64 >= me) return;
  int ks = blockIdx.x;           // 0..3
  int t = threadIdx.x;

  __shared__ __align__(16) u16 As[64*32];
  __shared__ __align__(16) u16 Bs[32*32];

  int r0 = t >> 2;
  int kc = ((t&3) - r0) & 3;
  int ko = kc*8;
  int mg = tm*64 + r0;
  int pa = perm[e*NPAIRS + min(mg, me-1)];
  const u16* arow = act + (size_t)pa*INTER + ko;
  int jr = r0 & 31;
  const u16* brow = dab + (size_t)(((jr>>4)*NEXP + e)*MAXRANK + (jr&15))*INTER + ko;

  int wv = t>>6, lane = t&63;
  u16* Asw = &As[wv*512];
  u16* Bsw = &Bs[(wv&1)*512];    // waves 0,1 stage the 32 B rows
  int l15 = lane&15, q = lane>>4;

  f32x4 acc[2] = {};
  int aoff; { int row = wv*16 + l15; aoff = row*32 + ((q+row)&3)*8; }
  int boff[2];
  #pragma unroll
  for (int j=0;j<2;++j){ int row = j*16 + l15; boff[j] = row*32 + ((q+row)&3)*8; }

  int kt0 = ks*22, kt1 = kt0 + 22;   // INTER/32 = 88 = 4*22
  for (int kt = kt0; kt < kt1; ++kt){
    __syncthreads();
    gl16(arow + kt*32, Asw);
    if (wv < 2) gl16(brow + kt*32, Bsw);
    __syncthreads();
    bf16x8 af = *(const bf16x8*)&As[aoff];
    bf16x8 b0 = *(const bf16x8*)&Bs[boff[0]];
    bf16x8 b1 = *(const bf16x8*)&Bs[boff[1]];
    acc[0] = __builtin_amdgcn_mfma_f32_16x16x32_bf16(af, b0, acc[0],0,0,0);
    acc[1] = __builtin_amdgcn_mfma_f32_16x16x32_bf16(af, b1, acc[1],0,0,0);
  }

  #pragma unroll
  for (int r=0;r<4;++r){
    int mgo = tm*64 + wv*16 + q*4 + r;
    if (mgo < me){
      int p = perm[e*NPAIRS + mgo];
      int a = token_adapter(p>>1, seq_lens, widx);
      int rank = ranks[a]; float sc = scal[a];
      #pragma unroll
      for (int j=0;j<2;++j){
        int jc = j*16 + l15;
        if ((jc>>4)==a && (jc&15)<rank)
          atomicAdd(&zdf[(size_t)p*32 + jc], sc*acc[j][r]);
      }
    }
  }
}

// ===================== fallback z-kernels (f32 weights) =====================
__global__ __launch_bounds__(256) void k_zgu(
    const float* __restrict__ x, const int* __restrict__ topk_ids,
    const float* __restrict__ gate_a, const float* __restrict__ up_a,
    const int* __restrict__ widx, const int* __restrict__ seq_lens,
    const int* __restrict__ ranks, const float* __restrict__ scal,
    u16* __restrict__ zg, u16* __restrict__ zu)
{
  int p = blockIdx.x, n = p >> 1, t = threadIdx.x;
  int e = topk_ids[p];
  __shared__ float xs[HIDDEN];
  for (int i = t; i < HIDDEN; i += 256) xs[i] = x[(size_t)n*HIDDEN + i];
  if (t < 32){ zg[p*32 + t] = 0; zu[p*32 + t] = 0; }
  __syncthreads();
  int a = token_adapter(n, seq_lens, widx);
  int rank = ranks[a];
  float scale = scal[a];
  int wv = t >> 6, lane = t & 63;
  for (int i = 0; i < 8; ++i){
    int o = wv*8 + i;
    int r = o & 15;
    const float* wrow = ((o < 16) ? gate_a : up_a) + (size_t)((a*NEXP + e)*MAXRANK + r)*HIDDEN;
    float s = 0.f;
    for (int h = lane; h < HIDDEN; h += 64) s += xs[h] * wrow[h];
    s += __shfl_down(s,32); s += __shfl_down(s,16); s += __shfl_down(s,8);
    s += __shfl_down(s,4);  s += __shfl_down(s,2);  s += __shfl_down(s,1);
    if (lane == 0 && r < rank)
      (o < 16 ? zg : zu)[p*32 + a*16 + r] = f2bf(scale * s);
  }
}

__global__ __launch_bounds__(256) void k_zd(
    const u16* __restrict__ act, const int* __restrict__ topk_ids,
    const float* __restrict__ down_a,
    const int* __restrict__ widx, const int* __restrict__ seq_lens,
    const int* __restrict__ ranks, const float* __restrict__ scal,
    u16* __restrict__ zd)
{
  int p = blockIdx.x, n = p >> 1, t = threadIdx.x;
  int e = topk_ids[p];
  __shared__ float as_[INTER];
  for (int i = t; i < INTER; i += 256) as_[i] = bf2f(act[(size_t)p*INTER + i]);
  if (t < 32) zd[p*32 + t] = 0;
  __syncthreads();
  int a = token_adapter(n, seq_lens, widx);
  int rank = ranks[a];
  float scale = scal[a];
  int wv = t >> 6, lane = t & 63;
  for (int i = 0; i < 4; ++i){
    int r = wv*4 + i;
    const float* wrow = down_a + (size_t)((a*NEXP + e)*MAXRANK + r)*INTER;
    float s = 0.f;
    for (int h = lane; h < INTER; h += 64) s += as_[h] * wrow[h];
    s += __shfl_down(s,32); s += __shfl_down(s,16); s += __shfl_down(s,8);
    s += __shfl_down(s,4);  s += __shfl_down(s,2);  s += __shfl_down(s,1);
    if (lane == 0 && r < rank) zd[p*32 + a*16 + r] = f2bf(scale * s);
  }
}

// ===================== gu GEMM: ALL-gl16 staging (B as raw f32), cvt at frag load ============
// B LDS layout: [64 rows][32 f32], 16B-slot swizzle: slot s of row r holds global half s^(r&7).
// Write-side: per-lane pre-swizzled GLOBAL address (LDS dest stays linear for gl16).
// Read-side: frag (row, f32 chunk q*8..q*8+7) = halves 2q,2q+1 at slots (2q+h)^(row&7).
// Bank math: bank = ((slot^(r&7))*4)%32 -> 8 positions x 4 banks, 2 lanes/bank = free.
__global__ __launch_bounds__(256) void k_gu_f32(
    const u16* __restrict__ xb, const float* __restrict__ wgu_f32,
    const u16* __restrict__ gbb, const u16* __restrict__ ubb,
    const u16* __restrict__ zg, const u16* __restrict__ zu,
    const int* __restrict__ cnt, const int* __restrict__ perm,
    u16* __restrict__ act)
{
  int id = blockIdx.x;
  int xcd = id & 7, s = id >> 3;
  int tm = s & 31;
  int P = (s >> 5)*8 + xcd;
  int tn = P % 44;
  int e  = P / 44;
  int me = cnt[e];
  if (tm*128 >= me) return;
  int t = threadIdx.x;

  __shared__ __align__(16) u16   As[128*32];   // 8KB bf16 A (unchanged)
  __shared__ __align__(16) float Bgf[64*32];   // 8KB f32 gate panel
  __shared__ __align__(16) float Buf[64*32];   // 8KB f32 up panel

  int wv = t>>6, lane = t&63;

  // A staging (unchanged swizzled bf16 path)
  int r0 = t >> 2;
  int kc = ((t&3) - r0) & 3;
  int ko = kc*8;
  int mg0 = tm*128 + r0, mg1 = mg0 + 64;
  int p0 = perm[e*NPAIRS + min(mg0, me-1)];
  int p1 = perm[e*NPAIRS + min(mg1, me-1)];
  const u16* arow0 = xb + (size_t)(p0>>1)*HIDDEN + ko;
  const u16* arow1 = xb + (size_t)(p1>>1)*HIDDEN + ko;
  int wvb = wv*512;
  u16* Asw0 = &As[wvb];
  u16* Asw1 = &As[2048 + wvb];

  // B f32 staging: wave wv covers chunks 2wv,2wv+1 (rows 16wv..16wv+15)
  int brA = 16*wv + (lane>>3);
  int brB = brA + 8;
  int bco = (((lane&7) ^ (lane>>3)) << 2);     // swizzled f32 col offset (16B granules)
  int jg0 = tn*64;
  const float* pg0 = wgu_f32 + ((size_t)e*NGU + jg0 + brA)*HIDDEN + bco;
  const float* pg1 = wgu_f32 + ((size_t)e*NGU + jg0 + brB)*HIDDEN + bco;
  const float* pu0 = wgu_f32 + ((size_t)e*NGU + INTER + jg0 + brA)*HIDDEN + bco;
  const float* pu1 = wgu_f32 + ((size_t)e*NGU + INTER + jg0 + brB)*HIDDEN + bco;
  float* BgD0 = &Bgf[wv*512];
  float* BgD1 = BgD0 + 256;
  float* BuD0 = &Buf[wv*512];
  float* BuD1 = BuD0 + 256;

  int wm = wv>>1, wn = wv&1;
  int l15 = lane&15, q = lane>>4;

  f32x4 accg[4][2] = {};
  f32x4 accu[4][2] = {};
  int aoff[4];
  #pragma unroll
  for (int i=0;i<4;++i){ int row = wm*64 + i*16 + l15; aoff[i] = row*32 + ((q+row)&3)*8; }
  int bo[2][2];     // [j][half] f32 index into 64x32 panel
  #pragma unroll
  for (int j=0;j<2;++j){
    int br = wn*32 + j*16 + l15;
    bo[j][0] = br*32 + (((2*q)   ^ (br&7))<<2);
    bo[j][1] = br*32 + (((2*q+1) ^ (br&7))<<2);
  }

  for (int kt = 0; kt < HIDDEN/32; ++kt){
    __syncthreads();
    gl16(arow0 + kt*32, Asw0);
    gl16(arow1 + kt*32, Asw1);
    gl16(pg0 + kt*32, BgD0);
    gl16(pg1 + kt*32, BgD1);
    gl16(pu0 + kt*32, BuD0);
    gl16(pu1 + kt*32, BuD1);
    __syncthreads();
    bf16x8 af[4], bgf[2], buf_[2];
    #pragma unroll
    for (int i=0;i<4;++i) af[i] = *(const bf16x8*)&As[aoff[i]];
    #pragma unroll
    for (int j=0;j<2;++j){
      f32x4 g0 = *(const f32x4*)&Bgf[bo[j][0]];
      f32x4 g1 = *(const f32x4*)&Bgf[bo[j][1]];
      bgf[j] = pack8v(g0, g1);
      f32x4 u0 = *(const f32x4*)&Buf[bo[j][0]];
      f32x4 u1 = *(const f32x4*)&Buf[bo[j][1]];
      buf_[j] = pack8v(u0, u1);
    }
    #pragma unroll
    for (int i=0;i<4;++i)
      #pragma unroll
      for (int j=0;j<2;++j){
        accg[i][j] = __builtin_amdgcn_mfma_f32_16x16x32_bf16(af[i], bgf[j], accg[i][j],0,0,0);
        accu[i][j] = __builtin_amdgcn_mfma_f32_16x16x32_bf16(af[i], buf_[j], accu[i][j],0,0,0);
      }
  }
  // LoRA K-extension (32 = NADAPT*MAXRANK), all-bf16 via gl16 — OLD layout in first 4KB of Bgf
  {
    int aid = kc>>1, rr = (kc&1)*8;
    int jg = tn*64 + r0;
    const u16* gB = gbb + ((size_t)(aid*NEXP+e)*INTER + jg)*MAXRANK + rr;
    const u16* uB = ubb + ((size_t)(aid*NEXP+e)*INTER + jg)*MAXRANK + rr;
    u16* BgwT = (u16*)Bgf + wvb;
    int boffT[2];
    #pragma unroll
    for (int j=0;j<2;++j){ int row = wn*32 + j*16 + l15; boffT[j] = row*32 + ((q+row)&3)*8; }
    __syncthreads();
    gl16(zg + (size_t)p0*32 + ko, Asw0);
    gl16(zg + (size_t)p1*32 + ko, Asw1);
    gl16(gB, BgwT);
    __syncthreads();
    {
      bf16x8 af[4], bgf[2];
      #pragma unroll
      for (int i=0;i<4;++i) af[i] = *(const bf16x8*)&As[aoff[i]];
      #pragma unroll
      for (int j=0;j<2;++j) bgf[j] = *(const bf16x8*)&((u16*)Bgf)[boffT[j]];
      #pragma unroll
      for (int i=0;i<4;++i)
        #pragma unroll
        for (int j=0;j<2;++j)
          accg[i][j] = __builtin_amdgcn_mfma_f32_16x16x32_bf16(af[i], bgf[j], accg[i][j],0,0,0);
    }
    __syncthreads();
    gl16(zu + (size_t)p0*32 + ko, Asw0);
    gl16(zu + (size_t)p1*32 + ko, Asw1);
    gl16(uB, BgwT);
    __syncthreads();
    {
      bf16x8 af[4], buf2[2];
      #pragma unroll
      for (int i=0;i<4;++i) af[i] = *(const bf16x8*)&As[aoff[i]];
      #pragma unroll
      for (int j=0;j<2;++j) buf2[j] = *(const bf16x8*)&((u16*)Bgf)[boffT[j]];
      #pragma unroll
      for (int i=0;i<4;++i)
        #pragma unroll
        for (int j=0;j<2;++j)
          accu[i][j] = __builtin_amdgcn_mfma_f32_16x16x32_bf16(af[i], buf2[j], accu[i][j],0,0,0);
    }
  }

  int col = l15, quad = q;
  #pragma unroll
  for (int i = 0; i < 4; ++i){
    #pragma unroll
    for (int r = 0; r < 4; ++r){
      int mg = tm*128 + wm*64 + i*16 + quad*4 + r;
      if (mg < me){
        int p = perm[e*NPAIRS + mg];
        size_t base = (size_t)p*INTER;
        #pragma unroll
        for (int j = 0; j < 2; ++j){
          int jc = tn*64 + wn*32 + j*16 + col;
          float g = accg[i][j][r], u = accu[i][j][r];
          float sg = g / (1.f + __expf(-g));
          act[base + jc] = f2bf(sg*u);
        }
      }
    }
  }
}

// ===================== down GEMM, split-K x4: ALL-gl16 staging (B as raw f32) ======
// Grid 8192. P = tn + 8*ks + 32*e; xcd=P%8, ring=(P/8)*32+tm; id=xcd+8*ring.
__global__ __launch_bounds__(256) void k_down_f32(
    const u16* __restrict__ act, const float* __restrict__ wd_f32,
    const u16* __restrict__ dbb, const u16* __restrict__ zd,
    const float* __restrict__ tw,
    const int* __restrict__ cnt, const int* __restrict__ perm,
    float* __restrict__ outf)
{
  int id = blockIdx.x;
  int xcd = id & 7, s = id >> 3;
  int tm = s & 31;
  int P = (s >> 5)*8 + xcd;
  int tn = P & 7;
  int ks = (P >> 3) & 3;
  int e  = P >> 5;
  int me = cnt[e];
  if (tm*128 >= me) return;
  int t = threadIdx.x;

  __shared__ __align__(16) u16   As[128*32];   // 8KB
  __shared__ __align__(16) float Bf[128*32];   // 16KB f32 panel (128 rows x 32 f32)

  int wv = t>>6, lane = t&63;

  int r0 = t >> 2;
  int kc = ((t&3) - r0) & 3;
  int ko = kc*8;
  int mg0 = tm*128 + r0, mg1 = mg0 + 64;
  int p0 = perm[e*NPAIRS + min(mg0, me-1)];
  int p1 = perm[e*NPAIRS + min(mg1, me-1)];
  const u16* arow0 = act + (size_t)p0*INTER + ko;
  const u16* arow1 = act + (size_t)p1*INTER + ko;
  int wvb = wv*512;
  u16* Asw0 = &As[wvb];
  u16* Asw1 = &As[2048 + wvb];

  // B f32 staging: wave wv covers chunks 4wv..4wv+3 (rows 32wv..32wv+31)
  int brA = 32*wv + (lane>>3);
  int bco = (((lane&7) ^ (lane>>3)) << 2);
  int j0base = tn*128;
  const float* pb0 = wd_f32 + ((size_t)e*HIDDEN + j0base + brA     )*INTER + bco;
  const float* pb1 = wd_f32 + ((size_t)e*HIDDEN + j0base + brA + 8 )*INTER + bco;
  const float* pb2 = wd_f32 + ((size_t)e*HIDDEN + j0base + brA + 16)*INTER + bco;
  const float* pb3 = wd_f32 + ((size_t)e*HIDDEN + j0base + brA + 24)*INTER + bco;
  float* BD0 = &Bf[wv*1024];
  float* BD1 = BD0 + 256;
  float* BD2 = BD0 + 512;
  float* BD3 = BD0 + 768;

  int wm = wv>>1, wn = wv&1;
  int l15 = lane&15, q = lane>>4;

  f32x4 acc[4][4] = {};
  int aoff[4];
  #pragma unroll
  for (int i=0;i<4;++i){ int row = wm*64 + i*16 + l15; aoff[i] = row*32 + ((q+row)&3)*8; }
  int bo[4][2];
  #pragma unroll
  for (int j=0;j<4;++j){
    int br = wn*64 + j*16 + l15;
    bo[j][0] = br*32 + (((2*q)   ^ (br&7))<<2);
    bo[j][1] = br*32 + (((2*q+1) ^ (br&7))<<2);
  }

  int kt0 = ks*22, kt1 = kt0 + 22;   // INTER/32 = 88 = 4*22
  for (int kt = kt0; kt < kt1; ++kt){
    __syncthreads();
    gl16(arow0 + kt*32, Asw0);
    gl16(arow1 + kt*32, Asw1);
    gl16(pb0 + kt*32, BD0);
    gl16(pb1 + kt*32, BD1);
    gl16(pb2 + kt*32, BD2);
    gl16(pb3 + kt*32, BD3);
    __syncthreads();
    bf16x8 af[4], bfr[4];
    #pragma unroll
    for (int i=0;i<4;++i) af[i] = *(const bf16x8*)&As[aoff[i]];
    #pragma unroll
    for (int j=0;j<4;++j){
      f32x4 b0 = *(const f32x4*)&Bf[bo[j][0]];
      f32x4 b1 = *(const f32x4*)&Bf[bo[j][1]];
      bfr[j] = pack8v(b0, b1);
    }
    #pragma unroll
    for (int i=0;i<4;++i)
      #pragma unroll
      for (int j=0;j<4;++j)
        acc[i][j] = __builtin_amdgcn_mfma_f32_16x16x32_bf16(af[i], bfr[j], acc[i][j],0,0,0);
  }
  if (ks == 3){
    int aid = kc>>1, rr = (kc&1)*8;
    int j0 = tn*128 + r0, j1 = j0 + 64;
    u16* BsT0 = (u16*)Bf + wvb;
    u16* BsT1 = (u16*)Bf + 2048 + wvb;
    int boffT[4];
    #pragma unroll
    for (int j=0;j<4;++j){ int row = wn*64 + j*16 + l15; boffT[j] = row*32 + ((q+row)&3)*8; }
    __syncthreads();
    gl16(zd + (size_t)p0*32 + ko, Asw0);
    gl16(zd + (size_t)p1*32 + ko, Asw1);
    gl16(dbb + ((size_t)(aid*NEXP+e)*HIDDEN + j0)*MAXRANK + rr, BsT0);
    gl16(dbb + ((size_t)(aid*NEXP+e)*HIDDEN + j1)*MAXRANK + rr, BsT1);
    __syncthreads();
    bf16x8 af[4], bfr[4];
    #pragma unroll
    for (int i=0;i<4;++i){ af[i] = *(const bf16x8*)&As[aoff[i]]; bfr[i] = *(const bf16x8*)&((u16*)Bf)[boffT[i]]; }
    #pragma unroll
    for (int i=0;i<4;++i)
      #pragma unroll
      for (int j=0;j<4;++j)
        acc[i][j] = __builtin_amdgcn_mfma_f32_16x16x32_bf16(af[i], bfr[j], acc[i][j],0,0,0);
  }

  int col = l15, quad = q;
  #pragma unroll
  for (int i = 0; i < 4; ++i){
    #pragma unroll
    for (int r = 0; r < 4; ++r){
      int mg = tm*128 + wm*64 + i*16 + quad*4 + r;
      if (mg < me){
        int p = perm[e*NPAIRS + mg];
        float wp = tw[p];
        size_t base = (size_t)(p >> 1)*HIDDEN;
        #pragma unroll
        for (int j = 0; j < 4; ++j){
          int jc = tn*128 + wn*64 + j*16 + col;
          atomicAdd(&outf[base + jc], wp * acc[i][j][r]);
        }
      }
    }
  }
}

// ===================== FALLBACK PATH GEMMs (f32 weights, verified) =====================
__global__ __launch_bounds__(256) void k_gufused(
    const float* __restrict__ x, const float* __restrict__ wgu,
    const float* __restrict__ gate_b, const float* __restrict__ up_b,
    const u16* __restrict__ zg, const u16* __restrict__ zu,
    const int* __restrict__ cnt, const int* __restrict__ perm,
    u16* __restrict__ act)
{
  int e = blockIdx.z;
  int me = cnt[e];
  int tm = blockIdx.y;
  if (tm*128 >= me) return;
  int tn = blockIdx.x;
  int t = threadIdx.x;

  __shared__ __align__(16) u16 As[128*32];
  __shared__ __align__(16) u16 Bg[64*32];
  __shared__ __align__(16) u16 Bu[64*32];

  int r0 = t >> 2, cc = t & 3;
  int mg0 = tm*128 + r0, mg1 = mg0 + 64;
  int p0 = perm[e*NPAIRS + min(mg0, me-1)];
  int p1 = perm[e*NPAIRS + min(mg1, me-1)];
  const float* arow0 = x + (size_t)(p0 >> 1)*HIDDEN;
  const float* arow1 = x + (size_t)(p1 >> 1)*HIDDEN;
  int jg = tn*64 + r0;
  const float* browg = wgu + ((size_t)e*NGU + jg)*HIDDEN;
  const float* browu = wgu + ((size_t)e*NGU + INTER + jg)*HIDDEN;

  int wv = t >> 6, lane = t & 63;
  int wm = wv >> 1, wn = wv & 1;

  f32x4 accg[4][2] = {};
  f32x4 accu[4][2] = {};
  int aoff[4], boff[2];
  #pragma unroll
  for (int i = 0; i < 4; ++i) aoff[i] = (wm*64 + i*16 + (lane&15))*32 + (lane>>4)*8;
  #pragma unroll
  for (int j = 0; j < 2; ++j) boff[j] = (wn*32 + j*16 + (lane&15))*32 + (lane>>4)*8;

  for (int kt = 0; kt < HIDDEN/32; ++kt){
    uint4 a0 = cvt8(arow0 + kt*32 + cc*8);
    uint4 a1 = cvt8(arow1 + kt*32 + cc*8);
    uint4 bg = cvt8(browg + kt*32 + cc*8);
    uint4 bu = cvt8(browu + kt*32 + cc*8);
    __syncthreads();
    *(uint4*)&As[r0*32 + cc*8]      = a0;
    *(uint4*)&As[(r0+64)*32 + cc*8] = a1;
    *(uint4*)&Bg[r0*32 + cc*8]      = bg;
    *(uint4*)&Bu[r0*32 + cc*8]      = bu;
    __syncthreads();
    bf16x8 af[4], bgf[2], buf[2];
    #pragma unroll
    for (int i = 0; i < 4; ++i) af[i] = *(const bf16x8*)&As[aoff[i]];
    #pragma unroll
    for (int j = 0; j < 2; ++j){ bgf[j] = *(const bf16x8*)&Bg[boff[j]]; buf[j] = *(const bf16x8*)&Bu[boff[j]]; }
    #pragma unroll
    for (int i = 0; i < 4; ++i)
      #pragma unroll
      for (int j = 0; j < 2; ++j){
        accg[i][j] = __builtin_amdgcn_mfma_f32_16x16x32_bf16(af[i], bgf[j], accg[i][j], 0, 0, 0);
        accu[i][j] = __builtin_amdgcn_mfma_f32_16x16x32_bf16(af[i], buf[j], accu[i][j], 0, 0, 0);
      }
  }
  {
    uint4 a0 = *(const uint4*)(zg + (size_t)p0*32 + cc*8);
    uint4 a1 = *(const uint4*)(zg + (size_t)p1*32 + cc*8);
    int aid = cc >> 1, rr = (cc & 1)*8;
    uint4 bg = cvt8(gate_b + ((size_t)(aid*NEXP + e)*INTER + jg)*MAXRANK + rr);
    __syncthreads();
    *(uint4*)&As[r0*32 + cc*8]      = a0;
    *(uint4*)&As[(r0+64)*32 + cc*8] = a1;
    *(uint4*)&Bg[r0*32 + cc*8]      = bg;
    __syncthreads();
    bf16x8 af[4], bgf[2];
    #pragma unroll
    for (int i = 0; i < 4; ++i) af[i] = *(const bf16x8*)&As[aoff[i]];
    #pragma unroll
    for (int j = 0; j < 2; ++j) bgf[j] = *(const bf16x8*)&Bg[boff[j]];
    #pragma unroll
    for (int i = 0; i < 4; ++i)
      #pragma unroll
      for (int j = 0; j < 2; ++j)
        accg[i][j] = __builtin_amdgcn_mfma_f32_16x16x32_bf16(af[i], bgf[j], accg[i][j], 0, 0, 0);
  }
  {
    uint4 a0 = *(const uint4*)(zu + (size_t)p0*32 + cc*8);
    uint4 a1 = *(const uint4*)(zu + (size_t)p1*32 + cc*8);
    int aid = cc >> 1, rr = (cc & 1)*8;
    uint4 bu = cvt8(up_b + ((size_t)(aid*NEXP + e)*INTER + jg)*MAXRANK + rr);
    __syncthreads();
    *(uint4*)&As[r0*32 + cc*8]      = a0;
    *(uint4*)&As[(r0+64)*32 + cc*8] = a1;
    *(uint4*)&Bg[r0*32 + cc*8]      = bu;
    __syncthreads();
    bf16x8 af[4], buf[2];
    #pragma unroll
    for (int i = 0; i < 4; ++i) af[i] = *(const bf16x8*)&As[aoff[i]];
    #pragma unroll
    for (int j = 0; j < 2; ++j) buf[j] = *(const bf16x8*)&Bg[boff[j]];
    #pragma unroll
    for (int i = 0; i < 4; ++i)
      #pragma unroll
      for (int j = 0; j < 2; ++j)
        accu[i][j] = __builtin_amdgcn_mfma_f32_16x16x32_bf16(af[i], buf[j], accu[i][j], 0, 0, 0);
  }
  int col = lane & 15, quad = lane >> 4;
  #pragma unroll
  for (int i = 0; i < 4; ++i){
    #pragma unroll
    for (int r = 0; r < 4; ++r){
      int mg = tm*128 + wm*64 + i*16 + quad*4 + r;
      if (mg < me){
        int p = perm[e*NPAIRS + mg];
        size_t base = (size_t)p*INTER;
        #pragma unroll
        for (int j = 0; j < 2; ++j){
          int jc = tn*64 + wn*32 + j*16 + col;
          float g = accg[i][j][r], u = accu[i][j][r];
          float s = g / (1.f + __expf(-g));
          act[base + jc] = f2bf(s*u);
        }
      }
    }
  }
}

__global__ __launch_bounds__(256) void k_gemm_down(
    const u16* __restrict__ act, const float* __restrict__ wd,
    const float* __restrict__ down_b, const u16* __restrict__ zd,
    const float* __restrict__ tw,
    const int* __restrict__ cnt, const int* __restrict__ perm,
    float* __restrict__ outf)
{
  int e = blockIdx.z;
  int me = cnt[e];
  int tm = blockIdx.y;
  if (tm*128 >= me) return;
  int tn = blockIdx.x;
  int t = threadIdx.x;

  __shared__ __align__(16) u16 As[128*32];
  __shared__ __align__(16) u16 Bs[128*32];

  int r0 = t >> 2, cc = t & 3;
  int mg0 = tm*128 + r0, mg1 = mg0 + 64;
  int p0 = perm[e*NPAIRS + min(mg0, me-1)];
  int p1 = perm[e*NPAIRS + min(mg1, me-1)];
  const u16* arow0 = act + (size_t)p0*INTER;
  const u16* arow1 = act + (size_t)p1*INTER;
  int j0 = tn*128 + r0, j1 = j0 + 64;
  const float* brow0 = wd + ((size_t)e*HIDDEN + j0)*INTER;
  const float* brow1 = wd + ((size_t)e*HIDDEN + j1)*INTER;

  int wv = t >> 6, lane = t & 63;
  int wm = wv >> 1, wn = wv & 1;

  f32x4 acc[4][4] = {};
  int aoff[4], boff[4];
  #pragma unroll
  for (int i = 0; i < 4; ++i){
    aoff[i] = (wm*64 + i*16 + (lane&15))*32 + (lane>>4)*8;
    boff[i] = (wn*64 + i*16 + (lane&15))*32 + (lane>>4)*8;
  }

  auto compute = [&](){
    bf16x8 af[4], bfr[4];
    #pragma unroll
    for (int i = 0; i < 4; ++i){
      af[i]  = *(const bf16x8*)&As[aoff[i]];
      bfr[i] = *(const bf16x8*)&Bs[boff[i]];
    }
    #pragma unroll
    for (int i = 0; i < 4; ++i)
      #pragma unroll
      for (int j = 0; j < 4; ++j)
        acc[i][j] = __builtin_amdgcn_mfma_f32_16x16x32_bf16(af[i], bfr[j], acc[i][j], 0, 0, 0);
  };

  for (int kt = 0; kt < INTER/32; ++kt){
    uint4 a0 = *(const uint4*)(arow0 + kt*32 + cc*8);
    uint4 a1 = *(const uint4*)(arow1 + kt*32 + cc*8);
    uint4 b0 = cvt8(brow0 + kt*32 + cc*8);
    uint4 b1 = cvt8(brow1 + kt*32 + cc*8);
    __syncthreads();
    *(uint4*)&As[r0*32 + cc*8]      = a0;
    *(uint4*)&As[(r0+64)*32 + cc*8] = a1;
    *(uint4*)&Bs[r0*32 + cc*8]      = b0;
    *(uint4*)&Bs[(r0+64)*32 + cc*8] = b1;
    __syncthreads();
    compute();
  }
  {
    uint4 a0 = *(const uint4*)(zd + (size_t)p0*32 + cc*8);
    uint4 a1 = *(const uint4*)(zd + (size_t)p1*32 + cc*8);
    int aid = cc >> 1, rr = (cc & 1)*8;
    uint4 b0 = cvt8(down_b + ((size_t)(aid*NEXP + e)*HIDDEN + j0)*MAXRANK + rr);
    uint4 b1 = cvt8(down_b + ((size_t)(aid*NEXP + e)*HIDDEN + j1)*MAXRANK + rr);
    __syncthreads();
    *(uint4*)&As[r0*32 + cc*8]      = a0;
    *(uint4*)&As[(r0+64)*32 + cc*8] = a1;
    *(uint4*)&Bs[r0*32 + cc*8]      = b0;
    *(uint4*)&Bs[(r0+64)*32 + cc*8] = b1;
    __syncthreads();
    compute();
  }
  int col = lane & 15, quad = lane >> 4;
  #pragma unroll
  for (int i = 0; i < 4; ++i){
    #pragma unroll
    for (int r = 0; r < 4; ++r){
      int mg = tm*128 + wm*64 + i*16 + quad*4 + r;
      if (mg < me){
        int p = perm[e*NPAIRS + mg];
        float wp = tw[p];
        size_t base = (size_t)(p >> 1)*HIDDEN;
        #pragma unroll
        for (int j = 0; j < 4; ++j){
          int jc = tn*128 + wn*64 + j*16 + col;
          atomicAdd(&outf[base + jc], wp * acc[i][j][r]);
        }
      }
    }
  }
}

extern "C" void kernel_launch(void* const* d_in, const int* in_sizes, int n_in,
                              void* d_out, int out_size, void* d_ws, size_t ws_size,
                              hipStream_t stream){
  const float* x        = (const float*)d_in[0];
  const int*   topk_ids = (const int*)d_in[1];
  const float* tw       = (const float*)d_in[2];
  const float* gate_a   = (const float*)d_in[3];
  const float* gate_b   = (const float*)d_in[4];
  const float* up_a     = (const float*)d_in[5];
  const float* up_b     = (const float*)d_in[6];
  const float* down_a   = (const float*)d_in[7];
  const float* down_b   = (const float*)d_in[8];
  const int*   widx     = (const int*)d_in[9];
  const int*   seq_lens = (const int*)d_in[10];
  const int*   ranks    = (const int*)d_in[11];
  const float* scal     = (const float*)d_in[12];
  const float* wgu      = (const float*)d_in[13];
  const float* wd       = (const float*)d_in[14];
  float* outf = (float*)d_out;
  char* ws = (char*)d_ws;

  if (ws_size >= (size_t)FAST_NEED){
    int* cnt  = (int*)(ws + F_CNT);
    int* perm = (int*)(ws + F_PERM);
    u16* zg   = (u16*)(ws + F_ZG);
    u16* zu   = (u16*)(ws + F_ZU);
    u16* zd   = (u16*)(ws + F_ZD);
    u16* xb   = (u16*)(ws + F_XBF);
    u16* act  = (u16*)(ws + F_ACT);
    u16* gbb  = (u16*)(ws + F_GB);
    u16* ubb  = (u16*)(ws + F_UB);
    u16* dbb  = (u16*)(ws + F_DB);
    u16* gab  = (u16*)(ws + F_GA_BF);
    u16* uab  = (u16*)(ws + F_UA_BF);
    float* zdf= (float*)(ws + F_ZDF);
    u16* dab  = (u16*)(ws + F_DA_BF);

    hipLaunchKernelGGL(k_prep, dim3(888), dim3(256), 0, stream,
                       x, gate_b, up_b, gate_a, up_a, down_b, down_a,
                       xb, gbb, ubb, gab, uab, dbb, dab, outf, zdf, cnt);
    hipLaunchKernelGGL(k_route, dim3(16), dim3(256), 0, stream, topk_ids, cnt, perm);
    hipLaunchKernelGGL(k_zgu_mfma, dim3(64, NEXP), dim3(256), 0, stream,
                       xb, gab, uab, cnt, perm, widx, seq_lens, ranks, scal, zg, zu);
    hipLaunchKernelGGL(k_gu_f32, dim3(44*32*NEXP), dim3(256), 0, stream,
                       xb, wgu, gbb, ubb, zg, zu, cnt, perm, act);
    hipLaunchKernelGGL(k_zd_mfma, dim3(4, 64, NEXP), dim3(256), 0, stream,
                       act, dab, cnt, perm, widx, seq_lens, ranks, scal, zdf);
    hipLaunchKernelGGL(k_cvt, dim3((NPAIRS*32/4+255)/256), dim3(256), 0, stream,
                       zdf, zd, NPAIRS*32/4);
    hipLaunchKernelGGL(k_down_f32, dim3(8*4*32*NEXP), dim3(256), 0, stream,
                       act, wd, dbb, zd, tw, cnt, perm, outf);
  } else {
    int* cnt  = (int*)(ws + B_CNT);
    int* perm = (int*)(ws + B_PERM);
    u16* zg   = (u16*)(ws + B_ZG);
    u16* zu   = (u16*)(ws + B_ZU);
    u16* zd   = (u16*)(ws + B_ZD);
    u16* act  = (u16*)(ws + B_ACT);

    hipLaunchKernelGGL(k_zero,  dim3(2048), dim3(256), 0, stream, outf, cnt, outf);
    hipLaunchKernelGGL(k_route, dim3(16), dim3(256), 0, stream, topk_ids, cnt, perm);
    hipLaunchKernelGGL(k_zgu,   dim3(NPAIRS), dim3(256), 0, stream,
                       x, topk_ids, gate_a, up_a, widx, seq_lens, ranks, scal, zg, zu);
    hipLaunchKernelGGL(k_gufused, dim3(INTER/64, 32, NEXP), dim3(256), 0, stream,
                       x, wgu, gate_b, up_b, zg, zu, cnt, perm, act);
    hipLaunchKernelGGL(k_zd,    dim3(NPAIRS), dim3(256), 0, stream,
                       act, topk_ids, down_a, widx, seq_lens, ranks, scal, zd);
    hipLaunchKernelGGL(k_gemm_down, dim3(HIDDEN/128, 32, NEXP), dim3(256), 0, stream,
                       act, wd, down_b, zd, tw, cnt, perm, outf);
  }
}

// Round 9
// 622.617 us; speedup vs baseline: 1.0001x; 1.0001x over previous
//
#include <hip/hip_runtime.h>
#include <hip/hip_bf16.h>
#include <math.h>

#define N_TOK   2048
#define HIDDEN  1024
#define INTER   2816
#define NEXP    8
#define NADAPT  2
#define MAXRANK 16
#define TOPK    2
#define NSEQ    8
#define NPAIRS  (N_TOK*TOPK)     // 4096
#define NGU     (2*INTER)        // 5632

typedef unsigned short u16;
typedef __attribute__((ext_vector_type(8))) short bf16x8;
typedef __attribute__((ext_vector_type(4))) float f32x4;

// ---- FAST workspace layout (bytes), FAST_NEED = 164 MiB (unchanged) ----
#define F_CNT   0u
#define F_PERM  4096u        // 131072
#define F_ZG    139264u      // 262144
#define F_ZU    401408u      // 262144
#define F_ZD    663552u      // 262144 (ends 925696)
#define F_XBF   1048576u     // 4194304
#define F_ACT   5242880u     // 23068672
#define F_GB    28311552u    // 1441792
#define F_UB    29753344u    // 1441792
#define F_DB    31195136u    // 524288  (ends 31719424)
#define F_GA_BF 31719424u    // 524288  bf16 gate_a
#define F_UA_BF 32243712u    // 524288  bf16 up_a   (ends 32768000)
#define F_ZDF   32768000u    // 524288  f32 zd accumulator (ends 33292288)
#define F_DA_BF 33554432u    // 1441792 bf16 down_a
#define FAST_NEED 171966464u

// ---- fallback layout, ~24.1 MB ----
#define B_CNT   0u
#define B_PERM  4096u
#define B_ZG    262144u
#define B_ZU    524288u
#define B_ZD    786432u
#define B_ACT   1048576u

__device__ __forceinline__ float bf2f(u16 u){
  union { unsigned int i; float f; } v; v.i = ((unsigned int)u)<<16; return v.f;
}
__device__ __forceinline__ u16 f2bf(float f){
  union { float f; unsigned int i; } v; v.f = f;
  unsigned int i = v.i;
  return (u16)((i + 0x7fffu + ((i>>16)&1u)) >> 16);
}
__device__ __forceinline__ uint4 cvt8(const float* src){
  float4 lo = *(const float4*)src;
  float4 hi = *(const float4*)(src+4);
  uint4 r;
  r.x = (unsigned)f2bf(lo.x) | ((unsigned)f2bf(lo.y)<<16);
  r.y = (unsigned)f2bf(lo.z) | ((unsigned)f2bf(lo.w)<<16);
  r.z = (unsigned)f2bf(hi.x) | ((unsigned)f2bf(hi.y)<<16);
  r.w = (unsigned)f2bf(hi.z) | ((unsigned)f2bf(hi.w)<<16);
  return r;
}
__device__ __forceinline__ uint2 cvt4(float4 v){
  uint2 r;
  r.x = (unsigned)f2bf(v.x) | ((unsigned)f2bf(v.y)<<16);
  r.y = (unsigned)f2bf(v.z) | ((unsigned)f2bf(v.w)<<16);
  return r;
}

// HW packed f32->bf16 (gfx950 v_cvt_pk_bf16_f32) — weight-staging fast path only
__device__ __forceinline__ unsigned cvtpk(float a, float b){
  unsigned r;
  asm("v_cvt_pk_bf16_f32 %0, %1, %2" : "=v"(r) : "v"(a), "v"(b));
  return r;
}
__device__ __forceinline__ bf16x8 pack8v(f32x4 a, f32x4 b){
  union { uint4 u; bf16x8 h; } v;
  v.u.x = cvtpk(a[0], a[1]);
  v.u.y = cvtpk(a[2], a[3]);
  v.u.z = cvtpk(b[0], b[1]);
  v.u.w = cvtpk(b[2], b[3]);
  return v.h;
}

// convert one 8192-float chunk c: loads first (8 in flight), then stores
__device__ __forceinline__ void cvt_chunk8k(const float* __restrict__ src, u16* __restrict__ dst, int c, int t){
  size_t b4 = (size_t)c*2048 + t;
  float4 v0 = ((const float4*)src)[b4];
  float4 v1 = ((const float4*)src)[b4 + 256];
  float4 v2 = ((const float4*)src)[b4 + 512];
  float4 v3 = ((const float4*)src)[b4 + 768];
  float4 v4 = ((const float4*)src)[b4 + 1024];
  float4 v5 = ((const float4*)src)[b4 + 1280];
  float4 v6 = ((const float4*)src)[b4 + 1536];
  float4 v7 = ((const float4*)src)[b4 + 1792];
  ((uint2*)dst)[b4]        = cvt4(v0);
  ((uint2*)dst)[b4 + 256]  = cvt4(v1);
  ((uint2*)dst)[b4 + 512]  = cvt4(v2);
  ((uint2*)dst)[b4 + 768]  = cvt4(v3);
  ((uint2*)dst)[b4 + 1024] = cvt4(v4);
  ((uint2*)dst)[b4 + 1280] = cvt4(v5);
  ((uint2*)dst)[b4 + 1536] = cvt4(v6);
  ((uint2*)dst)[b4 + 1792] = cvt4(v7);
}
__device__ __forceinline__ void zero_chunk8k(float* dst, int c, int t){
  size_t b4 = (size_t)c*2048 + t;
  #pragma unroll
  for (int i = 0; i < 8; ++i)
    ((float4*)dst)[b4 + i*256] = make_float4(0.f,0.f,0.f,0.f);
}

// async 16B global -> LDS (wave-uniform LDS base + lane*16)
__device__ __forceinline__ void gl16(const void* g, void* l){
  __builtin_amdgcn_global_load_lds(
      (const __attribute__((address_space(1))) unsigned int*)g,
      (__attribute__((address_space(3))) unsigned int*)l, 16, 0, 0);
}

__device__ __forceinline__ int token_adapter(int n, const int* seq_lens, const int* widx){
  int cum = 0;
  #pragma unroll
  for (int s = 0; s < NSEQ; ++s){ cum += seq_lens[s]; if (n < cum) return widx[s]; }
  return widx[NSEQ-1];
}

// fallback-path zero kernel
__global__ void k_zero(float* outf, int* cnt, float* zdf){
  int t = threadIdx.x;
  if (blockIdx.x < 2048){
    int id = blockIdx.x*256 + t;
    *(float4*)&outf[(size_t)id*4] = make_float4(0.f,0.f,0.f,0.f);
  } else {
    int id = (blockIdx.x - 2048)*256 + t;
    *(float4*)&zdf[(size_t)id*4] = make_float4(0.f,0.f,0.f,0.f);
  }
  if (blockIdx.x == 0 && t < NEXP) cnt[t] = 0;
}

__global__ void k_route(const int* __restrict__ topk_ids, int* cnt, int* perm){
  int p = blockIdx.x*256 + threadIdx.x;
  if (p >= NPAIRS) return;
  int e = topk_ids[p];
  int pos = atomicAdd(&cnt[e], 1);
  perm[e*NPAIRS + pos] = p;
}

// f32 -> bf16, 4 elems/thread, coalesced (small late conversions)
__global__ void k_cvt(const float* __restrict__ src, u16* __restrict__ dst, int n4){
  int id = blockIdx.x*256 + threadIdx.x;
  if (id >= n4) return;
  ((uint2*)dst)[id] = cvt4(((const float4*)src)[id]);
}

// prep: all small conversions + zeroing, 1 launch, 8192 floats/block.
// blocks: x[0,256) gb[256,344) ub[344,432) ga[432,464) ua[464,496) db[496,528)
//         da[528,616) outfZ[616,872) zdfZ[872,888) -> grid 888
__global__ void k_prep(
    const float* __restrict__ x,  const float* __restrict__ gb, const float* __restrict__ ub,
    const float* __restrict__ ga, const float* __restrict__ ua, const float* __restrict__ db_,
    const float* __restrict__ da,
    u16* xb, u16* gbb, u16* ubb, u16* gab, u16* uab, u16* dbb, u16* dab,
    float* outf, float* zdf, int* cnt)
{
  int b = blockIdx.x, t = threadIdx.x;
  if (b == 0 && t < NEXP) cnt[t] = 0;
  if      (b < 256) cvt_chunk8k(x,   xb,  b,       t);
  else if (b < 344) cvt_chunk8k(gb,  gbb, b - 256, t);
  else if (b < 432) cvt_chunk8k(ub,  ubb, b - 344, t);
  else if (b < 464) cvt_chunk8k(ga,  gab, b - 432, t);
  else if (b < 496) cvt_chunk8k(ua,  uab, b - 464, t);
  else if (b < 528) cvt_chunk8k(db_, dbb, b - 496, t);
  else if (b < 616) cvt_chunk8k(da,  dab, b - 528, t);
  else if (b < 872) zero_chunk8k(outf, b - 616, t);
  else              zero_chunk8k(zdf,  b - 872, t);
}

// ===================== MFMA z-kernels (fast path, verified, unchanged) =====================
__global__ __launch_bounds__(256) void k_zgu_mfma(
    const u16* __restrict__ xb, const u16* __restrict__ gab, const u16* __restrict__ uab,
    const int* __restrict__ cnt, const int* __restrict__ perm,
    const int* __restrict__ widx, const int* __restrict__ seq_lens,
    const int* __restrict__ ranks, const float* __restrict__ scal,
    u16* __restrict__ zg, u16* __restrict__ zu)
{
  int e = blockIdx.y;
  int me = cnt[e];
  int tm = blockIdx.x;
  if (tm*64 >= me) return;
  int t = threadIdx.x;

  __shared__ __align__(16) u16 As[64*32];
  __shared__ __align__(16) u16 Bs[64*32];

  int r0 = t >> 2;
  int kc = ((t&3) - r0) & 3;
  int ko = kc*8;
  int mg = tm*64 + r0;
  int pa = perm[e*NPAIRS + min(mg, me-1)];
  const u16* arow = xb + (size_t)(pa>>1)*HIDDEN + ko;
  int jr = r0 & 31;
  const u16* brow = (r0 < 32 ? gab : uab)
                    + (size_t)(((jr>>4)*NEXP + e)*MAXRANK + (jr&15))*HIDDEN + ko;

  int wv = t>>6, lane = t&63;
  u16* Asw = &As[wv*512];
  u16* Bsw = &Bs[wv*512];
  int wm = wv>>1, wn = wv&1;
  int l15 = lane&15, q = lane>>4;

  f32x4 acc[2][2] = {};
  int aoff[2], boff[2];
  #pragma unroll
  for (int i=0;i<2;++i){ int row = wm*32 + i*16 + l15; aoff[i] = row*32 + ((q+row)&3)*8; }
  #pragma unroll
  for (int j=0;j<2;++j){ int row = wn*32 + j*16 + l15; boff[j] = row*32 + ((q+row)&3)*8; }

  for (int kt = 0; kt < HIDDEN/32; ++kt){
    __syncthreads();
    gl16(arow + kt*32, Asw);
    gl16(brow + kt*32, Bsw);
    __syncthreads();
    bf16x8 af[2], bfr[2];
    #pragma unroll
    for (int i=0;i<2;++i) af[i] = *(const bf16x8*)&As[aoff[i]];
    #pragma unroll
    for (int j=0;j<2;++j) bfr[j] = *(const bf16x8*)&Bs[boff[j]];
    #pragma unroll
    for (int i=0;i<2;++i)
      #pragma unroll
      for (int j=0;j<2;++j)
        acc[i][j] = __builtin_amdgcn_mfma_f32_16x16x32_bf16(af[i], bfr[j], acc[i][j],0,0,0);
  }

  u16* dstz = wn ? zu : zg;
  #pragma unroll
  for (int i=0;i<2;++i){
    #pragma unroll
    for (int r=0;r<4;++r){
      int mgo = tm*64 + wm*32 + i*16 + q*4 + r;
      if (mgo < me){
        int p = perm[e*NPAIRS + mgo];
        int a = token_adapter(p>>1, seq_lens, widx);
        int rank = ranks[a]; float sc = scal[a];
        #pragma unroll
        for (int j=0;j<2;++j){
          int jc = j*16 + l15;
          float v = ((jc>>4)==a && (jc&15)<rank) ? sc*acc[i][j][r] : 0.f;
          dstz[(size_t)p*32 + jc] = f2bf(v);
        }
      }
    }
  }
}

__global__ __launch_bounds__(256) void k_zd_mfma(
    const u16* __restrict__ act, const u16* __restrict__ dab,
    const int* __restrict__ cnt, const int* __restrict__ perm,
    const int* __restrict__ widx, const int* __restrict__ seq_lens,
    const int* __restrict__ ranks, const float* __restrict__ scal,
    float* __restrict__ zdf)
{
  int e = blockIdx.z;
  int me = cnt[e];
  int tm = blockIdx.y;
  if (tm*64 >= me) return;
  int ks = blockIdx.x;
  int t = threadIdx.x;

  __shared__ __align__(16) u16 As[64*32];
  __shared__ __align__(16) u16 Bs[32*32];

  int r0 = t >> 2;
  int kc = ((t&3) - r0) & 3;
  int ko = kc*8;
  int mg = tm*64 + r0;
  int pa = perm[e*NPAIRS + min(mg, me-1)];
  const u16* arow = act + (size_t)pa*INTER + ko;
  int jr = r0 & 31;
  const u16* brow = dab + (size_t)(((jr>>4)*NEXP + e)*MAXRANK + (jr&15))*INTER + ko;

  int wv = t>>6, lane = t&63;
  u16* Asw = &As[wv*512];
  u16* Bsw = &Bs[(wv&1)*512];
  int l15 = lane&15, q = lane>>4;

  f32x4 acc[2] = {};
  int aoff; { int row = wv*16 + l15; aoff = row*32 + ((q+row)&3)*8; }
  int boff[2];
  #pragma unroll
  for (int j=0;j<2;++j){ int row = j*16 + l15; boff[j] = row*32 + ((q+row)&3)*8; }

  int kt0 = ks*22, kt1 = kt0 + 22;
  for (int kt = kt0; kt < kt1; ++kt){
    __syncthreads();
    gl16(arow + kt*32, Asw);
    if (wv < 2) gl16(brow + kt*32, Bsw);
    __syncthreads();
    bf16x8 af = *(const bf16x8*)&As[aoff];
    bf16x8 b0 = *(const bf16x8*)&Bs[boff[0]];
    bf16x8 b1 = *(const bf16x8*)&Bs[boff[1]];
    acc[0] = __builtin_amdgcn_mfma_f32_16x16x32_bf16(af, b0, acc[0],0,0,0);
    acc[1] = __builtin_amdgcn_mfma_f32_16x16x32_bf16(af, b1, acc[1],0,0,0);
  }

  #pragma unroll
  for (int r=0;r<4;++r){
    int mgo = tm*64 + wv*16 + q*4 + r;
    if (mgo < me){
      int p = perm[e*NPAIRS + mgo];
      int a = token_adapter(p>>1, seq_lens, widx);
      int rank = ranks[a]; float sc = scal[a];
      #pragma unroll
      for (int j=0;j<2;++j){
        int jc = j*16 + l15;
        if ((jc>>4)==a && (jc&15)<rank)
          atomicAdd(&zdf[(size_t)p*32 + jc], sc*acc[j][r]);
      }
    }
  }
}

// ===================== fallback z-kernels (f32 weights) =====================
__global__ __launch_bounds__(256) void k_zgu(
    const float* __restrict__ x, const int* __restrict__ topk_ids,
    const float* __restrict__ gate_a, const float* __restrict__ up_a,
    const int* __restrict__ widx, const int* __restrict__ seq_lens,
    const int* __restrict__ ranks, const float* __restrict__ scal,
    u16* __restrict__ zg, u16* __restrict__ zu)
{
  int p = blockIdx.x, n = p >> 1, t = threadIdx.x;
  int e = topk_ids[p];
  __shared__ float xs[HIDDEN];
  for (int i = t; i < HIDDEN; i += 256) xs[i] = x[(size_t)n*HIDDEN + i];
  if (t < 32){ zg[p*32 + t] = 0; zu[p*32 + t] = 0; }
  __syncthreads();
  int a = token_adapter(n, seq_lens, widx);
  int rank = ranks[a];
  float scale = scal[a];
  int wv = t >> 6, lane = t & 63;
  for (int i = 0; i < 8; ++i){
    int o = wv*8 + i;
    int r = o & 15;
    const float* wrow = ((o < 16) ? gate_a : up_a) + (size_t)((a*NEXP + e)*MAXRANK + r)*HIDDEN;
    float s = 0.f;
    for (int h = lane; h < HIDDEN; h += 64) s += xs[h] * wrow[h];
    s += __shfl_down(s,32); s += __shfl_down(s,16); s += __shfl_down(s,8);
    s += __shfl_down(s,4);  s += __shfl_down(s,2);  s += __shfl_down(s,1);
    if (lane == 0 && r < rank)
      (o < 16 ? zg : zu)[p*32 + a*16 + r] = f2bf(scale * s);
  }
}

__global__ __launch_bounds__(256) void k_zd(
    const u16* __restrict__ act, const int* __restrict__ topk_ids,
    const float* __restrict__ down_a,
    const int* __restrict__ widx, const int* __restrict__ seq_lens,
    const int* __restrict__ ranks, const float* __restrict__ scal,
    u16* __restrict__ zd)
{
  int p = blockIdx.x, n = p >> 1, t = threadIdx.x;
  int e = topk_ids[p];
  __shared__ float as_[INTER];
  for (int i = t; i < INTER; i += 256) as_[i] = bf2f(act[(size_t)p*INTER + i]);
  if (t < 32) zd[p*32 + t] = 0;
  __syncthreads();
  int a = token_adapter(n, seq_lens, widx);
  int rank = ranks[a];
  float scale = scal[a];
  int wv = t >> 6, lane = t & 63;
  for (int i = 0; i < 4; ++i){
    int r = wv*4 + i;
    const float* wrow = down_a + (size_t)((a*NEXP + e)*MAXRANK + r)*INTER;
    float s = 0.f;
    for (int h = lane; h < INTER; h += 64) s += as_[h] * wrow[h];
    s += __shfl_down(s,32); s += __shfl_down(s,16); s += __shfl_down(s,8);
    s += __shfl_down(s,4);  s += __shfl_down(s,2);  s += __shfl_down(s,1);
    if (lane == 0 && r < rank) zd[p*32 + a*16 + r] = f2bf(scale * s);
  }
}

// ===================== gu GEMM: BK=64, all-gl16, f32 B, cvt at frag load ============
// A LDS [128 rows][64 bf16] (128B rows): slot s (16B) of row r holds global chunk s^(r&7).
// B LDS [64 rows][64 f32]  (256B rows): slot s (16B) of row r holds global chunk s^(r&15).
// Write-side: pre-swizzled per-lane GLOBAL address, linear LDS dest (gl16 requirement).
// 16 main iterations (HIDDEN/64), 12 gl16/wave per iteration, 32 MFMA per iteration.
__global__ __launch_bounds__(256) void k_gu_f32(
    const u16* __restrict__ xb, const float* __restrict__ wgu_f32,
    const u16* __restrict__ gbb, const u16* __restrict__ ubb,
    const u16* __restrict__ zg, const u16* __restrict__ zu,
    const int* __restrict__ cnt, const int* __restrict__ perm,
    u16* __restrict__ act)
{
  int id = blockIdx.x;
  int xcd = id & 7, s = id >> 3;
  int tm = s & 31;
  int P = (s >> 5)*8 + xcd;
  int tn = P % 44;
  int e  = P / 44;
  int me = cnt[e];
  if (tm*128 >= me) return;
  int t = threadIdx.x;

  __shared__ __align__(16) u16   As[128*64];   // 16KB
  __shared__ __align__(16) float Bgf[64*64];   // 16KB
  __shared__ __align__(16) float Buf[64*64];   // 16KB

  int wv = t>>6, lane = t&63;
  int wm = wv>>1, wn = wv&1;
  int l15 = lane&15, q = lane>>4;

  // ---- A staging: wave wv stages rows 32wv..32wv+31 via 4 gl16 (8 rows each)
  const u16* asrc[4];
  u16* adst[4];
  #pragma unroll
  for (int i=0;i<4;++i){
    int R = 32*wv + 8*i + (lane>>3);
    int p = perm[e*NPAIRS + min(tm*128 + R, me-1)];
    asrc[i] = xb + (size_t)(p>>1)*HIDDEN + (((lane&7) ^ (R&7))<<3);
    adst[i] = &As[(32*wv + 8*i)*64];
  }
  // ---- B staging: per panel, wave wv stages rows 16wv..16wv+15 via 4 gl16 (4 rows each)
  const float* gsrcG[4]; const float* gsrcU[4];
  float* gdstG[4]; float* gdstU[4];
  #pragma unroll
  for (int i=0;i<4;++i){
    int R = 16*wv + 4*i + (lane>>4);
    int co = (((lane&15) ^ (R&15))<<2);
    gsrcG[i] = wgu_f32 + ((size_t)e*NGU + tn*64 + R)*HIDDEN + co;
    gsrcU[i] = wgu_f32 + ((size_t)e*NGU + INTER + tn*64 + R)*HIDDEN + co;
    gdstG[i] = &Bgf[(16*wv + 4*i)*64];
    gdstU[i] = &Buf[(16*wv + 4*i)*64];
  }

  f32x4 accg[4][2] = {};
  f32x4 accu[4][2] = {};
  int arow[4], brow_[2];
  #pragma unroll
  for (int i=0;i<4;++i) arow[i] = wm*64 + i*16 + l15;
  #pragma unroll
  for (int j=0;j<2;++j) brow_[j] = wn*32 + j*16 + l15;

  for (int kt = 0; kt < HIDDEN/64; ++kt){
    __syncthreads();
    #pragma unroll
    for (int i=0;i<4;++i) gl16(asrc[i] + kt*64, adst[i]);
    #pragma unroll
    for (int i=0;i<4;++i) gl16(gsrcG[i] + kt*64, gdstG[i]);
    #pragma unroll
    for (int i=0;i<4;++i) gl16(gsrcU[i] + kt*64, gdstU[i]);
    __syncthreads();
    #pragma unroll
    for (int kk=0;kk<2;++kk){
      bf16x8 af[4], bgf[2], buf_[2];
      #pragma unroll
      for (int i=0;i<4;++i)
        af[i] = *(const bf16x8*)&As[arow[i]*64 + (((4*kk+q) ^ (arow[i]&7))<<3)];
      #pragma unroll
      for (int j=0;j<2;++j){
        int c0 = 8*kk + 2*q;
        f32x4 g0 = *(const f32x4*)&Bgf[brow_[j]*64 + (((c0  ) ^ (brow_[j]&15))<<2)];
        f32x4 g1 = *(const f32x4*)&Bgf[brow_[j]*64 + (((c0+1) ^ (brow_[j]&15))<<2)];
        bgf[j] = pack8v(g0, g1);
        f32x4 u0 = *(const f32x4*)&Buf[brow_[j]*64 + (((c0  ) ^ (brow_[j]&15))<<2)];
        f32x4 u1 = *(const f32x4*)&Buf[brow_[j]*64 + (((c0+1) ^ (brow_[j]&15))<<2)];
        buf_[j] = pack8v(u0, u1);
      }
      #pragma unroll
      for (int i=0;i<4;++i)
        #pragma unroll
        for (int j=0;j<2;++j){
          accg[i][j] = __builtin_amdgcn_mfma_f32_16x16x32_bf16(af[i], bgf[j], accg[i][j],0,0,0);
          accu[i][j] = __builtin_amdgcn_mfma_f32_16x16x32_bf16(af[i], buf_[j], accu[i][j],0,0,0);
        }
    }
  }
  // LoRA K-extension (round-8-verified code; fits in first 8KB of As / 4KB of Bgf)
  {
    int r0 = t >> 2;
    int kc = ((t&3) - r0) & 3;
    int ko = kc*8;
    int p0 = perm[e*NPAIRS + min(tm*128 + r0, me-1)];
    int p1 = perm[e*NPAIRS + min(tm*128 + r0 + 64, me-1)];
    int wvb = wv*512;
    u16* Asw0 = &As[wvb];
    u16* Asw1 = &As[2048 + wvb];
    int jg = tn*64 + r0;
    const u16* gB = gbb + ((size_t)((kc>>1)*NEXP+e)*INTER + jg)*MAXRANK + (kc&1)*8;
    const u16* uB = ubb + ((size_t)((kc>>1)*NEXP+e)*INTER + jg)*MAXRANK + (kc&1)*8;
    u16* BgwT = (u16*)Bgf + wvb;
    int aoffT[4], boffT[2];
    #pragma unroll
    for (int i=0;i<4;++i){ int row = wm*64 + i*16 + l15; aoffT[i] = row*32 + ((q+row)&3)*8; }
    #pragma unroll
    for (int j=0;j<2;++j){ int row = wn*32 + j*16 + l15; boffT[j] = row*32 + ((q+row)&3)*8; }
    __syncthreads();
    gl16(zg + (size_t)p0*32 + ko, Asw0);
    gl16(zg + (size_t)p1*32 + ko, Asw1);
    gl16(gB, BgwT);
    __syncthreads();
    {
      bf16x8 af[4], bgf[2];
      #pragma unroll
      for (int i=0;i<4;++i) af[i] = *(const bf16x8*)&As[aoffT[i]];
      #pragma unroll
      for (int j=0;j<2;++j) bgf[j] = *(const bf16x8*)&((u16*)Bgf)[boffT[j]];
      #pragma unroll
      for (int i=0;i<4;++i)
        #pragma unroll
        for (int j=0;j<2;++j)
          accg[i][j] = __builtin_amdgcn_mfma_f32_16x16x32_bf16(af[i], bgf[j], accg[i][j],0,0,0);
    }
    __syncthreads();
    gl16(zu + (size_t)p0*32 + ko, Asw0);
    gl16(zu + (size_t)p1*32 + ko, Asw1);
    gl16(uB, BgwT);
    __syncthreads();
    {
      bf16x8 af[4], buf2[2];
      #pragma unroll
      for (int i=0;i<4;++i) af[i] = *(const bf16x8*)&As[aoffT[i]];
      #pragma unroll
      for (int j=0;j<2;++j) buf2[j] = *(const bf16x8*)&((u16*)Bgf)[boffT[j]];
      #pragma unroll
      for (int i=0;i<4;++i)
        #pragma unroll
        for (int j=0;j<2;++j)
          accu[i][j] = __builtin_amdgcn_mfma_f32_16x16x32_bf16(af[i], buf2[j], accu[i][j],0,0,0);
    }
  }

  int col = l15, quad = q;
  #pragma unroll
  for (int i = 0; i < 4; ++i){
    #pragma unroll
    for (int r = 0; r < 4; ++r){
      int mg = tm*128 + wm*64 + i*16 + quad*4 + r;
      if (mg < me){
        int p = perm[e*NPAIRS + mg];
        size_t base = (size_t)p*INTER;
        #pragma unroll
        for (int j = 0; j < 2; ++j){
          int jc = tn*64 + wn*32 + j*16 + col;
          float g = accg[i][j][r], u = accu[i][j][r];
          float sg = g / (1.f + __expf(-g));
          act[base + jc] = f2bf(sg*u);
        }
      }
    }
  }
}

// ===================== down GEMM, split-K x4: BK=64, all-gl16, f32 B ======
// Grid 8192. P = tn + 8*ks + 32*e; xcd=P%8, ring=(P/8)*32+tm; id=xcd+8*ring.
// 11 main iterations per ks (INTER/64 = 44 = 4*11), 12 gl16/wave, 32 MFMA per iteration.
__global__ __launch_bounds__(256) void k_down_f32(
    const u16* __restrict__ act, const float* __restrict__ wd_f32,
    const u16* __restrict__ dbb, const u16* __restrict__ zd,
    const float* __restrict__ tw,
    const int* __restrict__ cnt, const int* __restrict__ perm,
    float* __restrict__ outf)
{
  int id = blockIdx.x;
  int xcd = id & 7, s = id >> 3;
  int tm = s & 31;
  int P = (s >> 5)*8 + xcd;
  int tn = P & 7;
  int ks = (P >> 3) & 3;
  int e  = P >> 5;
  int me = cnt[e];
  if (tm*128 >= me) return;
  int t = threadIdx.x;

  __shared__ __align__(16) u16   As[128*64];   // 16KB
  __shared__ __align__(16) float Bf[128*64];   // 32KB

  int wv = t>>6, lane = t&63;
  int wm = wv>>1, wn = wv&1;
  int l15 = lane&15, q = lane>>4;

  // A staging: wave wv rows 32wv..32wv+31 via 4 gl16
  const u16* asrc[4];
  u16* adst[4];
  #pragma unroll
  for (int i=0;i<4;++i){
    int R = 32*wv + 8*i + (lane>>3);
    int p = perm[e*NPAIRS + min(tm*128 + R, me-1)];
    asrc[i] = act + (size_t)p*INTER + (((lane&7) ^ (R&7))<<3);
    adst[i] = &As[(32*wv + 8*i)*64];
  }
  // B staging: wave wv rows 32wv..32wv+31 via 8 gl16 (4 rows each)
  const float* bsrc[8];
  float* bdst[8];
  #pragma unroll
  for (int i=0;i<8;++i){
    int R = 32*wv + 4*i + (lane>>4);
    int co = (((lane&15) ^ (R&15))<<2);
    bsrc[i] = wd_f32 + ((size_t)e*HIDDEN + tn*128 + R)*INTER + co;
    bdst[i] = &Bf[(32*wv + 4*i)*64];
  }

  f32x4 acc[4][4] = {};
  int arow[4], brow_[4];
  #pragma unroll
  for (int i=0;i<4;++i) arow[i] = wm*64 + i*16 + l15;
  #pragma unroll
  for (int j=0;j<4;++j) brow_[j] = wn*64 + j*16 + l15;

  int kt0 = ks*11, kt1 = kt0 + 11;   // INTER/64 = 44 = 4*11
  for (int kt = kt0; kt < kt1; ++kt){
    __syncthreads();
    #pragma unroll
    for (int i=0;i<4;++i) gl16(asrc[i] + kt*64, adst[i]);
    #pragma unroll
    for (int i=0;i<8;++i) gl16(bsrc[i] + kt*64, bdst[i]);
    __syncthreads();
    #pragma unroll
    for (int kk=0;kk<2;++kk){
      bf16x8 af[4], bfr[4];
      #pragma unroll
      for (int i=0;i<4;++i)
        af[i] = *(const bf16x8*)&As[arow[i]*64 + (((4*kk+q) ^ (arow[i]&7))<<3)];
      #pragma unroll
      for (int j=0;j<4;++j){
        int c0 = 8*kk + 2*q;
        f32x4 b0 = *(const f32x4*)&Bf[brow_[j]*64 + (((c0  ) ^ (brow_[j]&15))<<2)];
        f32x4 b1 = *(const f32x4*)&Bf[brow_[j]*64 + (((c0+1) ^ (brow_[j]&15))<<2)];
        bfr[j] = pack8v(b0, b1);
      }
      #pragma unroll
      for (int i=0;i<4;++i)
        #pragma unroll
        for (int j=0;j<4;++j)
          acc[i][j] = __builtin_amdgcn_mfma_f32_16x16x32_bf16(af[i], bfr[j], acc[i][j],0,0,0);
    }
  }
  if (ks == 3){
    int r0 = t >> 2;
    int kc = ((t&3) - r0) & 3;
    int ko = kc*8;
    int p0 = perm[e*NPAIRS + min(tm*128 + r0, me-1)];
    int p1 = perm[e*NPAIRS + min(tm*128 + r0 + 64, me-1)];
    int wvb = wv*512;
    u16* Asw0 = &As[wvb];
    u16* Asw1 = &As[2048 + wvb];
    int j0 = tn*128 + r0, j1 = j0 + 64;
    u16* BsT0 = (u16*)Bf + wvb;
    u16* BsT1 = (u16*)Bf + 2048 + wvb;
    int aoffT[4], boffT[4];
    #pragma unroll
    for (int i=0;i<4;++i){ int row = wm*64 + i*16 + l15; aoffT[i] = row*32 + ((q+row)&3)*8; }
    #pragma unroll
    for (int j=0;j<4;++j){ int row = wn*64 + j*16 + l15; boffT[j] = row*32 + ((q+row)&3)*8; }
    __syncthreads();
    gl16(zd + (size_t)p0*32 + ko, Asw0);
    gl16(zd + (size_t)p1*32 + ko, Asw1);
    gl16(dbb + ((size_t)((kc>>1)*NEXP+e)*HIDDEN + j0)*MAXRANK + (kc&1)*8, BsT0);
    gl16(dbb + ((size_t)((kc>>1)*NEXP+e)*HIDDEN + j1)*MAXRANK + (kc&1)*8, BsT1);
    __syncthreads();
    bf16x8 af[4], bfr[4];
    #pragma unroll
    for (int i=0;i<4;++i){ af[i] = *(const bf16x8*)&As[aoffT[i]]; bfr[i] = *(const bf16x8*)&((u16*)Bf)[boffT[i]]; }
    #pragma unroll
    for (int i=0;i<4;++i)
      #pragma unroll
      for (int j=0;j<4;++j)
        acc[i][j] = __builtin_amdgcn_mfma_f32_16x16x32_bf16(af[i], bfr[j], acc[i][j],0,0,0);
  }

  int col = l15, quad = q;
  #pragma unroll
  for (int i = 0; i < 4; ++i){
    #pragma unroll
    for (int r = 0; r < 4; ++r){
      int mg = tm*128 + wm*64 + i*16 + quad*4 + r;
      if (mg < me){
        int p = perm[e*NPAIRS + mg];
        float wp = tw[p];
        size_t base = (size_t)(p >> 1)*HIDDEN;
        #pragma unroll
        for (int j = 0; j < 4; ++j){
          int jc = tn*128 + wn*64 + j*16 + col;
          atomicAdd(&outf[base + jc], wp * acc[i][j][r]);
        }
      }
    }
  }
}

// ===================== FALLBACK PATH GEMMs (f32 weights, verified) =====================
__global__ __launch_bounds__(256) void k_gufused(
    const float* __restrict__ x, const float* __restrict__ wgu,
    const float* __restrict__ gate_b, const float* __restrict__ up_b,
    const u16* __restrict__ zg, const u16* __restrict__ zu,
    const int* __restrict__ cnt, const int* __restrict__ perm,
    u16* __restrict__ act)
{
  int e = blockIdx.z;
  int me = cnt[e];
  int tm = blockIdx.y;
  if (tm*128 >= me) return;
  int tn = blockIdx.x;
  int t = threadIdx.x;

  __shared__ __align__(16) u16 As[128*32];
  __shared__ __align__(16) u16 Bg[64*32];
  __shared__ __align__(16) u16 Bu[64*32];

  int r0 = t >> 2, cc = t & 3;
  int mg0 = tm*128 + r0, mg1 = mg0 + 64;
  int p0 = perm[e*NPAIRS + min(mg0, me-1)];
  int p1 = perm[e*NPAIRS + min(mg1, me-1)];
  const float* arow0 = x + (size_t)(p0 >> 1)*HIDDEN;
  const float* arow1 = x + (size_t)(p1 >> 1)*HIDDEN;
  int jg = tn*64 + r0;
  const float* browg = wgu + ((size_t)e*NGU + jg)*HIDDEN;
  const float* browu = wgu + ((size_t)e*NGU + INTER + jg)*HIDDEN;

  int wv = t >> 6, lane = t & 63;
  int wm = wv >> 1, wn = wv & 1;

  f32x4 accg[4][2] = {};
  f32x4 accu[4][2] = {};
  int aoff[4], boff[2];
  #pragma unroll
  for (int i = 0; i < 4; ++i) aoff[i] = (wm*64 + i*16 + (lane&15))*32 + (lane>>4)*8;
  #pragma unroll
  for (int j = 0; j < 2; ++j) boff[j] = (wn*32 + j*16 + (lane&15))*32 + (lane>>4)*8;

  for (int kt = 0; kt < HIDDEN/32; ++kt){
    uint4 a0 = cvt8(arow0 + kt*32 + cc*8);
    uint4 a1 = cvt8(arow1 + kt*32 + cc*8);
    uint4 bg = cvt8(browg + kt*32 + cc*8);
    uint4 bu = cvt8(browu + kt*32 + cc*8);
    __syncthreads();
    *(uint4*)&As[r0*32 + cc*8]      = a0;
    *(uint4*)&As[(r0+64)*32 + cc*8] = a1;
    *(uint4*)&Bg[r0*32 + cc*8]      = bg;
    *(uint4*)&Bu[r0*32 + cc*8]      = bu;
    __syncthreads();
    bf16x8 af[4], bgf[2], buf[2];
    #pragma unroll
    for (int i = 0; i < 4; ++i) af[i] = *(const bf16x8*)&As[aoff[i]];
    #pragma unroll
    for (int j = 0; j < 2; ++j){ bgf[j] = *(const bf16x8*)&Bg[boff[j]]; buf[j] = *(const bf16x8*)&Bu[boff[j]]; }
    #pragma unroll
    for (int i = 0; i < 4; ++i)
      #pragma unroll
      for (int j = 0; j < 2; ++j){
        accg[i][j] = __builtin_amdgcn_mfma_f32_16x16x32_bf16(af[i], bgf[j], accg[i][j], 0, 0, 0);
        accu[i][j] = __builtin_amdgcn_mfma_f32_16x16x32_bf16(af[i], buf[j], accu[i][j], 0, 0, 0);
      }
  }
  {
    uint4 a0 = *(const uint4*)(zg + (size_t)p0*32 + cc*8);
    uint4 a1 = *(const uint4*)(zg + (size_t)p1*32 + cc*8);
    int aid = cc >> 1, rr = (cc & 1)*8;
    uint4 bg = cvt8(gate_b + ((size_t)(aid*NEXP + e)*INTER + jg)*MAXRANK + rr);
    __syncthreads();
    *(uint4*)&As[r0*32 + cc*8]      = a0;
    *(uint4*)&As[(r0+64)*32 + cc*8] = a1;
    *(uint4*)&Bg[r0*32 + cc*8]      = bg;
    __syncthreads();
    bf16x8 af[4], bgf[2];
    #pragma unroll
    for (int i = 0; i < 4; ++i) af[i] = *(const bf16x8*)&As[aoff[i]];
    #pragma unroll
    for (int j = 0; j < 2; ++j) bgf[j] = *(const bf16x8*)&Bg[boff[j]];
    #pragma unroll
    for (int i = 0; i < 4; ++i)
      #pragma unroll
      for (int j = 0; j < 2; ++j)
        accg[i][j] = __builtin_amdgcn_mfma_f32_16x16x32_bf16(af[i], bgf[j], accg[i][j], 0, 0, 0);
  }
  {
    uint4 a0 = *(const uint4*)(zu + (size_t)p0*32 + cc*8);
    uint4 a1 = *(const uint4*)(zu + (size_t)p1*32 + cc*8);
    int aid = cc >> 1, rr = (cc & 1)*8;
    uint4 bu = cvt8(up_b + ((size_t)(aid*NEXP + e)*INTER + jg)*MAXRANK + rr);
    __syncthreads();
    *(uint4*)&As[r0*32 + cc*8]      = a0;
    *(uint4*)&As[(r0+64)*32 + cc*8] = a1;
    *(uint4*)&Bg[r0*32 + cc*8]      = bu;
    __syncthreads();
    bf16x8 af[4], buf[2];
    #pragma unroll
    for (int i = 0; i < 4; ++i) af[i] = *(const bf16x8*)&As[aoff[i]];
    #pragma unroll
    for (int j = 0; j < 2; ++j) buf[j] = *(const bf16x8*)&Bg[boff[j]];
    #pragma unroll
    for (int i = 0; i < 4; ++i)
      #pragma unroll
      for (int j = 0; j < 2; ++j)
        accu[i][j] = __builtin_amdgcn_mfma_f32_16x16x32_bf16(af[i], buf[j], accu[i][j], 0, 0, 0);
  }
  int col = lane & 15, quad = lane >> 4;
  #pragma unroll
  for (int i = 0; i < 4; ++i){
    #pragma unroll
    for (int r = 0; r < 4; ++r){
      int mg = tm*128 + wm*64 + i*16 + quad*4 + r;
      if (mg < me){
        int p = perm[e*NPAIRS + mg];
        size_t base = (size_t)p*INTER;
        #pragma unroll
        for (int j = 0; j < 2; ++j){
          int jc = tn*64 + wn*32 + j*16 + col;
          float g = accg[i][j][r], u = accu[i][j][r];
          float s = g / (1.f + __expf(-g));
          act[base + jc] = f2bf(s*u);
        }
      }
    }
  }
}

__global__ __launch_bounds__(256) void k_gemm_down(
    const u16* __restrict__ act, const float* __restrict__ wd,
    const float* __restrict__ down_b, const u16* __restrict__ zd,
    const float* __restrict__ tw,
    const int* __restrict__ cnt, const int* __restrict__ perm,
    float* __restrict__ outf)
{
  int e = blockIdx.z;
  int me = cnt[e];
  int tm = blockIdx.y;
  if (tm*128 >= me) return;
  int tn = blockIdx.x;
  int t = threadIdx.x;

  __shared__ __align__(16) u16 As[128*32];
  __shared__ __align__(16) u16 Bs[128*32];

  int r0 = t >> 2, cc = t & 3;
  int mg0 = tm*128 + r0, mg1 = mg0 + 64;
  int p0 = perm[e*NPAIRS + min(mg0, me-1)];
  int p1 = perm[e*NPAIRS + min(mg1, me-1)];
  const u16* arow0 = act + (size_t)p0*INTER;
  const u16* arow1 = act + (size_t)p1*INTER;
  int j0 = tn*128 + r0, j1 = j0 + 64;
  const float* brow0 = wd + ((size_t)e*HIDDEN + j0)*INTER;
  const float* brow1 = wd + ((size_t)e*HIDDEN + j1)*INTER;

  int wv = t >> 6, lane = t & 63;
  int wm = wv >> 1, wn = wv & 1;

  f32x4 acc[4][4] = {};
  int aoff[4], boff[4];
  #pragma unroll
  for (int i = 0; i < 4; ++i){
    aoff[i] = (wm*64 + i*16 + (lane&15))*32 + (lane>>4)*8;
    boff[i] = (wn*64 + i*16 + (lane&15))*32 + (lane>>4)*8;
  }

  auto compute = [&](){
    bf16x8 af[4], bfr[4];
    #pragma unroll
    for (int i = 0; i < 4; ++i){
      af[i]  = *(const bf16x8*)&As[aoff[i]];
      bfr[i] = *(const bf16x8*)&Bs[boff[i]];
    }
    #pragma unroll
    for (int i = 0; i < 4; ++i)
      #pragma unroll
      for (int j = 0; j < 4; ++j)
        acc[i][j] = __builtin_amdgcn_mfma_f32_16x16x32_bf16(af[i], bfr[j], acc[i][j], 0, 0, 0);
  };

  for (int kt = 0; kt < INTER/32; ++kt){
    uint4 a0 = *(const uint4*)(arow0 + kt*32 + cc*8);
    uint4 a1 = *(const uint4*)(arow1 + kt*32 + cc*8);
    uint4 b0 = cvt8(brow0 + kt*32 + cc*8);
    uint4 b1 = cvt8(brow1 + kt*32 + cc*8);
    __syncthreads();
    *(uint4*)&As[r0*32 + cc*8]      = a0;
    *(uint4*)&As[(r0+64)*32 + cc*8] = a1;
    *(uint4*)&Bs[r0*32 + cc*8]      = b0;
    *(uint4*)&Bs[(r0+64)*32 + cc*8] = b1;
    __syncthreads();
    compute();
  }
  {
    uint4 a0 = *(const uint4*)(zd + (size_t)p0*32 + cc*8);
    uint4 a1 = *(const uint4*)(zd + (size_t)p1*32 + cc*8);
    int aid = cc >> 1, rr = (cc & 1)*8;
    uint4 b0 = cvt8(down_b + ((size_t)(aid*NEXP + e)*HIDDEN + j0)*MAXRANK + rr);
    uint4 b1 = cvt8(down_b + ((size_t)(aid*NEXP + e)*HIDDEN + j1)*MAXRANK + rr);
    __syncthreads();
    *(uint4*)&As[r0*32 + cc*8]      = a0;
    *(uint4*)&As[(r0+64)*32 + cc*8] = a1;
    *(uint4*)&Bs[r0*32 + cc*8]      = b0;
    *(uint4*)&Bs[(r0+64)*32 + cc*8] = b1;
    __syncthreads();
    compute();
  }
  int col = lane & 15, quad = lane >> 4;
  #pragma unroll
  for (int i = 0; i < 4; ++i){
    #pragma unroll
    for (int r = 0; r < 4; ++r){
      int mg = tm*128 + wm*64 + i*16 + quad*4 + r;
      if (mg < me){
        int p = perm[e*NPAIRS + mg];
        float wp = tw[p];
        size_t base = (size_t)(p >> 1)*HIDDEN;
        #pragma unroll
        for (int j = 0; j < 4; ++j){
          int jc = tn*128 + wn*64 + j*16 + col;
          atomicAdd(&outf[base + jc], wp * acc[i][j][r]);
        }
      }
    }
  }
}

extern "C" void kernel_launch(void* const* d_in, const int* in_sizes, int n_in,
                              void* d_out, int out_size, void* d_ws, size_t ws_size,
                              hipStream_t stream){
  const float* x        = (const float*)d_in[0];
  const int*   topk_ids = (const int*)d_in[1];
  const float* tw       = (const float*)d_in[2];
  const float* gate_a   = (const float*)d_in[3];
  const float* gate_b   = (const float*)d_in[4];
  const float* up_a     = (const float*)d_in[5];
  const float* up_b     = (const float*)d_in[6];
  const float* down_a   = (const float*)d_in[7];
  const float* down_b   = (const float*)d_in[8];
  const int*   widx     = (const int*)d_in[9];
  const int*   seq_lens = (const int*)d_in[10];
  const int*   ranks    = (const int*)d_in[11];
  const float* scal     = (const float*)d_in[12];
  const float* wgu      = (const float*)d_in[13];
  const float* wd       = (const float*)d_in[14];
  float* outf = (float*)d_out;
  char* ws = (char*)d_ws;

  if (ws_size >= (size_t)FAST_NEED){
    int* cnt  = (int*)(ws + F_CNT);
    int* perm = (int*)(ws + F_PERM);
    u16* zg   = (u16*)(ws + F_ZG);
    u16* zu   = (u16*)(ws + F_ZU);
    u16* zd   = (u16*)(ws + F_ZD);
    u16* xb   = (u16*)(ws + F_XBF);
    u16* act  = (u16*)(ws + F_ACT);
    u16* gbb  = (u16*)(ws + F_GB);
    u16* ubb  = (u16*)(ws + F_UB);
    u16* dbb  = (u16*)(ws + F_DB);
    u16* gab  = (u16*)(ws + F_GA_BF);
    u16* uab  = (u16*)(ws + F_UA_BF);
    float* zdf= (float*)(ws + F_ZDF);
    u16* dab  = (u16*)(ws + F_DA_BF);

    hipLaunchKernelGGL(k_prep, dim3(888), dim3(256), 0, stream,
                       x, gate_b, up_b, gate_a, up_a, down_b, down_a,
                       xb, gbb, ubb, gab, uab, dbb, dab, outf, zdf, cnt);
    hipLaunchKernelGGL(k_route, dim3(16), dim3(256), 0, stream, topk_ids, cnt, perm);
    hipLaunchKernelGGL(k_zgu_mfma, dim3(64, NEXP), dim3(256), 0, stream,
                       xb, gab, uab, cnt, perm, widx, seq_lens, ranks, scal, zg, zu);
    hipLaunchKernelGGL(k_gu_f32, dim3(44*32*NEXP), dim3(256), 0, stream,
                       xb, wgu, gbb, ubb, zg, zu, cnt, perm, act);
    hipLaunchKernelGGL(k_zd_mfma, dim3(4, 64, NEXP), dim3(256), 0, stream,
                       act, dab, cnt, perm, widx, seq_lens, ranks, scal, zdf);
    hipLaunchKernelGGL(k_cvt, dim3((NPAIRS*32/4+255)/256), dim3(256), 0, stream,
                       zdf, zd, NPAIRS*32/4);
    hipLaunchKernelGGL(k_down_f32, dim3(8*4*32*NEXP), dim3(256), 0, stream,
                       act, wd, dbb, zd, tw, cnt, perm, outf);
  } else {
    int* cnt  = (int*)(ws + B_CNT);
    int* perm = (int*)(ws + B_PERM);
    u16* zg   = (u16*)(ws + B_ZG);
    u16* zu   = (u16*)(ws + B_ZU);
    u16* zd   = (u16*)(ws + B_ZD);
    u16* act  = (u16*)(ws + B_ACT);

    hipLaunchKernelGGL(k_zero,  dim3(2048), dim3(256), 0, stream, outf, cnt, outf);
    hipLaunchKernelGGL(k_route, dim3(16), dim3(256), 0, stream, topk_ids, cnt, perm);
    hipLaunchKernelGGL(k_zgu,   dim3(NPAIRS), dim3(256), 0, stream,
                       x, topk_ids, gate_a, up_a, widx, seq_lens, ranks, scal, zg, zu);
    hipLaunchKernelGGL(k_gufused, dim3(INTER/64, 32, NEXP), dim3(256), 0, stream,
                       x, wgu, gate_b, up_b, zg, zu, cnt, perm, act);
    hipLaunchKernelGGL(k_zd,    dim3(NPAIRS), dim3(256), 0, stream,
                       act, topk_ids, down_a, widx, seq_lens, ranks, scal, zd);
    hipLaunchKernelGGL(k_gemm_down, dim3(HIDDEN/128, 32, NEXP), dim3(256), 0, stream,
                       act, wd, down_b, zd, tw, cnt, perm, outf);
  }
}

// Round 10
// 583.770 us; speedup vs baseline: 1.0667x; 1.0665x over previous
//
#include <hip/hip_runtime.h>
#include <hip/hip_bf16.h>
#include <math.h>

#define N_TOK   2048
#define HIDDEN  1024
#define INTER   2816
#define NEXP    8
#define NADAPT  2
#define MAXRANK 16
#define TOPK    2
#define NSEQ    8
#define NPAIRS  (N_TOK*TOPK)     // 4096
#define NGU     (2*INTER)        // 5632

typedef unsigned short u16;
typedef __attribute__((ext_vector_type(8))) short bf16x8;
typedef __attribute__((ext_vector_type(4))) float f32x4;

// ---- FAST workspace layout (bytes), FAST_NEED = 164 MiB (unchanged) ----
#define F_CNT   0u
#define F_PERM  4096u        // 131072
#define F_ZG    139264u      // 262144
#define F_ZU    401408u      // 262144
#define F_ZD    663552u      // 262144 (ends 925696)
#define F_XBF   1048576u     // 4194304
#define F_ACT   5242880u     // 23068672
#define F_GB    28311552u    // 1441792
#define F_UB    29753344u    // 1441792
#define F_DB    31195136u    // 524288  (ends 31719424)
#define F_GA_BF 31719424u    // 524288  bf16 gate_a
#define F_UA_BF 32243712u    // 524288  bf16 up_a   (ends 32768000)
#define F_ZDF   32768000u    // 524288  f32 zd accumulator (ends 33292288)
#define F_DA_BF 33554432u    // 1441792 bf16 down_a
#define FAST_NEED 171966464u

// ---- fallback layout, ~24.1 MB ----
#define B_CNT   0u
#define B_PERM  4096u
#define B_ZG    262144u
#define B_ZU    524288u
#define B_ZD    786432u
#define B_ACT   1048576u

__device__ __forceinline__ float bf2f(u16 u){
  union { unsigned int i; float f; } v; v.i = ((unsigned int)u)<<16; return v.f;
}
__device__ __forceinline__ u16 f2bf(float f){
  union { float f; unsigned int i; } v; v.f = f;
  unsigned int i = v.i;
  return (u16)((i + 0x7fffu + ((i>>16)&1u)) >> 16);
}
__device__ __forceinline__ uint4 cvt8(const float* src){
  float4 lo = *(const float4*)src;
  float4 hi = *(const float4*)(src+4);
  uint4 r;
  r.x = (unsigned)f2bf(lo.x) | ((unsigned)f2bf(lo.y)<<16);
  r.y = (unsigned)f2bf(lo.z) | ((unsigned)f2bf(lo.w)<<16);
  r.z = (unsigned)f2bf(hi.x) | ((unsigned)f2bf(hi.y)<<16);
  r.w = (unsigned)f2bf(hi.z) | ((unsigned)f2bf(hi.w)<<16);
  return r;
}
__device__ __forceinline__ uint2 cvt4(float4 v){
  uint2 r;
  r.x = (unsigned)f2bf(v.x) | ((unsigned)f2bf(v.y)<<16);
  r.y = (unsigned)f2bf(v.z) | ((unsigned)f2bf(v.w)<<16);
  return r;
}

// HW packed f32->bf16 (gfx950 v_cvt_pk_bf16_f32) — weight-staging fast path only
__device__ __forceinline__ unsigned cvtpk(float a, float b){
  unsigned r;
  asm("v_cvt_pk_bf16_f32 %0, %1, %2" : "=v"(r) : "v"(a), "v"(b));
  return r;
}
__device__ __forceinline__ uint4 pack8(const float* src){
  float4 lo = *(const float4*)src;
  float4 hi = *(const float4*)(src+4);
  uint4 r;
  r.x = cvtpk(lo.x, lo.y);
  r.y = cvtpk(lo.z, lo.w);
  r.z = cvtpk(hi.x, hi.y);
  r.w = cvtpk(hi.z, hi.w);
  return r;
}

// convert one 8192-float chunk c: loads first (8 in flight), then stores
__device__ __forceinline__ void cvt_chunk8k(const float* __restrict__ src, u16* __restrict__ dst, int c, int t){
  size_t b4 = (size_t)c*2048 + t;
  float4 v0 = ((const float4*)src)[b4];
  float4 v1 = ((const float4*)src)[b4 + 256];
  float4 v2 = ((const float4*)src)[b4 + 512];
  float4 v3 = ((const float4*)src)[b4 + 768];
  float4 v4 = ((const float4*)src)[b4 + 1024];
  float4 v5 = ((const float4*)src)[b4 + 1280];
  float4 v6 = ((const float4*)src)[b4 + 1536];
  float4 v7 = ((const float4*)src)[b4 + 1792];
  ((uint2*)dst)[b4]        = cvt4(v0);
  ((uint2*)dst)[b4 + 256]  = cvt4(v1);
  ((uint2*)dst)[b4 + 512]  = cvt4(v2);
  ((uint2*)dst)[b4 + 768]  = cvt4(v3);
  ((uint2*)dst)[b4 + 1024] = cvt4(v4);
  ((uint2*)dst)[b4 + 1280] = cvt4(v5);
  ((uint2*)dst)[b4 + 1536] = cvt4(v6);
  ((uint2*)dst)[b4 + 1792] = cvt4(v7);
}
__device__ __forceinline__ void zero_chunk8k(float* dst, int c, int t){
  size_t b4 = (size_t)c*2048 + t;
  #pragma unroll
  for (int i = 0; i < 8; ++i)
    ((float4*)dst)[b4 + i*256] = make_float4(0.f,0.f,0.f,0.f);
}

// async 16B global -> LDS (wave-uniform LDS base + lane*16)
__device__ __forceinline__ void gl16(const void* g, void* l){
  __builtin_amdgcn_global_load_lds(
      (const __attribute__((address_space(1))) unsigned int*)g,
      (__attribute__((address_space(3))) unsigned int*)l, 16, 0, 0);
}

__device__ __forceinline__ int token_adapter(int n, const int* seq_lens, const int* widx){
  int cum = 0;
  #pragma unroll
  for (int s = 0; s < NSEQ; ++s){ cum += seq_lens[s]; if (n < cum) return widx[s]; }
  return widx[NSEQ-1];
}

// fallback-path zero kernel
__global__ void k_zero(float* outf, int* cnt, float* zdf){
  int t = threadIdx.x;
  if (blockIdx.x < 2048){
    int id = blockIdx.x*256 + t;
    *(float4*)&outf[(size_t)id*4] = make_float4(0.f,0.f,0.f,0.f);
  } else {
    int id = (blockIdx.x - 2048)*256 + t;
    *(float4*)&zdf[(size_t)id*4] = make_float4(0.f,0.f,0.f,0.f);
  }
  if (blockIdx.x == 0 && t < NEXP) cnt[t] = 0;
}

__global__ void k_route(const int* __restrict__ topk_ids, int* cnt, int* perm){
  int p = blockIdx.x*256 + threadIdx.x;
  if (p >= NPAIRS) return;
  int e = topk_ids[p];
  int pos = atomicAdd(&cnt[e], 1);
  perm[e*NPAIRS + pos] = p;
}

// f32 -> bf16, 4 elems/thread, coalesced (small late conversions)
__global__ void k_cvt(const float* __restrict__ src, u16* __restrict__ dst, int n4){
  int id = blockIdx.x*256 + threadIdx.x;
  if (id >= n4) return;
  ((uint2*)dst)[id] = cvt4(((const float4*)src)[id]);
}

// prep: all small conversions + zeroing, 1 launch, 8192 floats/block.
// blocks: x[0,256) gb[256,344) ub[344,432) ga[432,464) ua[464,496) db[496,528)
//         da[528,616) outfZ[616,872) zdfZ[872,888) -> grid 888
__global__ void k_prep(
    const float* __restrict__ x,  const float* __restrict__ gb, const float* __restrict__ ub,
    const float* __restrict__ ga, const float* __restrict__ ua, const float* __restrict__ db_,
    const float* __restrict__ da,
    u16* xb, u16* gbb, u16* ubb, u16* gab, u16* uab, u16* dbb, u16* dab,
    float* outf, float* zdf, int* cnt)
{
  int b = blockIdx.x, t = threadIdx.x;
  if (b == 0 && t < NEXP) cnt[t] = 0;
  if      (b < 256) cvt_chunk8k(x,   xb,  b,       t);
  else if (b < 344) cvt_chunk8k(gb,  gbb, b - 256, t);
  else if (b < 432) cvt_chunk8k(ub,  ubb, b - 344, t);
  else if (b < 464) cvt_chunk8k(ga,  gab, b - 432, t);
  else if (b < 496) cvt_chunk8k(ua,  uab, b - 464, t);
  else if (b < 528) cvt_chunk8k(db_, dbb, b - 496, t);
  else if (b < 616) cvt_chunk8k(da,  dab, b - 528, t);
  else if (b < 872) zero_chunk8k(outf, b - 616, t);
  else              zero_chunk8k(zdf,  b - 872, t);
}

// ===================== MFMA z-kernels (fast path, verified, unchanged) =====================
__global__ __launch_bounds__(256) void k_zgu_mfma(
    const u16* __restrict__ xb, const u16* __restrict__ gab, const u16* __restrict__ uab,
    const int* __restrict__ cnt, const int* __restrict__ perm,
    const int* __restrict__ widx, const int* __restrict__ seq_lens,
    const int* __restrict__ ranks, const float* __restrict__ scal,
    u16* __restrict__ zg, u16* __restrict__ zu)
{
  int e = blockIdx.y;
  int me = cnt[e];
  int tm = blockIdx.x;
  if (tm*64 >= me) return;
  int t = threadIdx.x;

  __shared__ __align__(16) u16 As[64*32];
  __shared__ __align__(16) u16 Bs[64*32];

  int r0 = t >> 2;
  int kc = ((t&3) - r0) & 3;     // swizzle: slot (t&3) holds logical chunk kc
  int ko = kc*8;
  int mg = tm*64 + r0;
  int pa = perm[e*NPAIRS + min(mg, me-1)];
  const u16* arow = xb + (size_t)(pa>>1)*HIDDEN + ko;
  int jr = r0 & 31;              // B row: r0<32 -> gate_a, else up_a
  const u16* brow = (r0 < 32 ? gab : uab)
                    + (size_t)(((jr>>4)*NEXP + e)*MAXRANK + (jr&15))*HIDDEN + ko;

  int wv = t>>6, lane = t&63;
  u16* Asw = &As[wv*512];
  u16* Bsw = &Bs[wv*512];
  int wm = wv>>1, wn = wv&1;
  int l15 = lane&15, q = lane>>4;

  f32x4 acc[2][2] = {};
  int aoff[2], boff[2];
  #pragma unroll
  for (int i=0;i<2;++i){ int row = wm*32 + i*16 + l15; aoff[i] = row*32 + ((q+row)&3)*8; }
  #pragma unroll
  for (int j=0;j<2;++j){ int row = wn*32 + j*16 + l15; boff[j] = row*32 + ((q+row)&3)*8; }

  for (int kt = 0; kt < HIDDEN/32; ++kt){
    __syncthreads();
    gl16(arow + kt*32, Asw);
    gl16(brow + kt*32, Bsw);
    __syncthreads();
    bf16x8 af[2], bfr[2];
    #pragma unroll
    for (int i=0;i<2;++i) af[i] = *(const bf16x8*)&As[aoff[i]];
    #pragma unroll
    for (int j=0;j<2;++j) bfr[j] = *(const bf16x8*)&Bs[boff[j]];
    #pragma unroll
    for (int i=0;i<2;++i)
      #pragma unroll
      for (int j=0;j<2;++j)
        acc[i][j] = __builtin_amdgcn_mfma_f32_16x16x32_bf16(af[i], bfr[j], acc[i][j],0,0,0);
  }

  u16* dstz = wn ? zu : zg;
  #pragma unroll
  for (int i=0;i<2;++i){
    #pragma unroll
    for (int r=0;r<4;++r){
      int mgo = tm*64 + wm*32 + i*16 + q*4 + r;
      if (mgo < me){
        int p = perm[e*NPAIRS + mgo];
        int a = token_adapter(p>>1, seq_lens, widx);
        int rank = ranks[a]; float sc = scal[a];
        #pragma unroll
        for (int j=0;j<2;++j){
          int jc = j*16 + l15;
          float v = ((jc>>4)==a && (jc&15)<rank) ? sc*acc[i][j][r] : 0.f;
          dstz[(size_t)p*32 + jc] = f2bf(v);
        }
      }
    }
  }
}

__global__ __launch_bounds__(256) void k_zd_mfma(
    const u16* __restrict__ act, const u16* __restrict__ dab,
    const int* __restrict__ cnt, const int* __restrict__ perm,
    const int* __restrict__ widx, const int* __restrict__ seq_lens,
    const int* __restrict__ ranks, const float* __restrict__ scal,
    float* __restrict__ zdf)
{
  int e = blockIdx.z;
  int me = cnt[e];
  int tm = blockIdx.y;
  if (tm*64 >= me) return;
  int ks = blockIdx.x;           // 0..3
  int t = threadIdx.x;

  __shared__ __align__(16) u16 As[64*32];
  __shared__ __align__(16) u16 Bs[32*32];

  int r0 = t >> 2;
  int kc = ((t&3) - r0) & 3;
  int ko = kc*8;
  int mg = tm*64 + r0;
  int pa = perm[e*NPAIRS + min(mg, me-1)];
  const u16* arow = act + (size_t)pa*INTER + ko;
  int jr = r0 & 31;
  const u16* brow = dab + (size_t)(((jr>>4)*NEXP + e)*MAXRANK + (jr&15))*INTER + ko;

  int wv = t>>6, lane = t&63;
  u16* Asw = &As[wv*512];
  u16* Bsw = &Bs[(wv&1)*512];    // waves 0,1 stage the 32 B rows
  int l15 = lane&15, q = lane>>4;

  f32x4 acc[2] = {};
  int aoff; { int row = wv*16 + l15; aoff = row*32 + ((q+row)&3)*8; }
  int boff[2];
  #pragma unroll
  for (int j=0;j<2;++j){ int row = j*16 + l15; boff[j] = row*32 + ((q+row)&3)*8; }

  int kt0 = ks*22, kt1 = kt0 + 22;   // INTER/32 = 88 = 4*22
  for (int kt = kt0; kt < kt1; ++kt){
    __syncthreads();
    gl16(arow + kt*32, Asw);
    if (wv < 2) gl16(brow + kt*32, Bsw);
    __syncthreads();
    bf16x8 af = *(const bf16x8*)&As[aoff];
    bf16x8 b0 = *(const bf16x8*)&Bs[boff[0]];
    bf16x8 b1 = *(const bf16x8*)&Bs[boff[1]];
    acc[0] = __builtin_amdgcn_mfma_f32_16x16x32_bf16(af, b0, acc[0],0,0,0);
    acc[1] = __builtin_amdgcn_mfma_f32_16x16x32_bf16(af, b1, acc[1],0,0,0);
  }

  #pragma unroll
  for (int r=0;r<4;++r){
    int mgo = tm*64 + wv*16 + q*4 + r;
    if (mgo < me){
      int p = perm[e*NPAIRS + mgo];
      int a = token_adapter(p>>1, seq_lens, widx);
      int rank = ranks[a]; float sc = scal[a];
      #pragma unroll
      for (int j=0;j<2;++j){
        int jc = j*16 + l15;
        if ((jc>>4)==a && (jc&15)<rank)
          atomicAdd(&zdf[(size_t)p*32 + jc], sc*acc[j][r]);
      }
    }
  }
}

// ===================== fallback z-kernels (f32 weights) =====================
__global__ __launch_bounds__(256) void k_zgu(
    const float* __restrict__ x, const int* __restrict__ topk_ids,
    const float* __restrict__ gate_a, const float* __restrict__ up_a,
    const int* __restrict__ widx, const int* __restrict__ seq_lens,
    const int* __restrict__ ranks, const float* __restrict__ scal,
    u16* __restrict__ zg, u16* __restrict__ zu)
{
  int p = blockIdx.x, n = p >> 1, t = threadIdx.x;
  int e = topk_ids[p];
  __shared__ float xs[HIDDEN];
  for (int i = t; i < HIDDEN; i += 256) xs[i] = x[(size_t)n*HIDDEN + i];
  if (t < 32){ zg[p*32 + t] = 0; zu[p*32 + t] = 0; }
  __syncthreads();
  int a = token_adapter(n, seq_lens, widx);
  int rank = ranks[a];
  float scale = scal[a];
  int wv = t >> 6, lane = t & 63;
  for (int i = 0; i < 8; ++i){
    int o = wv*8 + i;
    int r = o & 15;
    const float* wrow = ((o < 16) ? gate_a : up_a) + (size_t)((a*NEXP + e)*MAXRANK + r)*HIDDEN;
    float s = 0.f;
    for (int h = lane; h < HIDDEN; h += 64) s += xs[h] * wrow[h];
    s += __shfl_down(s,32); s += __shfl_down(s,16); s += __shfl_down(s,8);
    s += __shfl_down(s,4);  s += __shfl_down(s,2);  s += __shfl_down(s,1);
    if (lane == 0 && r < rank)
      (o < 16 ? zg : zu)[p*32 + a*16 + r] = f2bf(scale * s);
  }
}

__global__ __launch_bounds__(256) void k_zd(
    const u16* __restrict__ act, const int* __restrict__ topk_ids,
    const float* __restrict__ down_a,
    const int* __restrict__ widx, const int* __restrict__ seq_lens,
    const int* __restrict__ ranks, const float* __restrict__ scal,
    u16* __restrict__ zd)
{
  int p = blockIdx.x, n = p >> 1, t = threadIdx.x;
  int e = topk_ids[p];
  __shared__ float as_[INTER];
  for (int i = t; i < INTER; i += 256) as_[i] = bf2f(act[(size_t)p*INTER + i]);
  if (t < 32) zd[p*32 + t] = 0;
  __syncthreads();
  int a = token_adapter(n, seq_lens, widx);
  int rank = ranks[a];
  float scale = scal[a];
  int wv = t >> 6, lane = t & 63;
  for (int i = 0; i < 4; ++i){
    int r = wv*4 + i;
    const float* wrow = down_a + (size_t)((a*NEXP + e)*MAXRANK + r)*INTER;
    float s = 0.f;
    for (int h = lane; h < INTER; h += 64) s += as_[h] * wrow[h];
    s += __shfl_down(s,32); s += __shfl_down(s,16); s += __shfl_down(s,8);
    s += __shfl_down(s,4);  s += __shfl_down(s,2);  s += __shfl_down(s,1);
    if (lane == 0 && r < rank) zd[p*32 + a*16 + r] = f2bf(scale * s);
  }
}

// ===================== gu GEMM, round-4 structure + pack8 (cvt_pk) staging ============
__global__ __launch_bounds__(256) void k_gu_f32(
    const u16* __restrict__ xb, const float* __restrict__ wgu_f32,
    const u16* __restrict__ gbb, const u16* __restrict__ ubb,
    const u16* __restrict__ zg, const u16* __restrict__ zu,
    const int* __restrict__ cnt, const int* __restrict__ perm,
    u16* __restrict__ act)
{
  int e = blockIdx.z;
  int me = cnt[e];
  int tm = blockIdx.y;
  if (tm*128 >= me) return;
  int tn = blockIdx.x;            // 0..43, 64 inter-cols each
  int t = threadIdx.x;

  __shared__ __align__(16) u16 As[128*32];
  __shared__ __align__(16) u16 Bg[64*32];
  __shared__ __align__(16) u16 Bu[64*32];

  int r0 = t >> 2;
  int kc = ((t&3) - r0) & 3;
  int ko = kc*8;
  int mg0 = tm*128 + r0, mg1 = mg0 + 64;
  int p0 = perm[e*NPAIRS + min(mg0, me-1)];
  int p1 = perm[e*NPAIRS + min(mg1, me-1)];
  const u16* arow0 = xb + (size_t)(p0>>1)*HIDDEN + ko;
  const u16* arow1 = xb + (size_t)(p1>>1)*HIDDEN + ko;
  int jg = tn*64 + r0;
  const float* browg = wgu_f32 + ((size_t)e*NGU + jg)*HIDDEN + ko;
  const float* browu = wgu_f32 + ((size_t)e*NGU + INTER + jg)*HIDDEN + ko;

  int wvb = (t>>6)*512;
  u16* Asw0 = &As[wvb];
  u16* Asw1 = &As[2048 + wvb];
  u16* Bgw  = &Bg[wvb];

  int wv = t>>6, lane = t&63;
  int wm = wv>>1, wn = wv&1;
  int l15 = lane&15, q = lane>>4;

  f32x4 accg[4][2] = {};
  f32x4 accu[4][2] = {};
  int aoff[4], boff[2];
  #pragma unroll
  for (int i=0;i<4;++i){ int row = wm*64 + i*16 + l15; aoff[i] = row*32 + ((q+row)&3)*8; }
  #pragma unroll
  for (int j=0;j<2;++j){ int row = wn*32 + j*16 + l15; boff[j] = row*32 + ((q+row)&3)*8; }

  for (int kt = 0; kt < HIDDEN/32; ++kt){
    uint4 bg = pack8(browg + kt*32);    // f32 loads + HW cvt_pk before barrier
    uint4 bu = pack8(browu + kt*32);
    __syncthreads();
    gl16(arow0 + kt*32, Asw0);
    gl16(arow1 + kt*32, Asw1);
    *(uint4*)&Bg[wvb + lane*8] = bg;   // same slot gl16 would write
    *(uint4*)&Bu[wvb + lane*8] = bu;
    __syncthreads();
    bf16x8 af[4], bgf[2], buf[2];
    #pragma unroll
    for (int i=0;i<4;++i) af[i] = *(const bf16x8*)&As[aoff[i]];
    #pragma unroll
    for (int j=0;j<2;++j){ bgf[j] = *(const bf16x8*)&Bg[boff[j]]; buf[j] = *(const bf16x8*)&Bu[boff[j]]; }
    #pragma unroll
    for (int i=0;i<4;++i)
      #pragma unroll
      for (int j=0;j<2;++j){
        accg[i][j] = __builtin_amdgcn_mfma_f32_16x16x32_bf16(af[i], bgf[j], accg[i][j],0,0,0);
        accu[i][j] = __builtin_amdgcn_mfma_f32_16x16x32_bf16(af[i], buf[j], accu[i][j],0,0,0);
      }
  }
  // LoRA K-extension (32 = NADAPT*MAXRANK), all-bf16 via gl16 (unchanged)
  {
    int aid = kc>>1, rr = (kc&1)*8;
    const u16* gB = gbb + ((size_t)(aid*NEXP+e)*INTER + jg)*MAXRANK + rr;
    const u16* uB = ubb + ((size_t)(aid*NEXP+e)*INTER + jg)*MAXRANK + rr;
    __syncthreads();
    gl16(zg + (size_t)p0*32 + ko, Asw0);
    gl16(zg + (size_t)p1*32 + ko, Asw1);
    gl16(gB, Bgw);
    __syncthreads();
    {
      bf16x8 af[4], bgf[2];
      #pragma unroll
      for (int i=0;i<4;++i) af[i] = *(const bf16x8*)&As[aoff[i]];
      #pragma unroll
      for (int j=0;j<2;++j) bgf[j] = *(const bf16x8*)&Bg[boff[j]];
      #pragma unroll
      for (int i=0;i<4;++i)
        #pragma unroll
        for (int j=0;j<2;++j)
          accg[i][j] = __builtin_amdgcn_mfma_f32_16x16x32_bf16(af[i], bgf[j], accg[i][j],0,0,0);
    }
    __syncthreads();
    gl16(zu + (size_t)p0*32 + ko, Asw0);
    gl16(zu + (size_t)p1*32 + ko, Asw1);
    gl16(uB, Bgw);
    __syncthreads();
    {
      bf16x8 af[4], buf[2];
      #pragma unroll
      for (int i=0;i<4;++i) af[i] = *(const bf16x8*)&As[aoff[i]];
      #pragma unroll
      for (int j=0;j<2;++j) buf[j] = *(const bf16x8*)&Bg[boff[j]];
      #pragma unroll
      for (int i=0;i<4;++i)
        #pragma unroll
        for (int j=0;j<2;++j)
          accu[i][j] = __builtin_amdgcn_mfma_f32_16x16x32_bf16(af[i], buf[j], accu[i][j],0,0,0);
    }
  }

  int col = l15, quad = q;
  #pragma unroll
  for (int i = 0; i < 4; ++i){
    #pragma unroll
    for (int r = 0; r < 4; ++r){
      int mg = tm*128 + wm*64 + i*16 + quad*4 + r;
      if (mg < me){
        int p = perm[e*NPAIRS + mg];
        size_t base = (size_t)p*INTER;
        #pragma unroll
        for (int j = 0; j < 2; ++j){
          int jc = tn*64 + wn*32 + j*16 + col;
          float g = accg[i][j][r], u = accu[i][j][r];
          float s = g / (1.f + __expf(-g));
          act[base + jc] = f2bf(s*u);
        }
      }
    }
  }
}

// ===================== down GEMM, round-4 structure (split-K x4) + pack8 staging ======
__global__ __launch_bounds__(256) void k_down_f32(
    const u16* __restrict__ act, const float* __restrict__ wd_f32,
    const u16* __restrict__ dbb, const u16* __restrict__ zd,
    const float* __restrict__ tw,
    const int* __restrict__ cnt, const int* __restrict__ perm,
    float* __restrict__ outf)
{
  int e = blockIdx.z;
  int me = cnt[e];
  int tm = blockIdx.y;
  if (tm*128 >= me) return;
  int tn = blockIdx.x & 7;
  int ks = blockIdx.x >> 3;       // 0..3
  int t = threadIdx.x;

  __shared__ __align__(16) u16 As[128*32];
  __shared__ __align__(16) u16 Bs[128*32];

  int r0 = t >> 2;
  int kc = ((t&3) - r0) & 3;
  int ko = kc*8;
  int mg0 = tm*128 + r0, mg1 = mg0 + 64;
  int p0 = perm[e*NPAIRS + min(mg0, me-1)];
  int p1 = perm[e*NPAIRS + min(mg1, me-1)];
  const u16* arow0 = act + (size_t)p0*INTER + ko;
  const u16* arow1 = act + (size_t)p1*INTER + ko;
  int j0 = tn*128 + r0, j1 = j0 + 64;
  const float* brow0 = wd_f32 + ((size_t)e*HIDDEN + j0)*INTER + ko;
  const float* brow1 = wd_f32 + ((size_t)e*HIDDEN + j1)*INTER + ko;

  int wvb = (t>>6)*512;
  u16* Asw0 = &As[wvb];
  u16* Asw1 = &As[2048 + wvb];
  u16* Bsw0 = &Bs[wvb];
  u16* Bsw1 = &Bs[2048 + wvb];

  int wv = t>>6, lane = t&63;
  int wm = wv>>1, wn = wv&1;
  int l15 = lane&15, q = lane>>4;

  f32x4 acc[4][4] = {};
  int aoff[4], boff[4];
  #pragma unroll
  for (int i=0;i<4;++i){ int row = wm*64 + i*16 + l15; aoff[i] = row*32 + ((q+row)&3)*8; }
  #pragma unroll
  for (int j=0;j<4;++j){ int row = wn*64 + j*16 + l15; boff[j] = row*32 + ((q+row)&3)*8; }

  auto mma = [&](){
    bf16x8 af[4], bfr[4];
    #pragma unroll
    for (int i=0;i<4;++i){ af[i] = *(const bf16x8*)&As[aoff[i]]; bfr[i] = *(const bf16x8*)&Bs[boff[i]]; }
    #pragma unroll
    for (int i=0;i<4;++i)
      #pragma unroll
      for (int j=0;j<4;++j)
        acc[i][j] = __builtin_amdgcn_mfma_f32_16x16x32_bf16(af[i], bfr[j], acc[i][j],0,0,0);
  };

  int kt0 = ks*22, kt1 = kt0 + 22;
  for (int kt = kt0; kt < kt1; ++kt){
    uint4 b0 = pack8(brow0 + kt*32);
    uint4 b1 = pack8(brow1 + kt*32);
    __syncthreads();
    gl16(arow0 + kt*32, Asw0);
    gl16(arow1 + kt*32, Asw1);
    *(uint4*)&Bs[wvb + lane*8]        = b0;
    *(uint4*)&Bs[2048 + wvb + lane*8] = b1;
    __syncthreads();
    mma();
  }
  if (ks == 3){
    int aid = kc>>1, rr = (kc&1)*8;
    __syncthreads();
    gl16(zd + (size_t)p0*32 + ko, Asw0);
    gl16(zd + (size_t)p1*32 + ko, Asw1);
    gl16(dbb + ((size_t)(aid*NEXP+e)*HIDDEN + j0)*MAXRANK + rr, Bsw0);
    gl16(dbb + ((size_t)(aid*NEXP+e)*HIDDEN + j1)*MAXRANK + rr, Bsw1);
    __syncthreads();
    mma();
  }

  int col = l15, quad = q;
  #pragma unroll
  for (int i = 0; i < 4; ++i){
    #pragma unroll
    for (int r = 0; r < 4; ++r){
      int mg = tm*128 + wm*64 + i*16 + quad*4 + r;
      if (mg < me){
        int p = perm[e*NPAIRS + mg];
        float wp = tw[p];
        size_t base = (size_t)(p >> 1)*HIDDEN;
        #pragma unroll
        for (int j = 0; j < 4; ++j){
          int jc = tn*128 + wn*64 + j*16 + col;
          atomicAdd(&outf[base + jc], wp * acc[i][j][r]);
        }
      }
    }
  }
}

// ===================== FALLBACK PATH GEMMs (f32 weights, verified) =====================
__global__ __launch_bounds__(256) void k_gufused(
    const float* __restrict__ x, const float* __restrict__ wgu,
    const float* __restrict__ gate_b, const float* __restrict__ up_b,
    const u16* __restrict__ zg, const u16* __restrict__ zu,
    const int* __restrict__ cnt, const int* __restrict__ perm,
    u16* __restrict__ act)
{
  int e = blockIdx.z;
  int me = cnt[e];
  int tm = blockIdx.y;
  if (tm*128 >= me) return;
  int tn = blockIdx.x;
  int t = threadIdx.x;

  __shared__ __align__(16) u16 As[128*32];
  __shared__ __align__(16) u16 Bg[64*32];
  __shared__ __align__(16) u16 Bu[64*32];

  int r0 = t >> 2, cc = t & 3;
  int mg0 = tm*128 + r0, mg1 = mg0 + 64;
  int p0 = perm[e*NPAIRS + min(mg0, me-1)];
  int p1 = perm[e*NPAIRS + min(mg1, me-1)];
  const float* arow0 = x + (size_t)(p0 >> 1)*HIDDEN;
  const float* arow1 = x + (size_t)(p1 >> 1)*HIDDEN;
  int jg = tn*64 + r0;
  const float* browg = wgu + ((size_t)e*NGU + jg)*HIDDEN;
  const float* browu = wgu + ((size_t)e*NGU + INTER + jg)*HIDDEN;

  int wv = t >> 6, lane = t & 63;
  int wm = wv >> 1, wn = wv & 1;

  f32x4 accg[4][2] = {};
  f32x4 accu[4][2] = {};
  int aoff[4], boff[2];
  #pragma unroll
  for (int i = 0; i < 4; ++i) aoff[i] = (wm*64 + i*16 + (lane&15))*32 + (lane>>4)*8;
  #pragma unroll
  for (int j = 0; j < 2; ++j) boff[j] = (wn*32 + j*16 + (lane&15))*32 + (lane>>4)*8;

  for (int kt = 0; kt < HIDDEN/32; ++kt){
    uint4 a0 = cvt8(arow0 + kt*32 + cc*8);
    uint4 a1 = cvt8(arow1 + kt*32 + cc*8);
    uint4 bg = cvt8(browg + kt*32 + cc*8);
    uint4 bu = cvt8(browu + kt*32 + cc*8);
    __syncthreads();
    *(uint4*)&As[r0*32 + cc*8]      = a0;
    *(uint4*)&As[(r0+64)*32 + cc*8] = a1;
    *(uint4*)&Bg[r0*32 + cc*8]      = bg;
    *(uint4*)&Bu[r0*32 + cc*8]      = bu;
    __syncthreads();
    bf16x8 af[4], bgf[2], buf[2];
    #pragma unroll
    for (int i = 0; i < 4; ++i) af[i] = *(const bf16x8*)&As[aoff[i]];
    #pragma unroll
    for (int j = 0; j < 2; ++j){ bgf[j] = *(const bf16x8*)&Bg[boff[j]]; buf[j] = *(const bf16x8*)&Bu[boff[j]]; }
    #pragma unroll
    for (int i = 0; i < 4; ++i)
      #pragma unroll
      for (int j = 0; j < 2; ++j){
        accg[i][j] = __builtin_amdgcn_mfma_f32_16x16x32_bf16(af[i], bgf[j], accg[i][j], 0, 0, 0);
        accu[i][j] = __builtin_amdgcn_mfma_f32_16x16x32_bf16(af[i], buf[j], accu[i][j], 0, 0, 0);
      }
  }
  {
    uint4 a0 = *(const uint4*)(zg + (size_t)p0*32 + cc*8);
    uint4 a1 = *(const uint4*)(zg + (size_t)p1*32 + cc*8);
    int aid = cc >> 1, rr = (cc & 1)*8;
    uint4 bg = cvt8(gate_b + ((size_t)(aid*NEXP + e)*INTER + jg)*MAXRANK + rr);
    __syncthreads();
    *(uint4*)&As[r0*32 + cc*8]      = a0;
    *(uint4*)&As[(r0+64)*32 + cc*8] = a1;
    *(uint4*)&Bg[r0*32 + cc*8]      = bg;
    __syncthreads();
    bf16x8 af[4], bgf[2];
    #pragma unroll
    for (int i = 0; i < 4; ++i) af[i] = *(const bf16x8*)&As[aoff[i]];
    #pragma unroll
    for (int j = 0; j < 2; ++j) bgf[j] = *(const bf16x8*)&Bg[boff[j]];
    #pragma unroll
    for (int i = 0; i < 4; ++i)
      #pragma unroll
      for (int j = 0; j < 2; ++j)
        accg[i][j] = __builtin_amdgcn_mfma_f32_16x16x32_bf16(af[i], bgf[j], accg[i][j], 0, 0, 0);
  }
  {
    uint4 a0 = *(const uint4*)(zu + (size_t)p0*32 + cc*8);
    uint4 a1 = *(const uint4*)(zu + (size_t)p1*32 + cc*8);
    int aid = cc >> 1, rr = (cc & 1)*8;
    uint4 bu = cvt8(up_b + ((size_t)(aid*NEXP + e)*INTER + jg)*MAXRANK + rr);
    __syncthreads();
    *(uint4*)&As[r0*32 + cc*8]      = a0;
    *(uint4*)&As[(r0+64)*32 + cc*8] = a1;
    *(uint4*)&Bg[r0*32 + cc*8]      = bu;
    __syncthreads();
    bf16x8 af[4], buf[2];
    #pragma unroll
    for (int i = 0; i < 4; ++i) af[i] = *(const bf16x8*)&As[aoff[i]];
    #pragma unroll
    for (int j = 0; j < 2; ++j) buf[j] = *(const bf16x8*)&Bg[boff[j]];
    #pragma unroll
    for (int i = 0; i < 4; ++i)
      #pragma unroll
      for (int j = 0; j < 2; ++j)
        accu[i][j] = __builtin_amdgcn_mfma_f32_16x16x32_bf16(af[i], buf[j], accu[i][j], 0, 0, 0);
  }
  int col = lane & 15, quad = lane >> 4;
  #pragma unroll
  for (int i = 0; i < 4; ++i){
    #pragma unroll
    for (int r = 0; r < 4; ++r){
      int mg = tm*128 + wm*64 + i*16 + quad*4 + r;
      if (mg < me){
        int p = perm[e*NPAIRS + mg];
        size_t base = (size_t)p*INTER;
        #pragma unroll
        for (int j = 0; j < 2; ++j){
          int jc = tn*64 + wn*32 + j*16 + col;
          float g = accg[i][j][r], u = accu[i][j][r];
          float s = g / (1.f + __expf(-g));
          act[base + jc] = f2bf(s*u);
        }
      }
    }
  }
}

__global__ __launch_bounds__(256) void k_gemm_down(
    const u16* __restrict__ act, const float* __restrict__ wd,
    const float* __restrict__ down_b, const u16* __restrict__ zd,
    const float* __restrict__ tw,
    const int* __restrict__ cnt, const int* __restrict__ perm,
    float* __restrict__ outf)
{
  int e = blockIdx.z;
  int me = cnt[e];
  int tm = blockIdx.y;
  if (tm*128 >= me) return;
  int tn = blockIdx.x;
  int t = threadIdx.x;

  __shared__ __align__(16) u16 As[128*32];
  __shared__ __align__(16) u16 Bs[128*32];

  int r0 = t >> 2, cc = t & 3;
  int mg0 = tm*128 + r0, mg1 = mg0 + 64;
  int p0 = perm[e*NPAIRS + min(mg0, me-1)];
  int p1 = perm[e*NPAIRS + min(mg1, me-1)];
  const u16* arow0 = act + (size_t)p0*INTER;
  const u16* arow1 = act + (size_t)p1*INTER;
  int j0 = tn*128 + r0, j1 = j0 + 64;
  const float* brow0 = wd + ((size_t)e*HIDDEN + j0)*INTER;
  const float* brow1 = wd + ((size_t)e*HIDDEN + j1)*INTER;

  int wv = t >> 6, lane = t & 63;
  int wm = wv >> 1, wn = wv & 1;

  f32x4 acc[4][4] = {};
  int aoff[4], boff[4];
  #pragma unroll
  for (int i = 0; i < 4; ++i){
    aoff[i] = (wm*64 + i*16 + (lane&15))*32 + (lane>>4)*8;
    boff[i] = (wn*64 + i*16 + (lane&15))*32 + (lane>>4)*8;
  }

  auto compute = [&](){
    bf16x8 af[4], bfr[4];
    #pragma unroll
    for (int i = 0; i < 4; ++i){
      af[i]  = *(const bf16x8*)&As[aoff[i]];
      bfr[i] = *(const bf16x8*)&Bs[boff[i]];
    }
    #pragma unroll
    for (int i = 0; i < 4; ++i)
      #pragma unroll
      for (int j = 0; j < 4; ++j)
        acc[i][j] = __builtin_amdgcn_mfma_f32_16x16x32_bf16(af[i], bfr[j], acc[i][j], 0, 0, 0);
  };

  for (int kt = 0; kt < INTER/32; ++kt){
    uint4 a0 = *(const uint4*)(arow0 + kt*32 + cc*8);
    uint4 a1 = *(const uint4*)(arow1 + kt*32 + cc*8);
    uint4 b0 = cvt8(brow0 + kt*32 + cc*8);
    uint4 b1 = cvt8(brow1 + kt*32 + cc*8);
    __syncthreads();
    *(uint4*)&As[r0*32 + cc*8]      = a0;
    *(uint4*)&As[(r0+64)*32 + cc*8] = a1;
    *(uint4*)&Bs[r0*32 + cc*8]      = b0;
    *(uint4*)&Bs[(r0+64)*32 + cc*8] = b1;
    __syncthreads();
    compute();
  }
  {
    uint4 a0 = *(const uint4*)(zd + (size_t)p0*32 + cc*8);
    uint4 a1 = *(const uint4*)(zd + (size_t)p1*32 + cc*8);
    int aid = cc >> 1, rr = (cc & 1)*8;
    uint4 b0 = cvt8(down_b + ((size_t)(aid*NEXP + e)*HIDDEN + j0)*MAXRANK + rr);
    uint4 b1 = cvt8(down_b + ((size_t)(aid*NEXP + e)*HIDDEN + j1)*MAXRANK + rr);
    __syncthreads();
    *(uint4*)&As[r0*32 + cc*8]      = a0;
    *(uint4*)&As[(r0+64)*32 + cc*8] = a1;
    *(uint4*)&Bs[r0*32 + cc*8]      = b0;
    *(uint4*)&Bs[(r0+64)*32 + cc*8] = b1;
    __syncthreads();
    compute();
  }
  int col = lane & 15, quad = lane >> 4;
  #pragma unroll
  for (int i = 0; i < 4; ++i){
    #pragma unroll
    for (int r = 0; r < 4; ++r){
      int mg = tm*128 + wm*64 + i*16 + quad*4 + r;
      if (mg < me){
        int p = perm[e*NPAIRS + mg];
        float wp = tw[p];
        size_t base = (size_t)(p >> 1)*HIDDEN;
        #pragma unroll
        for (int j = 0; j < 4; ++j){
          int jc = tn*128 + wn*64 + j*16 + col;
          atomicAdd(&outf[base + jc], wp * acc[i][j][r]);
        }
      }
    }
  }
}

extern "C" void kernel_launch(void* const* d_in, const int* in_sizes, int n_in,
                              void* d_out, int out_size, void* d_ws, size_t ws_size,
                              hipStream_t stream){
  const float* x        = (const float*)d_in[0];
  const int*   topk_ids = (const int*)d_in[1];
  const float* tw       = (const float*)d_in[2];
  const float* gate_a   = (const float*)d_in[3];
  const float* gate_b   = (const float*)d_in[4];
  const float* up_a     = (const float*)d_in[5];
  const float* up_b     = (const float*)d_in[6];
  const float* down_a   = (const float*)d_in[7];
  const float* down_b   = (const float*)d_in[8];
  const int*   widx     = (const int*)d_in[9];
  const int*   seq_lens = (const int*)d_in[10];
  const int*   ranks    = (const int*)d_in[11];
  const float* scal     = (const float*)d_in[12];
  const float* wgu      = (const float*)d_in[13];
  const float* wd       = (const float*)d_in[14];
  float* outf = (float*)d_out;
  char* ws = (char*)d_ws;

  if (ws_size >= (size_t)FAST_NEED){
    int* cnt  = (int*)(ws + F_CNT);
    int* perm = (int*)(ws + F_PERM);
    u16* zg   = (u16*)(ws + F_ZG);
    u16* zu   = (u16*)(ws + F_ZU);
    u16* zd   = (u16*)(ws + F_ZD);
    u16* xb   = (u16*)(ws + F_XBF);
    u16* act  = (u16*)(ws + F_ACT);
    u16* gbb  = (u16*)(ws + F_GB);
    u16* ubb  = (u16*)(ws + F_UB);
    u16* dbb  = (u16*)(ws + F_DB);
    u16* gab  = (u16*)(ws + F_GA_BF);
    u16* uab  = (u16*)(ws + F_UA_BF);
    float* zdf= (float*)(ws + F_ZDF);
    u16* dab  = (u16*)(ws + F_DA_BF);

    hipLaunchKernelGGL(k_prep, dim3(888), dim3(256), 0, stream,
                       x, gate_b, up_b, gate_a, up_a, down_b, down_a,
                       xb, gbb, ubb, gab, uab, dbb, dab, outf, zdf, cnt);
    hipLaunchKernelGGL(k_route, dim3(16), dim3(256), 0, stream, topk_ids, cnt, perm);
    hipLaunchKernelGGL(k_zgu_mfma, dim3(64, NEXP), dim3(256), 0, stream,
                       xb, gab, uab, cnt, perm, widx, seq_lens, ranks, scal, zg, zu);
    hipLaunchKernelGGL(k_gu_f32, dim3(INTER/64, 32, NEXP), dim3(256), 0, stream,
                       xb, wgu, gbb, ubb, zg, zu, cnt, perm, act);
    hipLaunchKernelGGL(k_zd_mfma, dim3(4, 64, NEXP), dim3(256), 0, stream,
                       act, dab, cnt, perm, widx, seq_lens, ranks, scal, zdf);
    hipLaunchKernelGGL(k_cvt, dim3((NPAIRS*32/4+255)/256), dim3(256), 0, stream,
                       zdf, zd, NPAIRS*32/4);
    hipLaunchKernelGGL(k_down_f32, dim3(32, 32, NEXP), dim3(256), 0, stream,
                       act, wd, dbb, zd, tw, cnt, perm, outf);
  } else {
    int* cnt  = (int*)(ws + B_CNT);
    int* perm = (int*)(ws + B_PERM);
    u16* zg   = (u16*)(ws + B_ZG);
    u16* zu   = (u16*)(ws + B_ZU);
    u16* zd   = (u16*)(ws + B_ZD);
    u16* act  = (u16*)(ws + B_ACT);

    hipLaunchKernelGGL(k_zero,  dim3(2048), dim3(256), 0, stream, outf, cnt, outf);
    hipLaunchKernelGGL(k_route, dim3(16), dim3(256), 0, stream, topk_ids, cnt, perm);
    hipLaunchKernelGGL(k_zgu,   dim3(NPAIRS), dim3(256), 0, stream,
                       x, topk_ids, gate_a, up_a, widx, seq_lens, ranks, scal, zg, zu);
    hipLaunchKernelGGL(k_gufused, dim3(INTER/64, 32, NEXP), dim3(256), 0, stream,
                       x, wgu, gate_b, up_b, zg, zu, cnt, perm, act);
    hipLaunchKernelGGL(k_zd,    dim3(NPAIRS), dim3(256), 0, stream,
                       act, topk_ids, down_a, widx, seq_lens, ranks, scal, zd);
    hipLaunchKernelGGL(k_gemm_down, dim3(HIDDEN/128, 32, NEXP), dim3(256), 0, stream,
                       act, wd, down_b, zd, tw, cnt, perm, outf);
  }
}

// Round 11
// 569.420 us; speedup vs baseline: 1.0936x; 1.0252x over previous
//
#include <hip/hip_runtime.h>
#include <hip/hip_bf16.h>
#include <math.h>

#define N_TOK   2048
#define HIDDEN  1024
#define INTER   2816
#define NEXP    8
#define NADAPT  2
#define MAXRANK 16
#define TOPK    2
#define NSEQ    8
#define NPAIRS  (N_TOK*TOPK)     // 4096
#define NGU     (2*INTER)        // 5632

typedef unsigned short u16;
typedef __attribute__((ext_vector_type(8))) short bf16x8;
typedef __attribute__((ext_vector_type(4))) float f32x4;

// ---- FAST workspace layout (bytes), FAST_NEED = 164 MiB (unchanged) ----
#define F_CNT   0u
#define F_PERM  4096u        // 131072
#define F_ZG    139264u      // 262144
#define F_ZU    401408u      // 262144
#define F_ZD    663552u      // 262144 (ends 925696)
#define F_XBF   1048576u     // 4194304
#define F_ACT   5242880u     // 23068672
#define F_GB    28311552u    // 1441792
#define F_UB    29753344u    // 1441792
#define F_DB    31195136u    // 524288  (ends 31719424)
#define F_GA_BF 31719424u    // 524288  bf16 gate_a
#define F_UA_BF 32243712u    // 524288  bf16 up_a   (ends 32768000)
#define F_ZDF   32768000u    // 524288  f32 zd accumulator (ends 33292288)
#define F_DA_BF 33554432u    // 1441792 bf16 down_a
#define FAST_NEED 171966464u

// ---- fallback layout, ~24.1 MB ----
#define B_CNT   0u
#define B_PERM  4096u
#define B_ZG    262144u
#define B_ZU    524288u
#define B_ZD    786432u
#define B_ACT   1048576u

__device__ __forceinline__ float bf2f(u16 u){
  union { unsigned int i; float f; } v; v.i = ((unsigned int)u)<<16; return v.f;
}
__device__ __forceinline__ u16 f2bf(float f){
  union { float f; unsigned int i; } v; v.f = f;
  unsigned int i = v.i;
  return (u16)((i + 0x7fffu + ((i>>16)&1u)) >> 16);
}
__device__ __forceinline__ uint4 cvt8(const float* src){
  float4 lo = *(const float4*)src;
  float4 hi = *(const float4*)(src+4);
  uint4 r;
  r.x = (unsigned)f2bf(lo.x) | ((unsigned)f2bf(lo.y)<<16);
  r.y = (unsigned)f2bf(lo.z) | ((unsigned)f2bf(lo.w)<<16);
  r.z = (unsigned)f2bf(hi.x) | ((unsigned)f2bf(hi.y)<<16);
  r.w = (unsigned)f2bf(hi.z) | ((unsigned)f2bf(hi.w)<<16);
  return r;
}
__device__ __forceinline__ uint2 cvt4(float4 v){
  uint2 r;
  r.x = (unsigned)f2bf(v.x) | ((unsigned)f2bf(v.y)<<16);
  r.y = (unsigned)f2bf(v.z) | ((unsigned)f2bf(v.w)<<16);
  return r;
}

// HW packed f32->bf16 (gfx950 v_cvt_pk_bf16_f32) — weight-staging fast path only
__device__ __forceinline__ unsigned cvtpk(float a, float b){
  unsigned r;
  asm("v_cvt_pk_bf16_f32 %0, %1, %2" : "=v"(r) : "v"(a), "v"(b));
  return r;
}
__device__ __forceinline__ uint4 pack8(const float* src){
  float4 lo = *(const float4*)src;
  float4 hi = *(const float4*)(src+4);
  uint4 r;
  r.x = cvtpk(lo.x, lo.y);
  r.y = cvtpk(lo.z, lo.w);
  r.z = cvtpk(hi.x, hi.y);
  r.w = cvtpk(hi.z, hi.w);
  return r;
}

// convert one 8192-float chunk c: loads first (8 in flight), then stores
__device__ __forceinline__ void cvt_chunk8k(const float* __restrict__ src, u16* __restrict__ dst, int c, int t){
  size_t b4 = (size_t)c*2048 + t;
  float4 v0 = ((const float4*)src)[b4];
  float4 v1 = ((const float4*)src)[b4 + 256];
  float4 v2 = ((const float4*)src)[b4 + 512];
  float4 v3 = ((const float4*)src)[b4 + 768];
  float4 v4 = ((const float4*)src)[b4 + 1024];
  float4 v5 = ((const float4*)src)[b4 + 1280];
  float4 v6 = ((const float4*)src)[b4 + 1536];
  float4 v7 = ((const float4*)src)[b4 + 1792];
  ((uint2*)dst)[b4]        = cvt4(v0);
  ((uint2*)dst)[b4 + 256]  = cvt4(v1);
  ((uint2*)dst)[b4 + 512]  = cvt4(v2);
  ((uint2*)dst)[b4 + 768]  = cvt4(v3);
  ((uint2*)dst)[b4 + 1024] = cvt4(v4);
  ((uint2*)dst)[b4 + 1280] = cvt4(v5);
  ((uint2*)dst)[b4 + 1536] = cvt4(v6);
  ((uint2*)dst)[b4 + 1792] = cvt4(v7);
}
__device__ __forceinline__ void zero_chunk8k(float* dst, int c, int t){
  size_t b4 = (size_t)c*2048 + t;
  #pragma unroll
  for (int i = 0; i < 8; ++i)
    ((float4*)dst)[b4 + i*256] = make_float4(0.f,0.f,0.f,0.f);
}

// async 16B global -> LDS (wave-uniform LDS base + lane*16)
__device__ __forceinline__ void gl16(const void* g, void* l){
  __builtin_amdgcn_global_load_lds(
      (const __attribute__((address_space(1))) unsigned int*)g,
      (__attribute__((address_space(3))) unsigned int*)l, 16, 0, 0);
}

__device__ __forceinline__ int token_adapter(int n, const int* seq_lens, const int* widx){
  int cum = 0;
  #pragma unroll
  for (int s = 0; s < NSEQ; ++s){ cum += seq_lens[s]; if (n < cum) return widx[s]; }
  return widx[NSEQ-1];
}

// fallback-path zero kernel
__global__ void k_zero(float* outf, int* cnt, float* zdf){
  int t = threadIdx.x;
  if (blockIdx.x < 2048){
    int id = blockIdx.x*256 + t;
    *(float4*)&outf[(size_t)id*4] = make_float4(0.f,0.f,0.f,0.f);
  } else {
    int id = (blockIdx.x - 2048)*256 + t;
    *(float4*)&zdf[(size_t)id*4] = make_float4(0.f,0.f,0.f,0.f);
  }
  if (blockIdx.x == 0 && t < NEXP) cnt[t] = 0;
}

__global__ void k_route(const int* __restrict__ topk_ids, int* cnt, int* perm){
  int p = blockIdx.x*256 + threadIdx.x;
  if (p >= NPAIRS) return;
  int e = topk_ids[p];
  int pos = atomicAdd(&cnt[e], 1);
  perm[e*NPAIRS + pos] = p;
}

// f32 -> bf16, 4 elems/thread, coalesced (small late conversions)
__global__ void k_cvt(const float* __restrict__ src, u16* __restrict__ dst, int n4){
  int id = blockIdx.x*256 + threadIdx.x;
  if (id >= n4) return;
  ((uint2*)dst)[id] = cvt4(((const float4*)src)[id]);
}

// prep: all small conversions + zeroing, 1 launch, 8192 floats/block.
// blocks: x[0,256) gb[256,344) ub[344,432) ga[432,464) ua[464,496) db[496,528)
//         da[528,616) outfZ[616,872) zdfZ[872,888) -> grid 888
__global__ void k_prep(
    const float* __restrict__ x,  const float* __restrict__ gb, const float* __restrict__ ub,
    const float* __restrict__ ga, const float* __restrict__ ua, const float* __restrict__ db_,
    const float* __restrict__ da,
    u16* xb, u16* gbb, u16* ubb, u16* gab, u16* uab, u16* dbb, u16* dab,
    float* outf, float* zdf, int* cnt)
{
  int b = blockIdx.x, t = threadIdx.x;
  if (b == 0 && t < NEXP) cnt[t] = 0;
  if      (b < 256) cvt_chunk8k(x,   xb,  b,       t);
  else if (b < 344) cvt_chunk8k(gb,  gbb, b - 256, t);
  else if (b < 432) cvt_chunk8k(ub,  ubb, b - 344, t);
  else if (b < 464) cvt_chunk8k(ga,  gab, b - 432, t);
  else if (b < 496) cvt_chunk8k(ua,  uab, b - 464, t);
  else if (b < 528) cvt_chunk8k(db_, dbb, b - 496, t);
  else if (b < 616) cvt_chunk8k(da,  dab, b - 528, t);
  else if (b < 872) zero_chunk8k(outf, b - 616, t);
  else              zero_chunk8k(zdf,  b - 872, t);
}

// ===================== MFMA z-kernels (fast path, verified, unchanged) =====================
__global__ __launch_bounds__(256) void k_zgu_mfma(
    const u16* __restrict__ xb, const u16* __restrict__ gab, const u16* __restrict__ uab,
    const int* __restrict__ cnt, const int* __restrict__ perm,
    const int* __restrict__ widx, const int* __restrict__ seq_lens,
    const int* __restrict__ ranks, const float* __restrict__ scal,
    u16* __restrict__ zg, u16* __restrict__ zu)
{
  int e = blockIdx.y;
  int me = cnt[e];
  int tm = blockIdx.x;
  if (tm*64 >= me) return;
  int t = threadIdx.x;

  __shared__ __align__(16) u16 As[64*32];
  __shared__ __align__(16) u16 Bs[64*32];

  int r0 = t >> 2;
  int kc = ((t&3) - r0) & 3;     // swizzle: slot (t&3) holds logical chunk kc
  int ko = kc*8;
  int mg = tm*64 + r0;
  int pa = perm[e*NPAIRS + min(mg, me-1)];
  const u16* arow = xb + (size_t)(pa>>1)*HIDDEN + ko;
  int jr = r0 & 31;              // B row: r0<32 -> gate_a, else up_a
  const u16* brow = (r0 < 32 ? gab : uab)
                    + (size_t)(((jr>>4)*NEXP + e)*MAXRANK + (jr&15))*HIDDEN + ko;

  int wv = t>>6, lane = t&63;
  u16* Asw = &As[wv*512];
  u16* Bsw = &Bs[wv*512];
  int wm = wv>>1, wn = wv&1;
  int l15 = lane&15, q = lane>>4;

  f32x4 acc[2][2] = {};
  int aoff[2], boff[2];
  #pragma unroll
  for (int i=0;i<2;++i){ int row = wm*32 + i*16 + l15; aoff[i] = row*32 + ((q+row)&3)*8; }
  #pragma unroll
  for (int j=0;j<2;++j){ int row = wn*32 + j*16 + l15; boff[j] = row*32 + ((q+row)&3)*8; }

  for (int kt = 0; kt < HIDDEN/32; ++kt){
    __syncthreads();
    gl16(arow + kt*32, Asw);
    gl16(brow + kt*32, Bsw);
    __syncthreads();
    bf16x8 af[2], bfr[2];
    #pragma unroll
    for (int i=0;i<2;++i) af[i] = *(const bf16x8*)&As[aoff[i]];
    #pragma unroll
    for (int j=0;j<2;++j) bfr[j] = *(const bf16x8*)&Bs[boff[j]];
    #pragma unroll
    for (int i=0;i<2;++i)
      #pragma unroll
      for (int j=0;j<2;++j)
        acc[i][j] = __builtin_amdgcn_mfma_f32_16x16x32_bf16(af[i], bfr[j], acc[i][j],0,0,0);
  }

  u16* dstz = wn ? zu : zg;
  #pragma unroll
  for (int i=0;i<2;++i){
    #pragma unroll
    for (int r=0;r<4;++r){
      int mgo = tm*64 + wm*32 + i*16 + q*4 + r;
      if (mgo < me){
        int p = perm[e*NPAIRS + mgo];
        int a = token_adapter(p>>1, seq_lens, widx);
        int rank = ranks[a]; float sc = scal[a];
        #pragma unroll
        for (int j=0;j<2;++j){
          int jc = j*16 + l15;
          float v = ((jc>>4)==a && (jc&15)<rank) ? sc*acc[i][j][r] : 0.f;
          dstz[(size_t)p*32 + jc] = f2bf(v);
        }
      }
    }
  }
}

__global__ __launch_bounds__(256) void k_zd_mfma(
    const u16* __restrict__ act, const u16* __restrict__ dab,
    const int* __restrict__ cnt, const int* __restrict__ perm,
    const int* __restrict__ widx, const int* __restrict__ seq_lens,
    const int* __restrict__ ranks, const float* __restrict__ scal,
    float* __restrict__ zdf)
{
  int e = blockIdx.z;
  int me = cnt[e];
  int tm = blockIdx.y;
  if (tm*64 >= me) return;
  int ks = blockIdx.x;           // 0..3
  int t = threadIdx.x;

  __shared__ __align__(16) u16 As[64*32];
  __shared__ __align__(16) u16 Bs[32*32];

  int r0 = t >> 2;
  int kc = ((t&3) - r0) & 3;
  int ko = kc*8;
  int mg = tm*64 + r0;
  int pa = perm[e*NPAIRS + min(mg, me-1)];
  const u16* arow = act + (size_t)pa*INTER + ko;
  int jr = r0 & 31;
  const u16* brow = dab + (size_t)(((jr>>4)*NEXP + e)*MAXRANK + (jr&15))*INTER + ko;

  int wv = t>>6, lane = t&63;
  u16* Asw = &As[wv*512];
  u16* Bsw = &Bs[(wv&1)*512];    // waves 0,1 stage the 32 B rows
  int l15 = lane&15, q = lane>>4;

  f32x4 acc[2] = {};
  int aoff; { int row = wv*16 + l15; aoff = row*32 + ((q+row)&3)*8; }
  int boff[2];
  #pragma unroll
  for (int j=0;j<2;++j){ int row = j*16 + l15; boff[j] = row*32 + ((q+row)&3)*8; }

  int kt0 = ks*22, kt1 = kt0 + 22;   // INTER/32 = 88 = 4*22
  for (int kt = kt0; kt < kt1; ++kt){
    __syncthreads();
    gl16(arow + kt*32, Asw);
    if (wv < 2) gl16(brow + kt*32, Bsw);
    __syncthreads();
    bf16x8 af = *(const bf16x8*)&As[aoff];
    bf16x8 b0 = *(const bf16x8*)&Bs[boff[0]];
    bf16x8 b1 = *(const bf16x8*)&Bs[boff[1]];
    acc[0] = __builtin_amdgcn_mfma_f32_16x16x32_bf16(af, b0, acc[0],0,0,0);
    acc[1] = __builtin_amdgcn_mfma_f32_16x16x32_bf16(af, b1, acc[1],0,0,0);
  }

  #pragma unroll
  for (int r=0;r<4;++r){
    int mgo = tm*64 + wv*16 + q*4 + r;
    if (mgo < me){
      int p = perm[e*NPAIRS + mgo];
      int a = token_adapter(p>>1, seq_lens, widx);
      int rank = ranks[a]; float sc = scal[a];
      #pragma unroll
      for (int j=0;j<2;++j){
        int jc = j*16 + l15;
        if ((jc>>4)==a && (jc&15)<rank)
          atomicAdd(&zdf[(size_t)p*32 + jc], sc*acc[j][r]);
      }
    }
  }
}

// ===================== fallback z-kernels (f32 weights) =====================
__global__ __launch_bounds__(256) void k_zgu(
    const float* __restrict__ x, const int* __restrict__ topk_ids,
    const float* __restrict__ gate_a, const float* __restrict__ up_a,
    const int* __restrict__ widx, const int* __restrict__ seq_lens,
    const int* __restrict__ ranks, const float* __restrict__ scal,
    u16* __restrict__ zg, u16* __restrict__ zu)
{
  int p = blockIdx.x, n = p >> 1, t = threadIdx.x;
  int e = topk_ids[p];
  __shared__ float xs[HIDDEN];
  for (int i = t; i < HIDDEN; i += 256) xs[i] = x[(size_t)n*HIDDEN + i];
  if (t < 32){ zg[p*32 + t] = 0; zu[p*32 + t] = 0; }
  __syncthreads();
  int a = token_adapter(n, seq_lens, widx);
  int rank = ranks[a];
  float scale = scal[a];
  int wv = t >> 6, lane = t & 63;
  for (int i = 0; i < 8; ++i){
    int o = wv*8 + i;
    int r = o & 15;
    const float* wrow = ((o < 16) ? gate_a : up_a) + (size_t)((a*NEXP + e)*MAXRANK + r)*HIDDEN;
    float s = 0.f;
    for (int h = lane; h < HIDDEN; h += 64) s += xs[h] * wrow[h];
    s += __shfl_down(s,32); s += __shfl_down(s,16); s += __shfl_down(s,8);
    s += __shfl_down(s,4);  s += __shfl_down(s,2);  s += __shfl_down(s,1);
    if (lane == 0 && r < rank)
      (o < 16 ? zg : zu)[p*32 + a*16 + r] = f2bf(scale * s);
  }
}

__global__ __launch_bounds__(256) void k_zd(
    const u16* __restrict__ act, const int* __restrict__ topk_ids,
    const float* __restrict__ down_a,
    const int* __restrict__ widx, const int* __restrict__ seq_lens,
    const int* __restrict__ ranks, const float* __restrict__ scal,
    u16* __restrict__ zd)
{
  int p = blockIdx.x, n = p >> 1, t = threadIdx.x;
  int e = topk_ids[p];
  __shared__ float as_[INTER];
  for (int i = t; i < INTER; i += 256) as_[i] = bf2f(act[(size_t)p*INTER + i]);
  if (t < 32) zd[p*32 + t] = 0;
  __syncthreads();
  int a = token_adapter(n, seq_lens, widx);
  int rank = ranks[a];
  float scale = scal[a];
  int wv = t >> 6, lane = t & 63;
  for (int i = 0; i < 4; ++i){
    int r = wv*4 + i;
    const float* wrow = down_a + (size_t)((a*NEXP + e)*MAXRANK + r)*INTER;
    float s = 0.f;
    for (int h = lane; h < INTER; h += 64) s += as_[h] * wrow[h];
    s += __shfl_down(s,32); s += __shfl_down(s,16); s += __shfl_down(s,8);
    s += __shfl_down(s,4);  s += __shfl_down(s,2);  s += __shfl_down(s,1);
    if (lane == 0 && r < rank) zd[p*32 + a*16 + r] = f2bf(scale * s);
  }
}

// ===================== gu GEMM: M-tile 256, 512 threads (8 waves), pack8 staging ============
// Halves B-panel staging amplification (2 active tm blocks share a panel vs 4).
// A: 256 rows x 32 bf16 (16KB), two gl16 passes. B: Bg/Bu 64 rows x 32 bf16 (4KB each),
// one combined reg-staged pass (waves 0-3 -> Bg, 4-7 -> Bu, 16 rows/wave, XOR-slot swizzle).
__global__ __launch_bounds__(512) void k_gu_f32(
    const u16* __restrict__ xb, const float* __restrict__ wgu_f32,
    const u16* __restrict__ gbb, const u16* __restrict__ ubb,
    const u16* __restrict__ zg, const u16* __restrict__ zu,
    const int* __restrict__ cnt, const int* __restrict__ perm,
    u16* __restrict__ act)
{
  int e = blockIdx.z;
  int me = cnt[e];
  int tm = blockIdx.y;            // 0..15, 256 pairs each
  if (tm*256 >= me) return;
  int tn = blockIdx.x;            // 0..43, 64 inter-cols each
  int t = threadIdx.x;            // 0..511

  __shared__ __align__(16) u16 As[256*32];   // 16KB
  __shared__ __align__(16) u16 Bg[64*32];    // 4KB
  __shared__ __align__(16) u16 Bu[64*32];    // 4KB

  int wv = t>>6, lane = t&63;
  int r0 = t >> 2;                // 0..127
  int kc = ((t&3) - r0) & 3;
  int ko = kc*8;
  int mg0 = tm*256 + r0, mg1 = mg0 + 128;
  int p0 = perm[e*NPAIRS + min(mg0, me-1)];
  int p1 = perm[e*NPAIRS + min(mg1, me-1)];
  const u16* arow0 = xb + (size_t)(p0>>1)*HIDDEN + ko;
  const u16* arow1 = xb + (size_t)(p1>>1)*HIDDEN + ko;

  // B staging (combined pass): waves 0-3 -> Bg rows, waves 4-7 -> Bu rows
  int rB  = (wv&3)*16 + (lane>>2);             // 0..63
  int kcB = ((lane&3) - rB) & 3;               // slot (lane&3) holds logical chunk kcB
  const float* browX = wgu_f32
      + ((size_t)e*NGU + (wv<4 ? 0 : INTER) + tn*64 + rB)*HIDDEN + kcB*8;
  u16* BdstX = (wv<4 ? Bg : Bu) + (wv&3)*512 + lane*8;

  u16* Asw0 = &As[wv*512];
  u16* Asw1 = &As[4096 + wv*512];

  int wm = wv>>1, wn = wv&1;      // wm 0..3 (row group of 64), wn 0..1 (col group of 32)
  int l15 = lane&15, q = lane>>4;

  f32x4 accg[4][2] = {};
  f32x4 accu[4][2] = {};
  int aoff[4], boff[2];
  #pragma unroll
  for (int i=0;i<4;++i){ int row = wm*64 + i*16 + l15; aoff[i] = row*32 + ((q+row)&3)*8; }
  #pragma unroll
  for (int j=0;j<2;++j){ int row = wn*32 + j*16 + l15; boff[j] = row*32 + ((q+row)&3)*8; }

  for (int kt = 0; kt < HIDDEN/32; ++kt){
    uint4 bx = pack8(browX + kt*32);   // f32 load + HW cvt_pk before barrier
    __syncthreads();
    gl16(arow0 + kt*32, Asw0);
    gl16(arow1 + kt*32, Asw1);
    *(uint4*)BdstX = bx;
    __syncthreads();
    bf16x8 af[4], bgf[2], buf[2];
    #pragma unroll
    for (int i=0;i<4;++i) af[i] = *(const bf16x8*)&As[aoff[i]];
    #pragma unroll
    for (int j=0;j<2;++j){ bgf[j] = *(const bf16x8*)&Bg[boff[j]]; buf[j] = *(const bf16x8*)&Bu[boff[j]]; }
    #pragma unroll
    for (int i=0;i<4;++i)
      #pragma unroll
      for (int j=0;j<2;++j){
        accg[i][j] = __builtin_amdgcn_mfma_f32_16x16x32_bf16(af[i], bgf[j], accg[i][j],0,0,0);
        accu[i][j] = __builtin_amdgcn_mfma_f32_16x16x32_bf16(af[i], buf[j], accu[i][j],0,0,0);
      }
  }
  // LoRA K-extension (32 = NADAPT*MAXRANK): A rows via 2 gl16 passes; B rows 0-63 by waves 0-3
  {
    int aid = kc>>1, rr = (kc&1)*8;
    int jg = tn*64 + r0;                 // only used by wv<4 (r0 < 64 there)
    const u16* gB = gbb + ((size_t)(aid*NEXP+e)*INTER + jg)*MAXRANK + rr;
    const u16* uB = ubb + ((size_t)(aid*NEXP+e)*INTER + jg)*MAXRANK + rr;
    u16* Bgw = &Bg[(wv&3)*512];
    __syncthreads();
    gl16(zg + (size_t)p0*32 + ko, Asw0);
    gl16(zg + (size_t)p1*32 + ko, Asw1);
    if (wv < 4) gl16(gB, Bgw);
    __syncthreads();
    {
      bf16x8 af[4], bgf[2];
      #pragma unroll
      for (int i=0;i<4;++i) af[i] = *(const bf16x8*)&As[aoff[i]];
      #pragma unroll
      for (int j=0;j<2;++j) bgf[j] = *(const bf16x8*)&Bg[boff[j]];
      #pragma unroll
      for (int i=0;i<4;++i)
        #pragma unroll
        for (int j=0;j<2;++j)
          accg[i][j] = __builtin_amdgcn_mfma_f32_16x16x32_bf16(af[i], bgf[j], accg[i][j],0,0,0);
    }
    __syncthreads();
    gl16(zu + (size_t)p0*32 + ko, Asw0);
    gl16(zu + (size_t)p1*32 + ko, Asw1);
    if (wv < 4) gl16(uB, Bgw);
    __syncthreads();
    {
      bf16x8 af[4], buf[2];
      #pragma unroll
      for (int i=0;i<4;++i) af[i] = *(const bf16x8*)&As[aoff[i]];
      #pragma unroll
      for (int j=0;j<2;++j) buf[j] = *(const bf16x8*)&Bg[boff[j]];
      #pragma unroll
      for (int i=0;i<4;++i)
        #pragma unroll
        for (int j=0;j<2;++j)
          accu[i][j] = __builtin_amdgcn_mfma_f32_16x16x32_bf16(af[i], buf[j], accu[i][j],0,0,0);
    }
  }

  int col = l15, quad = q;
  #pragma unroll
  for (int i = 0; i < 4; ++i){
    #pragma unroll
    for (int r = 0; r < 4; ++r){
      int mg = tm*256 + wm*64 + i*16 + quad*4 + r;
      if (mg < me){
        int p = perm[e*NPAIRS + mg];
        size_t base = (size_t)p*INTER;
        #pragma unroll
        for (int j = 0; j < 2; ++j){
          int jc = tn*64 + wn*32 + j*16 + col;
          float g = accg[i][j][r], u = accu[i][j][r];
          float s = g / (1.f + __expf(-g));
          act[base + jc] = f2bf(s*u);
        }
      }
    }
  }
}

// ===================== down GEMM, round-10 structure (split-K x4) + pack8 staging ======
__global__ __launch_bounds__(256) void k_down_f32(
    const u16* __restrict__ act, const float* __restrict__ wd_f32,
    const u16* __restrict__ dbb, const u16* __restrict__ zd,
    const float* __restrict__ tw,
    const int* __restrict__ cnt, const int* __restrict__ perm,
    float* __restrict__ outf)
{
  int e = blockIdx.z;
  int me = cnt[e];
  int tm = blockIdx.y;
  if (tm*128 >= me) return;
  int tn = blockIdx.x & 7;
  int ks = blockIdx.x >> 3;       // 0..3
  int t = threadIdx.x;

  __shared__ __align__(16) u16 As[128*32];
  __shared__ __align__(16) u16 Bs[128*32];

  int r0 = t >> 2;
  int kc = ((t&3) - r0) & 3;
  int ko = kc*8;
  int mg0 = tm*128 + r0, mg1 = mg0 + 64;
  int p0 = perm[e*NPAIRS + min(mg0, me-1)];
  int p1 = perm[e*NPAIRS + min(mg1, me-1)];
  const u16* arow0 = act + (size_t)p0*INTER + ko;
  const u16* arow1 = act + (size_t)p1*INTER + ko;
  int j0 = tn*128 + r0, j1 = j0 + 64;
  const float* brow0 = wd_f32 + ((size_t)e*HIDDEN + j0)*INTER + ko;
  const float* brow1 = wd_f32 + ((size_t)e*HIDDEN + j1)*INTER + ko;

  int wvb = (t>>6)*512;
  u16* Asw0 = &As[wvb];
  u16* Asw1 = &As[2048 + wvb];
  u16* Bsw0 = &Bs[wvb];
  u16* Bsw1 = &Bs[2048 + wvb];

  int wv = t>>6, lane = t&63;
  int wm = wv>>1, wn = wv&1;
  int l15 = lane&15, q = lane>>4;

  f32x4 acc[4][4] = {};
  int aoff[4], boff[4];
  #pragma unroll
  for (int i=0;i<4;++i){ int row = wm*64 + i*16 + l15; aoff[i] = row*32 + ((q+row)&3)*8; }
  #pragma unroll
  for (int j=0;j<4;++j){ int row = wn*64 + j*16 + l15; boff[j] = row*32 + ((q+row)&3)*8; }

  auto mma = [&](){
    bf16x8 af[4], bfr[4];
    #pragma unroll
    for (int i=0;i<4;++i){ af[i] = *(const bf16x8*)&As[aoff[i]]; bfr[i] = *(const bf16x8*)&Bs[boff[i]]; }
    #pragma unroll
    for (int i=0;i<4;++i)
      #pragma unroll
      for (int j=0;j<4;++j)
        acc[i][j] = __builtin_amdgcn_mfma_f32_16x16x32_bf16(af[i], bfr[j], acc[i][j],0,0,0);
  };

  int kt0 = ks*22, kt1 = kt0 + 22;
  for (int kt = kt0; kt < kt1; ++kt){
    uint4 b0 = pack8(brow0 + kt*32);
    uint4 b1 = pack8(brow1 + kt*32);
    __syncthreads();
    gl16(arow0 + kt*32, Asw0);
    gl16(arow1 + kt*32, Asw1);
    *(uint4*)&Bs[wvb + lane*8]        = b0;
    *(uint4*)&Bs[2048 + wvb + lane*8] = b1;
    __syncthreads();
    mma();
  }
  if (ks == 3){
    int aid = kc>>1, rr = (kc&1)*8;
    __syncthreads();
    gl16(zd + (size_t)p0*32 + ko, Asw0);
    gl16(zd + (size_t)p1*32 + ko, Asw1);
    gl16(dbb + ((size_t)(aid*NEXP+e)*HIDDEN + j0)*MAXRANK + rr, Bsw0);
    gl16(dbb + ((size_t)(aid*NEXP+e)*HIDDEN + j1)*MAXRANK + rr, Bsw1);
    __syncthreads();
    mma();
  }

  int col = l15, quad = q;
  #pragma unroll
  for (int i = 0; i < 4; ++i){
    #pragma unroll
    for (int r = 0; r < 4; ++r){
      int mg = tm*128 + wm*64 + i*16 + quad*4 + r;
      if (mg < me){
        int p = perm[e*NPAIRS + mg];
        float wp = tw[p];
        size_t base = (size_t)(p >> 1)*HIDDEN;
        #pragma unroll
        for (int j = 0; j < 4; ++j){
          int jc = tn*128 + wn*64 + j*16 + col;
          atomicAdd(&outf[base + jc], wp * acc[i][j][r]);
        }
      }
    }
  }
}

// ===================== FALLBACK PATH GEMMs (f32 weights, verified) =====================
__global__ __launch_bounds__(256) void k_gufused(
    const float* __restrict__ x, const float* __restrict__ wgu,
    const float* __restrict__ gate_b, const float* __restrict__ up_b,
    const u16* __restrict__ zg, const u16* __restrict__ zu,
    const int* __restrict__ cnt, const int* __restrict__ perm,
    u16* __restrict__ act)
{
  int e = blockIdx.z;
  int me = cnt[e];
  int tm = blockIdx.y;
  if (tm*128 >= me) return;
  int tn = blockIdx.x;
  int t = threadIdx.x;

  __shared__ __align__(16) u16 As[128*32];
  __shared__ __align__(16) u16 Bg[64*32];
  __shared__ __align__(16) u16 Bu[64*32];

  int r0 = t >> 2, cc = t & 3;
  int mg0 = tm*128 + r0, mg1 = mg0 + 64;
  int p0 = perm[e*NPAIRS + min(mg0, me-1)];
  int p1 = perm[e*NPAIRS + min(mg1, me-1)];
  const float* arow0 = x + (size_t)(p0 >> 1)*HIDDEN;
  const float* arow1 = x + (size_t)(p1 >> 1)*HIDDEN;
  int jg = tn*64 + r0;
  const float* browg = wgu + ((size_t)e*NGU + jg)*HIDDEN;
  const float* browu = wgu + ((size_t)e*NGU + INTER + jg)*HIDDEN;

  int wv = t >> 6, lane = t & 63;
  int wm = wv >> 1, wn = wv & 1;

  f32x4 accg[4][2] = {};
  f32x4 accu[4][2] = {};
  int aoff[4], boff[2];
  #pragma unroll
  for (int i = 0; i < 4; ++i) aoff[i] = (wm*64 + i*16 + (lane&15))*32 + (lane>>4)*8;
  #pragma unroll
  for (int j = 0; j < 2; ++j) boff[j] = (wn*32 + j*16 + (lane&15))*32 + (lane>>4)*8;

  for (int kt = 0; kt < HIDDEN/32; ++kt){
    uint4 a0 = cvt8(arow0 + kt*32 + cc*8);
    uint4 a1 = cvt8(arow1 + kt*32 + cc*8);
    uint4 bg = cvt8(browg + kt*32 + cc*8);
    uint4 bu = cvt8(browu + kt*32 + cc*8);
    __syncthreads();
    *(uint4*)&As[r0*32 + cc*8]      = a0;
    *(uint4*)&As[(r0+64)*32 + cc*8] = a1;
    *(uint4*)&Bg[r0*32 + cc*8]      = bg;
    *(uint4*)&Bu[r0*32 + cc*8]      = bu;
    __syncthreads();
    bf16x8 af[4], bgf[2], buf[2];
    #pragma unroll
    for (int i = 0; i < 4; ++i) af[i] = *(const bf16x8*)&As[aoff[i]];
    #pragma unroll
    for (int j = 0; j < 2; ++j){ bgf[j] = *(const bf16x8*)&Bg[boff[j]]; buf[j] = *(const bf16x8*)&Bu[boff[j]]; }
    #pragma unroll
    for (int i = 0; i < 4; ++i)
      #pragma unroll
      for (int j = 0; j < 2; ++j){
        accg[i][j] = __builtin_amdgcn_mfma_f32_16x16x32_bf16(af[i], bgf[j], accg[i][j], 0, 0, 0);
        accu[i][j] = __builtin_amdgcn_mfma_f32_16x16x32_bf16(af[i], buf[j], accu[i][j], 0, 0, 0);
      }
  }
  {
    uint4 a0 = *(const uint4*)(zg + (size_t)p0*32 + cc*8);
    uint4 a1 = *(const uint4*)(zg + (size_t)p1*32 + cc*8);
    int aid = cc >> 1, rr = (cc & 1)*8;
    uint4 bg = cvt8(gate_b + ((size_t)(aid*NEXP + e)*INTER + jg)*MAXRANK + rr);
    __syncthreads();
    *(uint4*)&As[r0*32 + cc*8]      = a0;
    *(uint4*)&As[(r0+64)*32 + cc*8] = a1;
    *(uint4*)&Bg[r0*32 + cc*8]      = bg;
    __syncthreads();
    bf16x8 af[4], bgf[2];
    #pragma unroll
    for (int i = 0; i < 4; ++i) af[i] = *(const bf16x8*)&As[aoff[i]];
    #pragma unroll
    for (int j = 0; j < 2; ++j) bgf[j] = *(const bf16x8*)&Bg[boff[j]];
    #pragma unroll
    for (int i = 0; i < 4; ++i)
      #pragma unroll
      for (int j = 0; j < 2; ++j)
        accg[i][j] = __builtin_amdgcn_mfma_f32_16x16x32_bf16(af[i], bgf[j], accg[i][j], 0, 0, 0);
  }
  {
    uint4 a0 = *(const uint4*)(zu + (size_t)p0*32 + cc*8);
    uint4 a1 = *(const uint4*)(zu + (size_t)p1*32 + cc*8);
    int aid = cc >> 1, rr = (cc & 1)*8;
    uint4 bu = cvt8(up_b + ((size_t)(aid*NEXP + e)*INTER + jg)*MAXRANK + rr);
    __syncthreads();
    *(uint4*)&As[r0*32 + cc*8]      = a0;
    *(uint4*)&As[(r0+64)*32 + cc*8] = a1;
    *(uint4*)&Bg[r0*32 + cc*8]      = bu;
    __syncthreads();
    bf16x8 af[4], buf[2];
    #pragma unroll
    for (int i = 0; i < 4; ++i) af[i] = *(const bf16x8*)&As[aoff[i]];
    #pragma unroll
    for (int j = 0; j < 2; ++j) buf[j] = *(const bf16x8*)&Bg[boff[j]];
    #pragma unroll
    for (int i = 0; i < 4; ++i)
      #pragma unroll
      for (int j = 0; j < 2; ++j)
        accu[i][j] = __builtin_amdgcn_mfma_f32_16x16x32_bf16(af[i], buf[j], accu[i][j], 0, 0, 0);
  }
  int col = lane & 15, quad = lane >> 4;
  #pragma unroll
  for (int i = 0; i < 4; ++i){
    #pragma unroll
    for (int r = 0; r < 4; ++r){
      int mg = tm*128 + wm*64 + i*16 + quad*4 + r;
      if (mg < me){
        int p = perm[e*NPAIRS + mg];
        size_t base = (size_t)p*INTER;
        #pragma unroll
        for (int j = 0; j < 2; ++j){
          int jc = tn*64 + wn*32 + j*16 + col;
          float g = accg[i][j][r], u = accu[i][j][r];
          float s = g / (1.f + __expf(-g));
          act[base + jc] = f2bf(s*u);
        }
      }
    }
  }
}

__global__ __launch_bounds__(256) void k_gemm_down(
    const u16* __restrict__ act, const float* __restrict__ wd,
    const float* __restrict__ down_b, const u16* __restrict__ zd,
    const float* __restrict__ tw,
    const int* __restrict__ cnt, const int* __restrict__ perm,
    float* __restrict__ outf)
{
  int e = blockIdx.z;
  int me = cnt[e];
  int tm = blockIdx.y;
  if (tm*128 >= me) return;
  int tn = blockIdx.x;
  int t = threadIdx.x;

  __shared__ __align__(16) u16 As[128*32];
  __shared__ __align__(16) u16 Bs[128*32];

  int r0 = t >> 2, cc = t & 3;
  int mg0 = tm*128 + r0, mg1 = mg0 + 64;
  int p0 = perm[e*NPAIRS + min(mg0, me-1)];
  int p1 = perm[e*NPAIRS + min(mg1, me-1)];
  const u16* arow0 = act + (size_t)p0*INTER;
  const u16* arow1 = act + (size_t)p1*INTER;
  int j0 = tn*128 + r0, j1 = j0 + 64;
  const float* brow0 = wd + ((size_t)e*HIDDEN + j0)*INTER;
  const float* brow1 = wd + ((size_t)e*HIDDEN + j1)*INTER;

  int wv = t >> 6, lane = t & 63;
  int wm = wv >> 1, wn = wv & 1;

  f32x4 acc[4][4] = {};
  int aoff[4], boff[4];
  #pragma unroll
  for (int i = 0; i < 4; ++i){
    aoff[i] = (wm*64 + i*16 + (lane&15))*32 + (lane>>4)*8;
    boff[i] = (wn*64 + i*16 + (lane&15))*32 + (lane>>4)*8;
  }

  auto compute = [&](){
    bf16x8 af[4], bfr[4];
    #pragma unroll
    for (int i = 0; i < 4; ++i){
      af[i]  = *(const bf16x8*)&As[aoff[i]];
      bfr[i] = *(const bf16x8*)&Bs[boff[i]];
    }
    #pragma unroll
    for (int i = 0; i < 4; ++i)
      #pragma unroll
      for (int j = 0; j < 4; ++j)
        acc[i][j] = __builtin_amdgcn_mfma_f32_16x16x32_bf16(af[i], bfr[j], acc[i][j], 0, 0, 0);
  };

  for (int kt = 0; kt < INTER/32; ++kt){
    uint4 a0 = *(const uint4*)(arow0 + kt*32 + cc*8);
    uint4 a1 = *(const uint4*)(arow1 + kt*32 + cc*8);
    uint4 b0 = cvt8(brow0 + kt*32 + cc*8);
    uint4 b1 = cvt8(brow1 + kt*32 + cc*8);
    __syncthreads();
    *(uint4*)&As[r0*32 + cc*8]      = a0;
    *(uint4*)&As[(r0+64)*32 + cc*8] = a1;
    *(uint4*)&Bs[r0*32 + cc*8]      = b0;
    *(uint4*)&Bs[(r0+64)*32 + cc*8] = b1;
    __syncthreads();
    compute();
  }
  {
    uint4 a0 = *(const uint4*)(zd + (size_t)p0*32 + cc*8);
    uint4 a1 = *(const uint4*)(zd + (size_t)p1*32 + cc*8);
    int aid = cc >> 1, rr = (cc & 1)*8;
    uint4 b0 = cvt8(down_b + ((size_t)(aid*NEXP + e)*HIDDEN + j0)*MAXRANK + rr);
    uint4 b1 = cvt8(down_b + ((size_t)(aid*NEXP + e)*HIDDEN + j1)*MAXRANK + rr);
    __syncthreads();
    *(uint4*)&As[r0*32 + cc*8]      = a0;
    *(uint4*)&As[(r0+64)*32 + cc*8] = a1;
    *(uint4*)&Bs[r0*32 + cc*8]      = b0;
    *(uint4*)&Bs[(r0+64)*32 + cc*8] = b1;
    __syncthreads();
    compute();
  }
  int col = lane & 15, quad = lane >> 4;
  #pragma unroll
  for (int i = 0; i < 4; ++i){
    #pragma unroll
    for (int r = 0; r < 4; ++r){
      int mg = tm*128 + wm*64 + i*16 + quad*4 + r;
      if (mg < me){
        int p = perm[e*NPAIRS + mg];
        float wp = tw[p];
        size_t base = (size_t)(p >> 1)*HIDDEN;
        #pragma unroll
        for (int j = 0; j < 4; ++j){
          int jc = tn*128 + wn*64 + j*16 + col;
          atomicAdd(&outf[base + jc], wp * acc[i][j][r]);
        }
      }
    }
  }
}

extern "C" void kernel_launch(void* const* d_in, const int* in_sizes, int n_in,
                              void* d_out, int out_size, void* d_ws, size_t ws_size,
                              hipStream_t stream){
  const float* x        = (const float*)d_in[0];
  const int*   topk_ids = (const int*)d_in[1];
  const float* tw       = (const float*)d_in[2];
  const float* gate_a   = (const float*)d_in[3];
  const float* gate_b   = (const float*)d_in[4];
  const float* up_a     = (const float*)d_in[5];
  const float* up_b     = (const float*)d_in[6];
  const float* down_a   = (const float*)d_in[7];
  const float* down_b   = (const float*)d_in[8];
  const int*   widx     = (const int*)d_in[9];
  const int*   seq_lens = (const int*)d_in[10];
  const int*   ranks    = (const int*)d_in[11];
  const float* scal     = (const float*)d_in[12];
  const float* wgu      = (const float*)d_in[13];
  const float* wd       = (const float*)d_in[14];
  float* outf = (float*)d_out;
  char* ws = (char*)d_ws;

  if (ws_size >= (size_t)FAST_NEED){
    int* cnt  = (int*)(ws + F_CNT);
    int* perm = (int*)(ws + F_PERM);
    u16* zg   = (u16*)(ws + F_ZG);
    u16* zu   = (u16*)(ws + F_ZU);
    u16* zd   = (u16*)(ws + F_ZD);
    u16* xb   = (u16*)(ws + F_XBF);
    u16* act  = (u16*)(ws + F_ACT);
    u16* gbb  = (u16*)(ws + F_GB);
    u16* ubb  = (u16*)(ws + F_UB);
    u16* dbb  = (u16*)(ws + F_DB);
    u16* gab  = (u16*)(ws + F_GA_BF);
    u16* uab  = (u16*)(ws + F_UA_BF);
    float* zdf= (float*)(ws + F_ZDF);
    u16* dab  = (u16*)(ws + F_DA_BF);

    hipLaunchKernelGGL(k_prep, dim3(888), dim3(256), 0, stream,
                       x, gate_b, up_b, gate_a, up_a, down_b, down_a,
                       xb, gbb, ubb, gab, uab, dbb, dab, outf, zdf, cnt);
    hipLaunchKernelGGL(k_route, dim3(16), dim3(256), 0, stream, topk_ids, cnt, perm);
    hipLaunchKernelGGL(k_zgu_mfma, dim3(64, NEXP), dim3(256), 0, stream,
                       xb, gab, uab, cnt, perm, widx, seq_lens, ranks, scal, zg, zu);
    hipLaunchKernelGGL(k_gu_f32, dim3(INTER/64, 16, NEXP), dim3(512), 0, stream,
                       xb, wgu, gbb, ubb, zg, zu, cnt, perm, act);
    hipLaunchKernelGGL(k_zd_mfma, dim3(4, 64, NEXP), dim3(256), 0, stream,
                       act, dab, cnt, perm, widx, seq_lens, ranks, scal, zdf);
    hipLaunchKernelGGL(k_cvt, dim3((NPAIRS*32/4+255)/256), dim3(256), 0, stream,
                       zdf, zd, NPAIRS*32/4);
    hipLaunchKernelGGL(k_down_f32, dim3(32, 32, NEXP), dim3(256), 0, stream,
                       act, wd, dbb, zd, tw, cnt, perm, outf);
  } else {
    int* cnt  = (int*)(ws + B_CNT);
    int* perm = (int*)(ws + B_PERM);
    u16* zg   = (u16*)(ws + B_ZG);
    u16* zu   = (u16*)(ws + B_ZU);
    u16* zd   = (u16*)(ws + B_ZD);
    u16* act  = (u16*)(ws + B_ACT);

    hipLaunchKernelGGL(k_zero,  dim3(2048), dim3(256), 0, stream, outf, cnt, outf);
    hipLaunchKernelGGL(k_route, dim3(16), dim3(256), 0, stream, topk_ids, cnt, perm);
    hipLaunchKernelGGL(k_zgu,   dim3(NPAIRS), dim3(256), 0, stream,
                       x, topk_ids, gate_a, up_a, widx, seq_lens, ranks, scal, zg, zu);
    hipLaunchKernelGGL(k_gufused, dim3(INTER/64, 32, NEXP), dim3(256), 0, stream,
                       x, wgu, gate_b, up_b, zg, zu, cnt, perm, act);
    hipLaunchKernelGGL(k_zd,    dim3(NPAIRS), dim3(256), 0, stream,
                       act, topk_ids, down_a, widx, seq_lens, ranks, scal, zd);
    hipLaunchKernelGGL(k_gemm_down, dim3(HIDDEN/128, 32, NEXP), dim3(256), 0, stream,
                       act, wd, down_b, zd, tw, cnt, perm, outf);
  }
}

// Round 12
// 567.019 us; speedup vs baseline: 1.0982x; 1.0042x over previous
//
#include <hip/hip_runtime.h>
#include <hip/hip_bf16.h>
#include <math.h>

#define N_TOK   2048
#define HIDDEN  1024
#define INTER   2816
#define NEXP    8
#define NADAPT  2
#define MAXRANK 16
#define TOPK    2
#define NSEQ    8
#define NPAIRS  (N_TOK*TOPK)     // 4096
#define NGU     (2*INTER)        // 5632

typedef unsigned short u16;
typedef __attribute__((ext_vector_type(8))) short bf16x8;
typedef __attribute__((ext_vector_type(4))) float f32x4;

// ---- FAST workspace layout (bytes), FAST_NEED = 164 MiB (unchanged) ----
#define F_CNT   0u
#define F_PERM  4096u        // 131072
#define F_ZG    139264u      // 262144
#define F_ZU    401408u      // 262144
#define F_ZD    663552u      // 262144 (ends 925696)
#define F_XBF   1048576u     // 4194304
#define F_ACT   5242880u     // 23068672
#define F_GB    28311552u    // 1441792
#define F_UB    29753344u    // 1441792
#define F_DB    31195136u    // 524288  (ends 31719424)
#define F_GA_BF 31719424u    // 524288  bf16 gate_a
#define F_UA_BF 32243712u    // 524288  bf16 up_a   (ends 32768000)
#define F_ZDF   32768000u    // 524288  f32 zd accumulator (ends 33292288)
#define F_DA_BF 33554432u    // 1441792 bf16 down_a
#define FAST_NEED 171966464u

// ---- fallback layout, ~24.1 MB ----
#define B_CNT   0u
#define B_PERM  4096u
#define B_ZG    262144u
#define B_ZU    524288u
#define B_ZD    786432u
#define B_ACT   1048576u

__device__ __forceinline__ float bf2f(u16 u){
  union { unsigned int i; float f; } v; v.i = ((unsigned int)u)<<16; return v.f;
}
__device__ __forceinline__ u16 f2bf(float f){
  union { float f; unsigned int i; } v; v.f = f;
  unsigned int i = v.i;
  return (u16)((i + 0x7fffu + ((i>>16)&1u)) >> 16);
}
__device__ __forceinline__ uint4 cvt8(const float* src){
  float4 lo = *(const float4*)src;
  float4 hi = *(const float4*)(src+4);
  uint4 r;
  r.x = (unsigned)f2bf(lo.x) | ((unsigned)f2bf(lo.y)<<16);
  r.y = (unsigned)f2bf(lo.z) | ((unsigned)f2bf(lo.w)<<16);
  r.z = (unsigned)f2bf(hi.x) | ((unsigned)f2bf(hi.y)<<16);
  r.w = (unsigned)f2bf(hi.z) | ((unsigned)f2bf(hi.w)<<16);
  return r;
}
__device__ __forceinline__ uint2 cvt4(float4 v){
  uint2 r;
  r.x = (unsigned)f2bf(v.x) | ((unsigned)f2bf(v.y)<<16);
  r.y = (unsigned)f2bf(v.z) | ((unsigned)f2bf(v.w)<<16);
  return r;
}

// HW packed f32->bf16 (gfx950 v_cvt_pk_bf16_f32) — weight-staging fast path only
__device__ __forceinline__ unsigned cvtpk(float a, float b){
  unsigned r;
  asm("v_cvt_pk_bf16_f32 %0, %1, %2" : "=v"(r) : "v"(a), "v"(b));
  return r;
}
__device__ __forceinline__ uint4 pack8(const float* src){
  float4 lo = *(const float4*)src;
  float4 hi = *(const float4*)(src+4);
  uint4 r;
  r.x = cvtpk(lo.x, lo.y);
  r.y = cvtpk(lo.z, lo.w);
  r.z = cvtpk(hi.x, hi.y);
  r.w = cvtpk(hi.z, hi.w);
  return r;
}

// convert one 8192-float chunk c: loads first (8 in flight), then stores
__device__ __forceinline__ void cvt_chunk8k(const float* __restrict__ src, u16* __restrict__ dst, int c, int t){
  size_t b4 = (size_t)c*2048 + t;
  float4 v0 = ((const float4*)src)[b4];
  float4 v1 = ((const float4*)src)[b4 + 256];
  float4 v2 = ((const float4*)src)[b4 + 512];
  float4 v3 = ((const float4*)src)[b4 + 768];
  float4 v4 = ((const float4*)src)[b4 + 1024];
  float4 v5 = ((const float4*)src)[b4 + 1280];
  float4 v6 = ((const float4*)src)[b4 + 1536];
  float4 v7 = ((const float4*)src)[b4 + 1792];
  ((uint2*)dst)[b4]        = cvt4(v0);
  ((uint2*)dst)[b4 + 256]  = cvt4(v1);
  ((uint2*)dst)[b4 + 512]  = cvt4(v2);
  ((uint2*)dst)[b4 + 768]  = cvt4(v3);
  ((uint2*)dst)[b4 + 1024] = cvt4(v4);
  ((uint2*)dst)[b4 + 1280] = cvt4(v5);
  ((uint2*)dst)[b4 + 1536] = cvt4(v6);
  ((uint2*)dst)[b4 + 1792] = cvt4(v7);
}
__device__ __forceinline__ void zero_chunk8k(float* dst, int c, int t){
  size_t b4 = (size_t)c*2048 + t;
  #pragma unroll
  for (int i = 0; i < 8; ++i)
    ((float4*)dst)[b4 + i*256] = make_float4(0.f,0.f,0.f,0.f);
}

// async 16B global -> LDS (wave-uniform LDS base + lane*16)
__device__ __forceinline__ void gl16(const void* g, void* l){
  __builtin_amdgcn_global_load_lds(
      (const __attribute__((address_space(1))) unsigned int*)g,
      (__attribute__((address_space(3))) unsigned int*)l, 16, 0, 0);
}

__device__ __forceinline__ int token_adapter(int n, const int* seq_lens, const int* widx){
  int cum = 0;
  #pragma unroll
  for (int s = 0; s < NSEQ; ++s){ cum += seq_lens[s]; if (n < cum) return widx[s]; }
  return widx[NSEQ-1];
}

// fallback-path zero kernel
__global__ void k_zero(float* outf, int* cnt, float* zdf){
  int t = threadIdx.x;
  if (blockIdx.x < 2048){
    int id = blockIdx.x*256 + t;
    *(float4*)&outf[(size_t)id*4] = make_float4(0.f,0.f,0.f,0.f);
  } else {
    int id = (blockIdx.x - 2048)*256 + t;
    *(float4*)&zdf[(size_t)id*4] = make_float4(0.f,0.f,0.f,0.f);
  }
  if (blockIdx.x == 0 && t < NEXP) cnt[t] = 0;
}

__global__ void k_route(const int* __restrict__ topk_ids, int* cnt, int* perm){
  int p = blockIdx.x*256 + threadIdx.x;
  if (p >= NPAIRS) return;
  int e = topk_ids[p];
  int pos = atomicAdd(&cnt[e], 1);
  perm[e*NPAIRS + pos] = p;
}

// f32 -> bf16, 4 elems/thread, coalesced (small late conversions)
__global__ void k_cvt(const float* __restrict__ src, u16* __restrict__ dst, int n4){
  int id = blockIdx.x*256 + threadIdx.x;
  if (id >= n4) return;
  ((uint2*)dst)[id] = cvt4(((const float4*)src)[id]);
}

// prep: all small conversions + zeroing, 1 launch, 8192 floats/block.
// blocks: x[0,256) gb[256,344) ub[344,432) ga[432,464) ua[464,496) db[496,528)
//         da[528,616) outfZ[616,872) zdfZ[872,888) -> grid 888
__global__ void k_prep(
    const float* __restrict__ x,  const float* __restrict__ gb, const float* __restrict__ ub,
    const float* __restrict__ ga, const float* __restrict__ ua, const float* __restrict__ db_,
    const float* __restrict__ da,
    u16* xb, u16* gbb, u16* ubb, u16* gab, u16* uab, u16* dbb, u16* dab,
    float* outf, float* zdf, int* cnt)
{
  int b = blockIdx.x, t = threadIdx.x;
  if (b == 0 && t < NEXP) cnt[t] = 0;
  if      (b < 256) cvt_chunk8k(x,   xb,  b,       t);
  else if (b < 344) cvt_chunk8k(gb,  gbb, b - 256, t);
  else if (b < 432) cvt_chunk8k(ub,  ubb, b - 344, t);
  else if (b < 464) cvt_chunk8k(ga,  gab, b - 432, t);
  else if (b < 496) cvt_chunk8k(ua,  uab, b - 464, t);
  else if (b < 528) cvt_chunk8k(db_, dbb, b - 496, t);
  else if (b < 616) cvt_chunk8k(da,  dab, b - 528, t);
  else if (b < 872) zero_chunk8k(outf, b - 616, t);
  else              zero_chunk8k(zdf,  b - 872, t);
}

// ===================== MFMA z-kernels (fast path, verified, unchanged) =====================
__global__ __launch_bounds__(256) void k_zgu_mfma(
    const u16* __restrict__ xb, const u16* __restrict__ gab, const u16* __restrict__ uab,
    const int* __restrict__ cnt, const int* __restrict__ perm,
    const int* __restrict__ widx, const int* __restrict__ seq_lens,
    const int* __restrict__ ranks, const float* __restrict__ scal,
    u16* __restrict__ zg, u16* __restrict__ zu)
{
  int e = blockIdx.y;
  int me = cnt[e];
  int tm = blockIdx.x;
  if (tm*64 >= me) return;
  int t = threadIdx.x;

  __shared__ __align__(16) u16 As[64*32];
  __shared__ __align__(16) u16 Bs[64*32];

  int r0 = t >> 2;
  int kc = ((t&3) - r0) & 3;     // swizzle: slot (t&3) holds logical chunk kc
  int ko = kc*8;
  int mg = tm*64 + r0;
  int pa = perm[e*NPAIRS + min(mg, me-1)];
  const u16* arow = xb + (size_t)(pa>>1)*HIDDEN + ko;
  int jr = r0 & 31;              // B row: r0<32 -> gate_a, else up_a
  const u16* brow = (r0 < 32 ? gab : uab)
                    + (size_t)(((jr>>4)*NEXP + e)*MAXRANK + (jr&15))*HIDDEN + ko;

  int wv = t>>6, lane = t&63;
  u16* Asw = &As[wv*512];
  u16* Bsw = &Bs[wv*512];
  int wm = wv>>1, wn = wv&1;
  int l15 = lane&15, q = lane>>4;

  f32x4 acc[2][2] = {};
  int aoff[2], boff[2];
  #pragma unroll
  for (int i=0;i<2;++i){ int row = wm*32 + i*16 + l15; aoff[i] = row*32 + ((q+row)&3)*8; }
  #pragma unroll
  for (int j=0;j<2;++j){ int row = wn*32 + j*16 + l15; boff[j] = row*32 + ((q+row)&3)*8; }

  for (int kt = 0; kt < HIDDEN/32; ++kt){
    __syncthreads();
    gl16(arow + kt*32, Asw);
    gl16(brow + kt*32, Bsw);
    __syncthreads();
    bf16x8 af[2], bfr[2];
    #pragma unroll
    for (int i=0;i<2;++i) af[i] = *(const bf16x8*)&As[aoff[i]];
    #pragma unroll
    for (int j=0;j<2;++j) bfr[j] = *(const bf16x8*)&Bs[boff[j]];
    #pragma unroll
    for (int i=0;i<2;++i)
      #pragma unroll
      for (int j=0;j<2;++j)
        acc[i][j] = __builtin_amdgcn_mfma_f32_16x16x32_bf16(af[i], bfr[j], acc[i][j],0,0,0);
  }

  u16* dstz = wn ? zu : zg;
  #pragma unroll
  for (int i=0;i<2;++i){
    #pragma unroll
    for (int r=0;r<4;++r){
      int mgo = tm*64 + wm*32 + i*16 + q*4 + r;
      if (mgo < me){
        int p = perm[e*NPAIRS + mgo];
        int a = token_adapter(p>>1, seq_lens, widx);
        int rank = ranks[a]; float sc = scal[a];
        #pragma unroll
        for (int j=0;j<2;++j){
          int jc = j*16 + l15;
          float v = ((jc>>4)==a && (jc&15)<rank) ? sc*acc[i][j][r] : 0.f;
          dstz[(size_t)p*32 + jc] = f2bf(v);
        }
      }
    }
  }
}

__global__ __launch_bounds__(256) void k_zd_mfma(
    const u16* __restrict__ act, const u16* __restrict__ dab,
    const int* __restrict__ cnt, const int* __restrict__ perm,
    const int* __restrict__ widx, const int* __restrict__ seq_lens,
    const int* __restrict__ ranks, const float* __restrict__ scal,
    float* __restrict__ zdf)
{
  int e = blockIdx.z;
  int me = cnt[e];
  int tm = blockIdx.y;
  if (tm*64 >= me) return;
  int ks = blockIdx.x;           // 0..3
  int t = threadIdx.x;

  __shared__ __align__(16) u16 As[64*32];
  __shared__ __align__(16) u16 Bs[32*32];

  int r0 = t >> 2;
  int kc = ((t&3) - r0) & 3;
  int ko = kc*8;
  int mg = tm*64 + r0;
  int pa = perm[e*NPAIRS + min(mg, me-1)];
  const u16* arow = act + (size_t)pa*INTER + ko;
  int jr = r0 & 31;
  const u16* brow = dab + (size_t)(((jr>>4)*NEXP + e)*MAXRANK + (jr&15))*INTER + ko;

  int wv = t>>6, lane = t&63;
  u16* Asw = &As[wv*512];
  u16* Bsw = &Bs[(wv&1)*512];    // waves 0,1 stage the 32 B rows
  int l15 = lane&15, q = lane>>4;

  f32x4 acc[2] = {};
  int aoff; { int row = wv*16 + l15; aoff = row*32 + ((q+row)&3)*8; }
  int boff[2];
  #pragma unroll
  for (int j=0;j<2;++j){ int row = j*16 + l15; boff[j] = row*32 + ((q+row)&3)*8; }

  int kt0 = ks*22, kt1 = kt0 + 22;   // INTER/32 = 88 = 4*22
  for (int kt = kt0; kt < kt1; ++kt){
    __syncthreads();
    gl16(arow + kt*32, Asw);
    if (wv < 2) gl16(brow + kt*32, Bsw);
    __syncthreads();
    bf16x8 af = *(const bf16x8*)&As[aoff];
    bf16x8 b0 = *(const bf16x8*)&Bs[boff[0]];
    bf16x8 b1 = *(const bf16x8*)&Bs[boff[1]];
    acc[0] = __builtin_amdgcn_mfma_f32_16x16x32_bf16(af, b0, acc[0],0,0,0);
    acc[1] = __builtin_amdgcn_mfma_f32_16x16x32_bf16(af, b1, acc[1],0,0,0);
  }

  #pragma unroll
  for (int r=0;r<4;++r){
    int mgo = tm*64 + wv*16 + q*4 + r;
    if (mgo < me){
      int p = perm[e*NPAIRS + mgo];
      int a = token_adapter(p>>1, seq_lens, widx);
      int rank = ranks[a]; float sc = scal[a];
      #pragma unroll
      for (int j=0;j<2;++j){
        int jc = j*16 + l15;
        if ((jc>>4)==a && (jc&15)<rank)
          atomicAdd(&zdf[(size_t)p*32 + jc], sc*acc[j][r]);
      }
    }
  }
}

// ===================== fallback z-kernels (f32 weights) =====================
__global__ __launch_bounds__(256) void k_zgu(
    const float* __restrict__ x, const int* __restrict__ topk_ids,
    const float* __restrict__ gate_a, const float* __restrict__ up_a,
    const int* __restrict__ widx, const int* __restrict__ seq_lens,
    const int* __restrict__ ranks, const float* __restrict__ scal,
    u16* __restrict__ zg, u16* __restrict__ zu)
{
  int p = blockIdx.x, n = p >> 1, t = threadIdx.x;
  int e = topk_ids[p];
  __shared__ float xs[HIDDEN];
  for (int i = t; i < HIDDEN; i += 256) xs[i] = x[(size_t)n*HIDDEN + i];
  if (t < 32){ zg[p*32 + t] = 0; zu[p*32 + t] = 0; }
  __syncthreads();
  int a = token_adapter(n, seq_lens, widx);
  int rank = ranks[a];
  float scale = scal[a];
  int wv = t >> 6, lane = t & 63;
  for (int i = 0; i < 8; ++i){
    int o = wv*8 + i;
    int r = o & 15;
    const float* wrow = ((o < 16) ? gate_a : up_a) + (size_t)((a*NEXP + e)*MAXRANK + r)*HIDDEN;
    float s = 0.f;
    for (int h = lane; h < HIDDEN; h += 64) s += xs[h] * wrow[h];
    s += __shfl_down(s,32); s += __shfl_down(s,16); s += __shfl_down(s,8);
    s += __shfl_down(s,4);  s += __shfl_down(s,2);  s += __shfl_down(s,1);
    if (lane == 0 && r < rank)
      (o < 16 ? zg : zu)[p*32 + a*16 + r] = f2bf(scale * s);
  }
}

__global__ __launch_bounds__(256) void k_zd(
    const u16* __restrict__ act, const int* __restrict__ topk_ids,
    const float* __restrict__ down_a,
    const int* __restrict__ widx, const int* __restrict__ seq_lens,
    const int* __restrict__ ranks, const float* __restrict__ scal,
    u16* __restrict__ zd)
{
  int p = blockIdx.x, n = p >> 1, t = threadIdx.x;
  int e = topk_ids[p];
  __shared__ float as_[INTER];
  for (int i = t; i < INTER; i += 256) as_[i] = bf2f(act[(size_t)p*INTER + i]);
  if (t < 32) zd[p*32 + t] = 0;
  __syncthreads();
  int a = token_adapter(n, seq_lens, widx);
  int rank = ranks[a];
  float scale = scal[a];
  int wv = t >> 6, lane = t & 63;
  for (int i = 0; i < 4; ++i){
    int r = wv*4 + i;
    const float* wrow = down_a + (size_t)((a*NEXP + e)*MAXRANK + r)*INTER;
    float s = 0.f;
    for (int h = lane; h < INTER; h += 64) s += as_[h] * wrow[h];
    s += __shfl_down(s,32); s += __shfl_down(s,16); s += __shfl_down(s,8);
    s += __shfl_down(s,4);  s += __shfl_down(s,2);  s += __shfl_down(s,1);
    if (lane == 0 && r < rank) zd[p*32 + a*16 + r] = f2bf(scale * s);
  }
}

// ===================== gu GEMM: M-tile 256, 512 threads (8 waves), pack8 staging ============
// (round-11 verified, unchanged)
__global__ __launch_bounds__(512) void k_gu_f32(
    const u16* __restrict__ xb, const float* __restrict__ wgu_f32,
    const u16* __restrict__ gbb, const u16* __restrict__ ubb,
    const u16* __restrict__ zg, const u16* __restrict__ zu,
    const int* __restrict__ cnt, const int* __restrict__ perm,
    u16* __restrict__ act)
{
  int e = blockIdx.z;
  int me = cnt[e];
  int tm = blockIdx.y;            // 0..15, 256 pairs each
  if (tm*256 >= me) return;
  int tn = blockIdx.x;            // 0..43, 64 inter-cols each
  int t = threadIdx.x;            // 0..511

  __shared__ __align__(16) u16 As[256*32];   // 16KB
  __shared__ __align__(16) u16 Bg[64*32];    // 4KB
  __shared__ __align__(16) u16 Bu[64*32];    // 4KB

  int wv = t>>6, lane = t&63;
  int r0 = t >> 2;                // 0..127
  int kc = ((t&3) - r0) & 3;
  int ko = kc*8;
  int mg0 = tm*256 + r0, mg1 = mg0 + 128;
  int p0 = perm[e*NPAIRS + min(mg0, me-1)];
  int p1 = perm[e*NPAIRS + min(mg1, me-1)];
  const u16* arow0 = xb + (size_t)(p0>>1)*HIDDEN + ko;
  const u16* arow1 = xb + (size_t)(p1>>1)*HIDDEN + ko;

  // B staging (combined pass): waves 0-3 -> Bg rows, waves 4-7 -> Bu rows
  int rB  = (wv&3)*16 + (lane>>2);             // 0..63
  int kcB = ((lane&3) - rB) & 3;               // slot (lane&3) holds logical chunk kcB
  const float* browX = wgu_f32
      + ((size_t)e*NGU + (wv<4 ? 0 : INTER) + tn*64 + rB)*HIDDEN + kcB*8;
  u16* BdstX = (wv<4 ? Bg : Bu) + (wv&3)*512 + lane*8;

  u16* Asw0 = &As[wv*512];
  u16* Asw1 = &As[4096 + wv*512];

  int wm = wv>>1, wn = wv&1;      // wm 0..3 (row group of 64), wn 0..1 (col group of 32)
  int l15 = lane&15, q = lane>>4;

  f32x4 accg[4][2] = {};
  f32x4 accu[4][2] = {};
  int aoff[4], boff[2];
  #pragma unroll
  for (int i=0;i<4;++i){ int row = wm*64 + i*16 + l15; aoff[i] = row*32 + ((q+row)&3)*8; }
  #pragma unroll
  for (int j=0;j<2;++j){ int row = wn*32 + j*16 + l15; boff[j] = row*32 + ((q+row)&3)*8; }

  for (int kt = 0; kt < HIDDEN/32; ++kt){
    uint4 bx = pack8(browX + kt*32);   // f32 load + HW cvt_pk before barrier
    __syncthreads();
    gl16(arow0 + kt*32, Asw0);
    gl16(arow1 + kt*32, Asw1);
    *(uint4*)BdstX = bx;
    __syncthreads();
    bf16x8 af[4], bgf[2], buf[2];
    #pragma unroll
    for (int i=0;i<4;++i) af[i] = *(const bf16x8*)&As[aoff[i]];
    #pragma unroll
    for (int j=0;j<2;++j){ bgf[j] = *(const bf16x8*)&Bg[boff[j]]; buf[j] = *(const bf16x8*)&Bu[boff[j]]; }
    #pragma unroll
    for (int i=0;i<4;++i)
      #pragma unroll
      for (int j=0;j<2;++j){
        accg[i][j] = __builtin_amdgcn_mfma_f32_16x16x32_bf16(af[i], bgf[j], accg[i][j],0,0,0);
        accu[i][j] = __builtin_amdgcn_mfma_f32_16x16x32_bf16(af[i], buf[j], accu[i][j],0,0,0);
      }
  }
  // LoRA K-extension (32 = NADAPT*MAXRANK): A rows via 2 gl16 passes; B rows 0-63 by waves 0-3
  {
    int aid = kc>>1, rr = (kc&1)*8;
    int jg = tn*64 + r0;                 // only used by wv<4 (r0 < 64 there)
    const u16* gB = gbb + ((size_t)(aid*NEXP+e)*INTER + jg)*MAXRANK + rr;
    const u16* uB = ubb + ((size_t)(aid*NEXP+e)*INTER + jg)*MAXRANK + rr;
    u16* Bgw = &Bg[(wv&3)*512];
    __syncthreads();
    gl16(zg + (size_t)p0*32 + ko, Asw0);
    gl16(zg + (size_t)p1*32 + ko, Asw1);
    if (wv < 4) gl16(gB, Bgw);
    __syncthreads();
    {
      bf16x8 af[4], bgf[2];
      #pragma unroll
      for (int i=0;i<4;++i) af[i] = *(const bf16x8*)&As[aoff[i]];
      #pragma unroll
      for (int j=0;j<2;++j) bgf[j] = *(const bf16x8*)&Bg[boff[j]];
      #pragma unroll
      for (int i=0;i<4;++i)
        #pragma unroll
        for (int j=0;j<2;++j)
          accg[i][j] = __builtin_amdgcn_mfma_f32_16x16x32_bf16(af[i], bgf[j], accg[i][j],0,0,0);
    }
    __syncthreads();
    gl16(zu + (size_t)p0*32 + ko, Asw0);
    gl16(zu + (size_t)p1*32 + ko, Asw1);
    if (wv < 4) gl16(uB, Bgw);
    __syncthreads();
    {
      bf16x8 af[4], buf[2];
      #pragma unroll
      for (int i=0;i<4;++i) af[i] = *(const bf16x8*)&As[aoff[i]];
      #pragma unroll
      for (int j=0;j<2;++j) buf[j] = *(const bf16x8*)&Bg[boff[j]];
      #pragma unroll
      for (int i=0;i<4;++i)
        #pragma unroll
        for (int j=0;j<2;++j)
          accu[i][j] = __builtin_amdgcn_mfma_f32_16x16x32_bf16(af[i], buf[j], accu[i][j],0,0,0);
    }
  }

  int col = l15, quad = q;
  #pragma unroll
  for (int i = 0; i < 4; ++i){
    #pragma unroll
    for (int r = 0; r < 4; ++r){
      int mg = tm*256 + wm*64 + i*16 + quad*4 + r;
      if (mg < me){
        int p = perm[e*NPAIRS + mg];
        size_t base = (size_t)p*INTER;
        #pragma unroll
        for (int j = 0; j < 2; ++j){
          int jc = tn*64 + wn*32 + j*16 + col;
          float g = accg[i][j][r], u = accu[i][j][r];
          float s = g / (1.f + __expf(-g));
          act[base + jc] = f2bf(s*u);
        }
      }
    }
  }
}

// ===================== down GEMM: M-tile 256, 512 threads (8 waves), split-K x4, pack8 ======
// A: 256 rows x 32 bf16 (16KB), two gl16 passes. B: 128 rows x 32 bf16 (8KB),
// one pack8 per thread (thread t -> Bs[t*8], row t>>2, XOR-slot swizzle).
__global__ __launch_bounds__(512) void k_down_f32(
    const u16* __restrict__ act, const float* __restrict__ wd_f32,
    const u16* __restrict__ dbb, const u16* __restrict__ zd,
    const float* __restrict__ tw,
    const int* __restrict__ cnt, const int* __restrict__ perm,
    float* __restrict__ outf)
{
  int e = blockIdx.z;
  int me = cnt[e];
  int tm = blockIdx.y;            // 0..15, 256 pairs each
  if (tm*256 >= me) return;
  int tn = blockIdx.x & 7;
  int ks = blockIdx.x >> 3;       // 0..3
  int t = threadIdx.x;            // 0..511

  __shared__ __align__(16) u16 As[256*32];   // 16KB
  __shared__ __align__(16) u16 Bs[128*32];   // 8KB

  int wv = t>>6, lane = t&63;
  int r0 = t >> 2;                // 0..127
  int kc = ((t&3) - r0) & 3;
  int ko = kc*8;
  int mg0 = tm*256 + r0, mg1 = mg0 + 128;
  int p0 = perm[e*NPAIRS + min(mg0, me-1)];
  int p1 = perm[e*NPAIRS + min(mg1, me-1)];
  const u16* arow0 = act + (size_t)p0*INTER + ko;
  const u16* arow1 = act + (size_t)p1*INTER + ko;
  // B: thread t stages row r0 (0..127), slot t&3 holds chunk kc
  const float* brow = wd_f32 + ((size_t)e*HIDDEN + tn*128 + r0)*INTER + ko;

  u16* Asw0 = &As[wv*512];
  u16* Asw1 = &As[4096 + wv*512];
  u16* Bdst = &Bs[(size_t)t*8];

  int wm = wv>>1, wn = wv&1;      // wm 0..3 (row group of 64), wn 0..1 (col group of 64)
  int l15 = lane&15, q = lane>>4;

  f32x4 acc[4][4] = {};
  int aoff[4], boff[4];
  #pragma unroll
  for (int i=0;i<4;++i){ int row = wm*64 + i*16 + l15; aoff[i] = row*32 + ((q+row)&3)*8; }
  #pragma unroll
  for (int j=0;j<4;++j){ int row = wn*64 + j*16 + l15; boff[j] = row*32 + ((q+row)&3)*8; }

  auto mma = [&](){
    bf16x8 af[4], bfr[4];
    #pragma unroll
    for (int i=0;i<4;++i){ af[i] = *(const bf16x8*)&As[aoff[i]]; bfr[i] = *(const bf16x8*)&Bs[boff[i]]; }
    #pragma unroll
    for (int i=0;i<4;++i)
      #pragma unroll
      for (int j=0;j<4;++j)
        acc[i][j] = __builtin_amdgcn_mfma_f32_16x16x32_bf16(af[i], bfr[j], acc[i][j],0,0,0);
  };

  int kt0 = ks*22, kt1 = kt0 + 22;
  for (int kt = kt0; kt < kt1; ++kt){
    uint4 b = pack8(brow + kt*32);
    __syncthreads();
    gl16(arow0 + kt*32, Asw0);
    gl16(arow1 + kt*32, Asw1);
    *(uint4*)Bdst = b;
    __syncthreads();
    mma();
  }
  if (ks == 3){
    int aid = kc>>1, rr = (kc&1)*8;
    // B: 128 rows of dbb staged by all 8 waves (16 rows each), same slot math
    const u16* dB = dbb + ((size_t)(aid*NEXP+e)*HIDDEN + tn*128 + r0)*MAXRANK + rr;
    u16* Bw = &Bs[wv*512];
    __syncthreads();
    gl16(zd + (size_t)p0*32 + ko, Asw0);
    gl16(zd + (size_t)p1*32 + ko, Asw1);
    gl16(dB, Bw);
    __syncthreads();
    mma();
  }

  int col = l15, quad = q;
  #pragma unroll
  for (int i = 0; i < 4; ++i){
    #pragma unroll
    for (int r = 0; r < 4; ++r){
      int mg = tm*256 + wm*64 + i*16 + quad*4 + r;
      if (mg < me){
        int p = perm[e*NPAIRS + mg];
        float wp = tw[p];
        size_t base = (size_t)(p >> 1)*HIDDEN;
        #pragma unroll
        for (int j = 0; j < 4; ++j){
          int jc = tn*128 + wn*64 + j*16 + col;
          atomicAdd(&outf[base + jc], wp * acc[i][j][r]);
        }
      }
    }
  }
}

// ===================== FALLBACK PATH GEMMs (f32 weights, verified) =====================
__global__ __launch_bounds__(256) void k_gufused(
    const float* __restrict__ x, const float* __restrict__ wgu,
    const float* __restrict__ gate_b, const float* __restrict__ up_b,
    const u16* __restrict__ zg, const u16* __restrict__ zu,
    const int* __restrict__ cnt, const int* __restrict__ perm,
    u16* __restrict__ act)
{
  int e = blockIdx.z;
  int me = cnt[e];
  int tm = blockIdx.y;
  if (tm*128 >= me) return;
  int tn = blockIdx.x;
  int t = threadIdx.x;

  __shared__ __align__(16) u16 As[128*32];
  __shared__ __align__(16) u16 Bg[64*32];
  __shared__ __align__(16) u16 Bu[64*32];

  int r0 = t >> 2, cc = t & 3;
  int mg0 = tm*128 + r0, mg1 = mg0 + 64;
  int p0 = perm[e*NPAIRS + min(mg0, me-1)];
  int p1 = perm[e*NPAIRS + min(mg1, me-1)];
  const float* arow0 = x + (size_t)(p0 >> 1)*HIDDEN;
  const float* arow1 = x + (size_t)(p1 >> 1)*HIDDEN;
  int jg = tn*64 + r0;
  const float* browg = wgu + ((size_t)e*NGU + jg)*HIDDEN;
  const float* browu = wgu + ((size_t)e*NGU + INTER + jg)*HIDDEN;

  int wv = t >> 6, lane = t & 63;
  int wm = wv >> 1, wn = wv & 1;

  f32x4 accg[4][2] = {};
  f32x4 accu[4][2] = {};
  int aoff[4], boff[2];
  #pragma unroll
  for (int i = 0; i < 4; ++i) aoff[i] = (wm*64 + i*16 + (lane&15))*32 + (lane>>4)*8;
  #pragma unroll
  for (int j = 0; j < 2; ++j) boff[j] = (wn*32 + j*16 + (lane&15))*32 + (lane>>4)*8;

  for (int kt = 0; kt < HIDDEN/32; ++kt){
    uint4 a0 = cvt8(arow0 + kt*32 + cc*8);
    uint4 a1 = cvt8(arow1 + kt*32 + cc*8);
    uint4 bg = cvt8(browg + kt*32 + cc*8);
    uint4 bu = cvt8(browu + kt*32 + cc*8);
    __syncthreads();
    *(uint4*)&As[r0*32 + cc*8]      = a0;
    *(uint4*)&As[(r0+64)*32 + cc*8] = a1;
    *(uint4*)&Bg[r0*32 + cc*8]      = bg;
    *(uint4*)&Bu[r0*32 + cc*8]      = bu;
    __syncthreads();
    bf16x8 af[4], bgf[2], buf[2];
    #pragma unroll
    for (int i = 0; i < 4; ++i) af[i] = *(const bf16x8*)&As[aoff[i]];
    #pragma unroll
    for (int j = 0; j < 2; ++j){ bgf[j] = *(const bf16x8*)&Bg[boff[j]]; buf[j] = *(const bf16x8*)&Bu[boff[j]]; }
    #pragma unroll
    for (int i = 0; i < 4; ++i)
      #pragma unroll
      for (int j = 0; j < 2; ++j){
        accg[i][j] = __builtin_amdgcn_mfma_f32_16x16x32_bf16(af[i], bgf[j], accg[i][j], 0, 0, 0);
        accu[i][j] = __builtin_amdgcn_mfma_f32_16x16x32_bf16(af[i], buf[j], accu[i][j], 0, 0, 0);
      }
  }
  {
    uint4 a0 = *(const uint4*)(zg + (size_t)p0*32 + cc*8);
    uint4 a1 = *(const uint4*)(zg + (size_t)p1*32 + cc*8);
    int aid = cc >> 1, rr = (cc & 1)*8;
    uint4 bg = cvt8(gate_b + ((size_t)(aid*NEXP + e)*INTER + jg)*MAXRANK + rr);
    __syncthreads();
    *(uint4*)&As[r0*32 + cc*8]      = a0;
    *(uint4*)&As[(r0+64)*32 + cc*8] = a1;
    *(uint4*)&Bg[r0*32 + cc*8]      = bg;
    __syncthreads();
    bf16x8 af[4], bgf[2];
    #pragma unroll
    for (int i = 0; i < 4; ++i) af[i] = *(const bf16x8*)&As[aoff[i]];
    #pragma unroll
    for (int j = 0; j < 2; ++j) bgf[j] = *(const bf16x8*)&Bg[boff[j]];
    #pragma unroll
    for (int i = 0; i < 4; ++i)
      #pragma unroll
      for (int j = 0; j < 2; ++j)
        accg[i][j] = __builtin_amdgcn_mfma_f32_16x16x32_bf16(af[i], bgf[j], accg[i][j], 0, 0, 0);
  }
  {
    uint4 a0 = *(const uint4*)(zu + (size_t)p0*32 + cc*8);
    uint4 a1 = *(const uint4*)(zu + (size_t)p1*32 + cc*8);
    int aid = cc >> 1, rr = (cc & 1)*8;
    uint4 bu = cvt8(up_b + ((size_t)(aid*NEXP + e)*INTER + jg)*MAXRANK + rr);
    __syncthreads();
    *(uint4*)&As[r0*32 + cc*8]      = a0;
    *(uint4*)&As[(r0+64)*32 + cc*8] = a1;
    *(uint4*)&Bg[r0*32 + cc*8]      = bu;
    __syncthreads();
    bf16x8 af[4], buf[2];
    #pragma unroll
    for (int i = 0; i < 4; ++i) af[i] = *(const bf16x8*)&As[aoff[i]];
    #pragma unroll
    for (int j = 0; j < 2; ++j) buf[j] = *(const bf16x8*)&Bg[boff[j]];
    #pragma unroll
    for (int i = 0; i < 4; ++i)
      #pragma unroll
      for (int j = 0; j < 2; ++j)
        accu[i][j] = __builtin_amdgcn_mfma_f32_16x16x32_bf16(af[i], buf[j], accu[i][j], 0, 0, 0);
  }
  int col = lane & 15, quad = lane >> 4;
  #pragma unroll
  for (int i = 0; i < 4; ++i){
    #pragma unroll
    for (int r = 0; r < 4; ++r){
      int mg = tm*128 + wm*64 + i*16 + quad*4 + r;
      if (mg < me){
        int p = perm[e*NPAIRS + mg];
        size_t base = (size_t)p*INTER;
        #pragma unroll
        for (int j = 0; j < 2; ++j){
          int jc = tn*64 + wn*32 + j*16 + col;
          float g = accg[i][j][r], u = accu[i][j][r];
          float s = g / (1.f + __expf(-g));
          act[base + jc] = f2bf(s*u);
        }
      }
    }
  }
}

__global__ __launch_bounds__(256) void k_gemm_down(
    const u16* __restrict__ act, const float* __restrict__ wd,
    const float* __restrict__ down_b, const u16* __restrict__ zd,
    const float* __restrict__ tw,
    const int* __restrict__ cnt, const int* __restrict__ perm,
    float* __restrict__ outf)
{
  int e = blockIdx.z;
  int me = cnt[e];
  int tm = blockIdx.y;
  if (tm*128 >= me) return;
  int tn = blockIdx.x;
  int t = threadIdx.x;

  __shared__ __align__(16) u16 As[128*32];
  __shared__ __align__(16) u16 Bs[128*32];

  int r0 = t >> 2, cc = t & 3;
  int mg0 = tm*128 + r0, mg1 = mg0 + 64;
  int p0 = perm[e*NPAIRS + min(mg0, me-1)];
  int p1 = perm[e*NPAIRS + min(mg1, me-1)];
  const u16* arow0 = act + (size_t)p0*INTER;
  const u16* arow1 = act + (size_t)p1*INTER;
  int j0 = tn*128 + r0, j1 = j0 + 64;
  const float* brow0 = wd + ((size_t)e*HIDDEN + j0)*INTER;
  const float* brow1 = wd + ((size_t)e*HIDDEN + j1)*INTER;

  int wv = t >> 6, lane = t & 63;
  int wm = wv >> 1, wn = wv & 1;

  f32x4 acc[4][4] = {};
  int aoff[4], boff[4];
  #pragma unroll
  for (int i = 0; i < 4; ++i){
    aoff[i] = (wm*64 + i*16 + (lane&15))*32 + (lane>>4)*8;
    boff[i] = (wn*64 + i*16 + (lane&15))*32 + (lane>>4)*8;
  }

  auto compute = [&](){
    bf16x8 af[4], bfr[4];
    #pragma unroll
    for (int i = 0; i < 4; ++i){
      af[i]  = *(const bf16x8*)&As[aoff[i]];
      bfr[i] = *(const bf16x8*)&Bs[boff[i]];
    }
    #pragma unroll
    for (int i = 0; i < 4; ++i)
      #pragma unroll
      for (int j = 0; j < 4; ++j)
        acc[i][j] = __builtin_amdgcn_mfma_f32_16x16x32_bf16(af[i], bfr[j], acc[i][j], 0, 0, 0);
  };

  for (int kt = 0; kt < INTER/32; ++kt){
    uint4 a0 = *(const uint4*)(arow0 + kt*32 + cc*8);
    uint4 a1 = *(const uint4*)(arow1 + kt*32 + cc*8);
    uint4 b0 = cvt8(brow0 + kt*32 + cc*8);
    uint4 b1 = cvt8(brow1 + kt*32 + cc*8);
    __syncthreads();
    *(uint4*)&As[r0*32 + cc*8]      = a0;
    *(uint4*)&As[(r0+64)*32 + cc*8] = a1;
    *(uint4*)&Bs[r0*32 + cc*8]      = b0;
    *(uint4*)&Bs[(r0+64)*32 + cc*8] = b1;
    __syncthreads();
    compute();
  }
  {
    uint4 a0 = *(const uint4*)(zd + (size_t)p0*32 + cc*8);
    uint4 a1 = *(const uint4*)(zd + (size_t)p1*32 + cc*8);
    int aid = cc >> 1, rr = (cc & 1)*8;
    uint4 b0 = cvt8(down_b + ((size_t)(aid*NEXP + e)*HIDDEN + j0)*MAXRANK + rr);
    uint4 b1 = cvt8(down_b + ((size_t)(aid*NEXP + e)*HIDDEN + j1)*MAXRANK + rr);
    __syncthreads();
    *(uint4*)&As[r0*32 + cc*8]      = a0;
    *(uint4*)&As[(r0+64)*32 + cc*8] = a1;
    *(uint4*)&Bs[r0*32 + cc*8]      = b0;
    *(uint4*)&Bs[(r0+64)*32 + cc*8] = b1;
    __syncthreads();
    compute();
  }
  int col = lane & 15, quad = lane >> 4;
  #pragma unroll
  for (int i = 0; i < 4; ++i){
    #pragma unroll
    for (int r = 0; r < 4; ++r){
      int mg = tm*128 + wm*64 + i*16 + quad*4 + r;
      if (mg < me){
        int p = perm[e*NPAIRS + mg];
        float wp = tw[p];
        size_t base = (size_t)(p >> 1)*HIDDEN;
        #pragma unroll
        for (int j = 0; j < 4; ++j){
          int jc = tn*128 + wn*64 + j*16 + col;
          atomicAdd(&outf[base + jc], wp * acc[i][j][r]);
        }
      }
    }
  }
}

extern "C" void kernel_launch(void* const* d_in, const int* in_sizes, int n_in,
                              void* d_out, int out_size, void* d_ws, size_t ws_size,
                              hipStream_t stream){
  const float* x        = (const float*)d_in[0];
  const int*   topk_ids = (const int*)d_in[1];
  const float* tw       = (const float*)d_in[2];
  const float* gate_a   = (const float*)d_in[3];
  const float* gate_b   = (const float*)d_in[4];
  const float* up_a     = (const float*)d_in[5];
  const float* up_b     = (const float*)d_in[6];
  const float* down_a   = (const float*)d_in[7];
  const float* down_b   = (const float*)d_in[8];
  const int*   widx     = (const int*)d_in[9];
  const int*   seq_lens = (const int*)d_in[10];
  const int*   ranks    = (const int*)d_in[11];
  const float* scal     = (const float*)d_in[12];
  const float* wgu      = (const float*)d_in[13];
  const float* wd       = (const float*)d_in[14];
  float* outf = (float*)d_out;
  char* ws = (char*)d_ws;

  if (ws_size >= (size_t)FAST_NEED){
    int* cnt  = (int*)(ws + F_CNT);
    int* perm = (int*)(ws + F_PERM);
    u16* zg   = (u16*)(ws + F_ZG);
    u16* zu   = (u16*)(ws + F_ZU);
    u16* zd   = (u16*)(ws + F_ZD);
    u16* xb   = (u16*)(ws + F_XBF);
    u16* act  = (u16*)(ws + F_ACT);
    u16* gbb  = (u16*)(ws + F_GB);
    u16* ubb  = (u16*)(ws + F_UB);
    u16* dbb  = (u16*)(ws + F_DB);
    u16* gab  = (u16*)(ws + F_GA_BF);
    u16* uab  = (u16*)(ws + F_UA_BF);
    float* zdf= (float*)(ws + F_ZDF);
    u16* dab  = (u16*)(ws + F_DA_BF);

    hipLaunchKernelGGL(k_prep, dim3(888), dim3(256), 0, stream,
                       x, gate_b, up_b, gate_a, up_a, down_b, down_a,
                       xb, gbb, ubb, gab, uab, dbb, dab, outf, zdf, cnt);
    hipLaunchKernelGGL(k_route, dim3(16), dim3(256), 0, stream, topk_ids, cnt, perm);
    hipLaunchKernelGGL(k_zgu_mfma, dim3(64, NEXP), dim3(256), 0, stream,
                       xb, gab, uab, cnt, perm, widx, seq_lens, ranks, scal, zg, zu);
    hipLaunchKernelGGL(k_gu_f32, dim3(INTER/64, 16, NEXP), dim3(512), 0, stream,
                       xb, wgu, gbb, ubb, zg, zu, cnt, perm, act);
    hipLaunchKernelGGL(k_zd_mfma, dim3(4, 64, NEXP), dim3(256), 0, stream,
                       act, dab, cnt, perm, widx, seq_lens, ranks, scal, zdf);
    hipLaunchKernelGGL(k_cvt, dim3((NPAIRS*32/4+255)/256), dim3(256), 0, stream,
                       zdf, zd, NPAIRS*32/4);
    hipLaunchKernelGGL(k_down_f32, dim3(32, 16, NEXP), dim3(512), 0, stream,
                       act, wd, dbb, zd, tw, cnt, perm, outf);
  } else {
    int* cnt  = (int*)(ws + B_CNT);
    int* perm = (int*)(ws + B_PERM);
    u16* zg   = (u16*)(ws + B_ZG);
    u16* zu   = (u16*)(ws + B_ZU);
    u16* zd   = (u16*)(ws + B_ZD);
    u16* act  = (u16*)(ws + B_ACT);

    hipLaunchKernelGGL(k_zero,  dim3(2048), dim3(256), 0, stream, outf, cnt, outf);
    hipLaunchKernelGGL(k_route, dim3(16), dim3(256), 0, stream, topk_ids, cnt, perm);
    hipLaunchKernelGGL(k_zgu,   dim3(NPAIRS), dim3(256), 0, stream,
                       x, topk_ids, gate_a, up_a, widx, seq_lens, ranks, scal, zg, zu);
    hipLaunchKernelGGL(k_gufused, dim3(INTER/64, 32, NEXP), dim3(256), 0, stream,
                       x, wgu, gate_b, up_b, zg, zu, cnt, perm, act);
    hipLaunchKernelGGL(k_zd,    dim3(NPAIRS), dim3(256), 0, stream,
                       act, topk_ids, down_a, widx, seq_lens, ranks, scal, zd);
    hipLaunchKernelGGL(k_gemm_down, dim3(HIDDEN/128, 32, NEXP), dim3(256), 0, stream,
                       act, wd, down_b, zd, tw, cnt, perm, outf);
  }
}